// Round 11
// baseline (1081.855 us; speedup 1.0000x reference)
//
#include <hip/hip_runtime.h>
#include <hip/hip_bf16.h>

// ---- model dims ----
constexpr int TB = 512, TL = 200, TH = 128, TNH = 4, TD = 32;
constexpr int TFT = 32, TTP = 64, TIP = 200;
constexpr int TSH = 512, TFH = 256;
constexpr int TITEMS = 100001;
constexpr int TNT = TB * TTP;   // 32768
constexpr int TNI = TB * TIP;   // 102400
constexpr int TLP = 224;        // L padded (K of scb GEMM1)
constexpr int TIPAD = 100096;   // items padded to 128

typedef __attribute__((ext_vector_type(8))) short short8v;
typedef __attribute__((ext_vector_type(4))) float f32x4;

// tanh-form gelu, |err| <= ~3e-4 (below bf16 quantization of the result)
__device__ inline float gelu_fast(float x) {
    float u = x + 0.044715f * x * x * x;
    float e = exp2f(-2.302208f * u);
    return x / (1.0f + e);
}
__device__ inline unsigned short to_bf16u(float x) {
    __hip_bfloat16 h = __float2bfloat16(x);
    return *reinterpret_cast<unsigned short*>(&h);
}
__device__ inline float bfu_to_f(unsigned short u) {
    unsigned int x = ((unsigned int)u) << 16;
    return __uint_as_float(x);
}

__device__ inline float block_reduce_sum(float v, float* red) {
    for (int o = 32; o > 0; o >>= 1) v += __shfl_down(v, o, 64);
    int nw = blockDim.x >> 6;
    if ((threadIdx.x & 63) == 0) red[threadIdx.x >> 6] = v;
    __syncthreads();
    float r = 0.f;
    for (int w = 0; w < nw; ++w) r += red[w];
    __syncthreads();
    return r;
}

// out[r,:] = table[idx[r],:]  (f32)
__global__ __launch_bounds__(256) void k_gather(const float* __restrict__ tab,
                                                const int* __restrict__ idx,
                                                float* __restrict__ out, int nrows) {
    int e = blockIdx.x * blockDim.x + threadIdx.x;
    if (e >= nrows * 32) return;
    int r = e >> 5, c = e & 31;
    ((float4*)out)[e] = ((const float4*)tab)[(size_t)idx[r] * 32 + c];
}

// out[r,:] = bf16(table[idx[r],:])
__global__ __launch_bounds__(256) void k_gather_bf(const float* __restrict__ tab,
                                                   const int* __restrict__ idx,
                                                   unsigned short* __restrict__ out, int nrows) {
    int e = blockIdx.x * blockDim.x + threadIdx.x;
    if (e >= nrows * 16) return;
    int r = e >> 4, c = e & 15;
    const float4 a = ((const float4*)tab)[(size_t)idx[r] * 32 + c * 2];
    const float4 b = ((const float4*)tab)[(size_t)idx[r] * 32 + c * 2 + 1];
    uint4 u;
    u.x = (unsigned int)to_bf16u(a.x) | ((unsigned int)to_bf16u(a.y) << 16);
    u.y = (unsigned int)to_bf16u(a.z) | ((unsigned int)to_bf16u(a.w) << 16);
    u.z = (unsigned int)to_bf16u(b.x) | ((unsigned int)to_bf16u(b.y) << 16);
    u.w = (unsigned int)to_bf16u(b.z) | ((unsigned int)to_bf16u(b.w) << 16);
    *(uint4*)(out + (size_t)e * 8) = u;
}

// one-time conversion of small weights to bf16, pre-transposed to [n][k]
__global__ __launch_bounds__(256) void k_wcvt(const float* __restrict__ fw1, const float* __restrict__ fw2,
                                              const float* __restrict__ fw3, const float* __restrict__ giw,
                                              const float* __restrict__ gtw, unsigned short* __restrict__ WB) {
    int idx = blockIdx.x * 256 + threadIdx.x;  // 0..131071
    float v;
    if (idx < 16384) {           // fw1b[nb][n=256][k=32]
        int nb = idx >> 13, r = idx & 8191, n = r >> 5, k = r & 31;
        v = fw1[(size_t)nb * 8192 + k * 256 + n];
    } else if (idx < 32768) {    // fw2b (unused now, kept for layout stability)
        int t = idx - 16384;
        int nb = t >> 13, r = t & 8191, n = r >> 8, k = r & 255;
        v = fw2[(size_t)nb * 8192 + k * 32 + n];
    } else if (idx < 65536) {    // fw3b (unused now)
        int t = idx - 32768;
        int nb = t >> 14, r = t & 16383, n = r >> 7, k = r & 127;
        v = fw3[(size_t)nb * 16384 + k * 128 + n];
    } else if (idx < 98304) {    // giwb[hop][n][k]
        int t = idx - 65536;
        int hop = t >> 14, r = t & 16383, n = r >> 7, k = r & 127;
        v = giw[(size_t)hop * 16384 + k * 128 + n];
    } else {                     // gtwb[hop][n][k]
        int t = idx - 98304;
        int hop = t >> 14, r = t & 16383, n = r >> 7, k = r & 127;
        v = gtw[(size_t)hop * 16384 + k * 128 + n];
    }
    WB[idx] = to_bf16u(v);
}

// fold fcb w2@w3 -> MfT[nb][head][h=128][f=256] bf16
__global__ __launch_bounds__(128) void k_mprep(const float* __restrict__ fw2,
                                               const float* __restrict__ fw3,
                                               unsigned short* __restrict__ MfT) {
    int bx = blockIdx.x;                 // nb*1024 + k*256 + f
    int nb = bx >> 10, kk = (bx >> 8) & 3, f = bx & 255;
    int h = threadIdx.x;
    const float* w2p = fw2 + (size_t)nb * 8192 + f * 32;
    const float* w3p = fw3 + (size_t)nb * 16384 + kk * 32 * 128 + h;
    float a = 0.f;
#pragma unroll
    for (int c = 0; c < 32; ++c) a += w2p[c] * w3p[c * 128];
    MfT[(((size_t)nb * 4 + kk) * 128 + h) * 256 + f] = to_bf16u(a);
}

// fused LN + bf16 transpose: V[b][l][h] -> NV f32 (LN'd) + NVT[b][h][lp] bf16 (pad 0)
__global__ __launch_bounds__(128) void k_lnt(const float* __restrict__ V,
                                             const float* __restrict__ g, const float* __restrict__ b,
                                             float* __restrict__ NV, unsigned short* __restrict__ NVT) {
    __shared__ float tl[64][129];
    __shared__ float mrow[64], irow[64];
    int bb = blockIdx.y, l0 = blockIdx.x * 64, tid = threadIdx.x;
    for (int i = tid; i < 2048; i += 128) {
        int r = i >> 5, c = i & 31;
        int l = l0 + r;
        float4 v = {0.f, 0.f, 0.f, 0.f};
        if (l < TL) v = *(const float4*)(V + ((size_t)bb * TL + l) * TH + c * 4);
        tl[r][c * 4 + 0] = v.x; tl[r][c * 4 + 1] = v.y;
        tl[r][c * 4 + 2] = v.z; tl[r][c * 4 + 3] = v.w;
    }
    __syncthreads();
    {
        int row = tid >> 1, half = tid & 1;
        float s = 0.f, sq = 0.f;
        for (int k = 0; k < 64; ++k) {
            float v = tl[row][half * 64 + k];
            s += v; sq += v * v;
        }
        s += __shfl_xor(s, 1);
        sq += __shfl_xor(sq, 1);
        if (half == 0) {
            float mean = s * (1.f / 128.f);
            mrow[row] = mean;
            irow[row] = rsqrtf(sq * (1.f / 128.f) - mean * mean + 1e-8f);
        }
    }
    __syncthreads();
    for (int i = tid; i < 2048; i += 128) {
        int r = i >> 5, c = i & 31;
        int l = l0 + r;
        float4 o = {0.f, 0.f, 0.f, 0.f};
        if (l < TL) {
            float4 v = *(float4*)&tl[r][c * 4];
            float m = mrow[r], inv = irow[r];
            const float4 gg = ((const float4*)g)[c];
            const float4 bv = ((const float4*)b)[c];
            o.x = (v.x - m) * inv * gg.x + bv.x;
            o.y = (v.y - m) * inv * gg.y + bv.y;
            o.z = (v.z - m) * inv * gg.z + bv.z;
            o.w = (v.w - m) * inv * gg.w + bv.w;
            *(float4*)(NV + ((size_t)bb * TL + l) * TH + c * 4) = o;
        }
        *(float4*)&tl[r][c * 4] = o;
    }
    __syncthreads();
    int h = tid;
    int ng = (l0 + 64 > TLP) ? (TLP - l0) / 8 : 8;
    for (int lg = 0; lg < ng; ++lg) {
        uint4 u;
        unsigned int p[4];
#pragma unroll
        for (int q = 0; q < 4; ++q) {
            unsigned short ua = to_bf16u(tl[lg * 8 + q * 2 + 0][h]);
            unsigned short ub = to_bf16u(tl[lg * 8 + q * 2 + 1][h]);
            p[q] = (unsigned int)ua | ((unsigned int)ub << 16);
        }
        u.x = p[0]; u.y = p[1]; u.z = p[2]; u.w = p[3];
        *(uint4*)(NVT + ((size_t)bb * TH + h) * TLP + l0 + lg * 8) = u;
    }
}

// merged scb weight transposes
__global__ __launch_bounds__(256) void k_wscb(const float* __restrict__ w1, const float* __restrict__ w2,
                                              unsigned short* __restrict__ W1T,
                                              unsigned short* __restrict__ W2T) {
    int bx = blockIdx.x;
    if (bx < TSH) {
        int s = bx, l = threadIdx.x;
        if (l < TLP) W1T[(size_t)s * TLP + l] = to_bf16u(l < TL ? w1[(size_t)l * TSH + s] : 0.f);
    } else {
        int l = bx - TSH;   // 0..207
        for (int it = 0; it < 2; ++it) {
            int s = it * 256 + threadIdx.x;
            W2T[(size_t)l * TSH + s] = to_bf16u(l < TL ? w2[(size_t)s * TL + l] : 0.f);
        }
    }
}

// scb GEMM1: T[b][h][s] = gelu( sum_l NVT[b][h][l] * w1[l][s] ); packed T stores
__global__ __launch_bounds__(256) void k_mm1(const unsigned short* __restrict__ NVT,
                                             const unsigned short* __restrict__ W1T,
                                             unsigned short* __restrict__ T, int bh) {
    __shared__ unsigned short As[128][40];
    __shared__ unsigned short Bs[128][40];
    int tid = threadIdx.x;
    int b_local = blockIdx.y, b = bh * 256 + b_local;
    int s0 = blockIdx.x * 128;
    int lane = tid & 63, wid = tid >> 6;
    int mw = wid >> 1, nw = wid & 1;
    f32x4 accT[4][4];   // [j][i]: D[s][h] (swapped operands)
#pragma unroll
    for (int j = 0; j < 4; ++j)
#pragma unroll
        for (int i = 0; i < 4; ++i) accT[j][i] = (f32x4){0.f, 0.f, 0.f, 0.f};
    const unsigned short* Abase = NVT + (size_t)b * TH * TLP;
    const unsigned short* Bbase = W1T + (size_t)s0 * TLP;
    for (int kc = 0; kc < 7; ++kc) {
        __syncthreads();
        for (int i = tid; i < 512; i += 256) {
            int r = i >> 2, q = i & 3;
            *(uint4*)&As[r][q * 8] = *(const uint4*)(Abase + (size_t)r * TLP + kc * 32 + q * 8);
            *(uint4*)&Bs[r][q * 8] = *(const uint4*)(Bbase + (size_t)r * TLP + kc * 32 + q * 8);
        }
        __syncthreads();
        int ko = (lane >> 4) * 8;
        short8v af[4], bfr[4];
#pragma unroll
        for (int t = 0; t < 4; ++t) {
            af[t] = *(const short8v*)&As[mw * 64 + t * 16 + (lane & 15)][ko];
            bfr[t] = *(const short8v*)&Bs[nw * 64 + t * 16 + (lane & 15)][ko];
        }
#pragma unroll
        for (int j = 0; j < 4; ++j)
#pragma unroll
            for (int i = 0; i < 4; ++i)
                accT[j][i] = __builtin_amdgcn_mfma_f32_16x16x32_bf16(bfr[j], af[i], accT[j][i], 0, 0, 0);
    }
    int rbase = (lane >> 4) * 4, col = lane & 15;
#pragma unroll
    for (int i = 0; i < 4; ++i)
#pragma unroll
        for (int j = 0; j < 4; ++j) {
            int h = mw * 64 + i * 16 + col;
            int sb = s0 + nw * 64 + j * 16 + rbase;
            ushort4 pk;
            pk.x = to_bf16u(gelu_fast(accT[j][i][0]));
            pk.y = to_bf16u(gelu_fast(accT[j][i][1]));
            pk.z = to_bf16u(gelu_fast(accT[j][i][2]));
            pk.w = to_bf16u(gelu_fast(accT[j][i][3]));
            *(ushort4*)(T + ((size_t)b_local * TH + h) * TSH + sb) = pk;
        }
}

// scb GEMM2 + fcb LN fused: vs = NV + T@w2; NV <- LN(vs) in place
__global__ __launch_bounds__(256) void k_mm2l(const unsigned short* __restrict__ T,
                                              const unsigned short* __restrict__ W2T,
                                              float* __restrict__ NV,
                                              const float* __restrict__ lg, const float* __restrict__ lb,
                                              int bh) {
    __shared__ unsigned short As[128][40];
    __shared__ unsigned short Bs[64][40];
    __shared__ float vsl[64][132];
    __shared__ float mrow[64], irow[64];
    int tid = threadIdx.x;
    int b_local = blockIdx.y, b = bh * 256 + b_local;
    int l0 = blockIdx.x * 64;
    int lane = tid & 63, wid = tid >> 6;
    f32x4 acc[2][4];
#pragma unroll
    for (int i = 0; i < 2; ++i)
#pragma unroll
        for (int j = 0; j < 4; ++j) acc[i][j] = (f32x4){0.f, 0.f, 0.f, 0.f};
    const unsigned short* Abase = T + (size_t)b_local * TH * TSH;
    for (int kc = 0; kc < 16; ++kc) {
        __syncthreads();
        for (int i = tid; i < 512; i += 256) {
            int r = i >> 2, q = i & 3;
            *(uint4*)&As[r][q * 8] = *(const uint4*)(Abase + (size_t)r * TSH + kc * 32 + q * 8);
        }
        {
            int r = tid >> 2, q = tid & 3;
            int l = l0 + r;
            uint4 v = {0u, 0u, 0u, 0u};
            if (l < 208) v = *(const uint4*)(W2T + (size_t)l * TSH + kc * 32 + q * 8);
            *(uint4*)&Bs[r][q * 8] = v;
        }
        __syncthreads();
        int ko = (lane >> 4) * 8;
        short8v af[2], bfr[4];
#pragma unroll
        for (int t = 0; t < 2; ++t)
            af[t] = *(const short8v*)&As[wid * 32 + t * 16 + (lane & 15)][ko];
#pragma unroll
        for (int j = 0; j < 4; ++j)
            bfr[j] = *(const short8v*)&Bs[j * 16 + (lane & 15)][ko];
#pragma unroll
        for (int i = 0; i < 2; ++i)
#pragma unroll
            for (int j = 0; j < 4; ++j)
                acc[i][j] = __builtin_amdgcn_mfma_f32_16x16x32_bf16(af[i], bfr[j], acc[i][j], 0, 0, 0);
    }
    int rbase = (lane >> 4) * 4, col = lane & 15;
#pragma unroll
    for (int i = 0; i < 2; ++i)
#pragma unroll
        for (int j = 0; j < 4; ++j) {
            int l = l0 + j * 16 + col;
            int h0 = wid * 32 + i * 16 + rbase;
            float4 res = {0.f, 0.f, 0.f, 0.f};
            if (l < TL) res = *(const float4*)(NV + ((size_t)b * TL + l) * TH + h0);
            float4 o;
            o.x = acc[i][j][0] + res.x;
            o.y = acc[i][j][1] + res.y;
            o.z = acc[i][j][2] + res.z;
            o.w = acc[i][j][3] + res.w;
            *(float4*)&vsl[j * 16 + col][h0] = o;
        }
    __syncthreads();
    int row = tid >> 2, q = tid & 3;
    {
        float s = 0.f, sq = 0.f;
        for (int k = 0; k < 32; ++k) {
            float v = vsl[row][q * 32 + k];
            s += v; sq += v * v;
        }
        s += __shfl_xor(s, 1); s += __shfl_xor(s, 2);
        sq += __shfl_xor(sq, 1); sq += __shfl_xor(sq, 2);
        if (q == 0) {
            float mean = s * (1.f / 128.f);
            mrow[row] = mean;
            irow[row] = rsqrtf(sq * (1.f / 128.f) - mean * mean + 1e-8f);
        }
    }
    __syncthreads();
    {
        int l = l0 + row;
        if (l < TL) {
            float mean = mrow[row], inv = irow[row];
            float* dst = NV + ((size_t)b * TL + l) * TH + q * 32;
#pragma unroll
            for (int k4 = 0; k4 < 8; ++k4) {
                float4 v = *(float4*)&vsl[row][q * 32 + k4 * 4];
                const float4 gg = ((const float4*)lg)[q * 8 + k4];
                const float4 bv = ((const float4*)lb)[q * 8 + k4];
                float4 o;
                o.x = (v.x - mean) * inv * gg.x + bv.x;
                o.y = (v.y - mean) * inv * gg.y + bv.y;
                o.z = (v.z - mean) * inv * gg.z + bv.z;
                o.w = (v.w - mean) * inv * gg.w + bv.w;
                *(float4*)(dst + k4 * 4) = o;
            }
        }
    }
}

// full fcb in one kernel: V[m] = sum_head gelu(X_head@w1) @ M_head + X  (X = NV, LN2 out)
__global__ __launch_bounds__(256) void k_ffuse2(const float* __restrict__ NV,
                                                const unsigned short* __restrict__ FW1B,
                                                const unsigned short* __restrict__ MfT,
                                                float* __restrict__ V) {
    __shared__ unsigned short Xb[64 * 136];
    __shared__ unsigned short Yl[64 * 264];
    __shared__ unsigned short Bs2[128 * 40];
    int tid = threadIdx.x;
    int m0 = blockIdx.x * 64;
    int lane = tid & 63, wid = tid >> 6;
    int col = lane & 15, rbase = (lane >> 4) * 4, ko = (lane >> 4) * 8;
    // stage X (64 rows x 128, f32 -> bf16)
    for (int i = tid; i < 2048; i += 256) {
        int r = i >> 5, c = i & 31;
        const float4 v = *(const float4*)(NV + (size_t)(m0 + r) * TH + c * 4);
        ushort4 u;
        u.x = to_bf16u(v.x); u.y = to_bf16u(v.y); u.z = to_bf16u(v.z); u.w = to_bf16u(v.w);
        *(ushort4*)&Xb[r * 136 + c * 4] = u;
    }
    __syncthreads();
    f32x4 acc[8];
#pragma unroll
    for (int t = 0; t < 8; ++t) acc[t] = (f32x4){0.f, 0.f, 0.f, 0.f};
    int mrow = wid * 16 + col;
    int sw = ((mrow >> 2) & 7) << 3;
    for (int head = 0; head < 4; ++head) {
        // f1: Y_head[64][256] = gelu(X_head @ w1); swapped mfma -> packed Yl stores
        {
            short8v af[4], bfr[4];
#pragma unroll
            for (int i = 0; i < 4; ++i)
                af[i] = *(const short8v*)&Xb[(i * 16 + col) * 136 + head * 32 + ko];
#pragma unroll
            for (int j = 0; j < 4; ++j)
                bfr[j] = *(const short8v*)(FW1B + (size_t)(wid * 64 + j * 16 + col) * 32 + ko);
            f32x4 yt[4][4];
#pragma unroll
            for (int j = 0; j < 4; ++j)
#pragma unroll
                for (int i = 0; i < 4; ++i) yt[j][i] = (f32x4){0.f, 0.f, 0.f, 0.f};
#pragma unroll
            for (int j = 0; j < 4; ++j)
#pragma unroll
                for (int i = 0; i < 4; ++i)
                    yt[j][i] = __builtin_amdgcn_mfma_f32_16x16x32_bf16(bfr[j], af[i], yt[j][i], 0, 0, 0);
#pragma unroll
            for (int i = 0; i < 4; ++i)
#pragma unroll
                for (int j = 0; j < 4; ++j) {
                    int m = i * 16 + col;
                    int n0 = wid * 64 + j * 16 + rbase;
                    ushort4 pk;
                    pk.x = to_bf16u(gelu_fast(yt[j][i][0]));
                    pk.y = to_bf16u(gelu_fast(yt[j][i][1]));
                    pk.z = to_bf16u(gelu_fast(yt[j][i][2]));
                    pk.w = to_bf16u(gelu_fast(yt[j][i][3]));
                    int idx = (m * 264 + n0) ^ (((m >> 2) & 7) << 3);
                    *(ushort4*)&Yl[idx] = pk;
                }
        }
        // f2': acc += Y_head @ M_head  (K=256 in 8 chunks; M chunk staged in LDS)
        for (int kc = 0; kc < 8; ++kc) {
            for (int i = tid; i < 512; i += 256) {
                int r = i >> 2, q = i & 3;
                *(uint4*)&Bs2[r * 40 + q * 8] =
                    *(const uint4*)(MfT + ((size_t)head * 128 + r) * 256 + kc * 32 + q * 8);
            }
            __syncthreads();
            short8v a2 = *(const short8v*)&Yl[(mrow * 264 + kc * 32 + ko) ^ sw];
#pragma unroll
            for (int t = 0; t < 8; ++t) {
                short8v b2 = *(const short8v*)&Bs2[(t * 16 + col) * 40 + ko];
                acc[t] = __builtin_amdgcn_mfma_f32_16x16x32_bf16(b2, a2, acc[t], 0, 0, 0);
            }
            __syncthreads();
        }
    }
    // epilogue: V = acc + X residual (packed float4; acc is D[n][m] so reg walks h)
    int m = m0 + wid * 16 + col;
#pragma unroll
    for (int t = 0; t < 8; ++t) {
        int h0 = t * 16 + rbase;
        const float4 res = *(const float4*)(NV + (size_t)m * TH + h0);
        float4 o;
        o.x = acc[t][0] + res.x;
        o.y = acc[t][1] + res.y;
        o.z = acc[t][2] + res.z;
        o.w = acc[t][3] + res.w;
        *(float4*)(V + (size_t)m * TH + h0) = o;
    }
}

// C bf16 [N,128] = A[N,128](bf16) @ WB[n][k](bf16); packed stores (GAT features)
__global__ __launch_bounds__(256) void k_gmm_bb(const unsigned short* __restrict__ A,
                                                const unsigned short* __restrict__ WB,
                                                unsigned short* __restrict__ C) {
    __shared__ unsigned short As[128][40];
    __shared__ unsigned short Bs[128][40];
    int tid = threadIdx.x;
    int m0 = blockIdx.x * 128;
    int lane = tid & 63, wid = tid >> 6;
    int mw = wid >> 1, nw = wid & 1;
    f32x4 accT[4][4];   // [j][i]: D[n][m]
#pragma unroll
    for (int j = 0; j < 4; ++j)
#pragma unroll
        for (int i = 0; i < 4; ++i) accT[j][i] = (f32x4){0.f, 0.f, 0.f, 0.f};
    for (int kc = 0; kc < 4; ++kc) {
        __syncthreads();
        for (int i = tid; i < 512; i += 256) {
            int r = i >> 2, q = i & 3;
            *(uint4*)&As[r][q * 8] = *(const uint4*)(A + (size_t)(m0 + r) * TH + kc * 32 + q * 8);
            *(uint4*)&Bs[r][q * 8] = *(const uint4*)(WB + (size_t)r * TH + kc * 32 + q * 8);
        }
        __syncthreads();
        int ko = (lane >> 4) * 8;
        short8v af[4], bfr[4];
#pragma unroll
        for (int t = 0; t < 4; ++t) {
            af[t] = *(const short8v*)&As[mw * 64 + t * 16 + (lane & 15)][ko];
            bfr[t] = *(const short8v*)&Bs[nw * 64 + t * 16 + (lane & 15)][ko];
        }
#pragma unroll
        for (int j = 0; j < 4; ++j)
#pragma unroll
            for (int i = 0; i < 4; ++i)
                accT[j][i] = __builtin_amdgcn_mfma_f32_16x16x32_bf16(bfr[j], af[i], accT[j][i], 0, 0, 0);
    }
    int rbase = (lane >> 4) * 4, col = lane & 15;
#pragma unroll
    for (int i = 0; i < 4; ++i)
#pragma unroll
        for (int j = 0; j < 4; ++j) {
            int m = m0 + mw * 64 + i * 16 + col;
            int n0 = nw * 64 + j * 16 + rbase;
            ushort4 pk;
            pk.x = to_bf16u(accT[j][i][0]);
            pk.y = to_bf16u(accT[j][i][1]);
            pk.z = to_bf16u(accT[j][i][2]);
            pk.w = to_bf16u(accT[j][i][3]);
            *(ushort4*)(C + (size_t)m * TH + n0) = pk;
        }
}

// alpha = softmax(V@wv over L); g = sum_l alpha*V
__global__ __launch_bounds__(256) void k_pool(const float* __restrict__ V, const float* __restrict__ wv,
                                              float* __restrict__ g) {
    __shared__ float sc[TL];
    __shared__ float red[4];
    int b = blockIdx.x, tid = threadIdx.x;
    if (tid < TL) {
        float a = 0.f;
        const float* vp = V + (size_t)(b * TL + tid) * TH;
        for (int h = 0; h < TH; ++h) a += vp[h] * wv[h];
        sc[tid] = a;
    }
    __syncthreads();
    float m = (tid < TL) ? sc[tid] : -INFINITY;
    for (int o = 32; o > 0; o >>= 1) m = fmaxf(m, __shfl_down(m, o, 64));
    if ((tid & 63) == 0) red[tid >> 6] = m;
    __syncthreads();
    m = fmaxf(fmaxf(red[0], red[1]), fmaxf(red[2], red[3]));
    __syncthreads();
    float e = (tid < TL) ? expf(sc[tid] - m) : 0.f;
    float s = block_reduce_sum(e, red);
    if (tid < TL) sc[tid] = e / s;
    __syncthreads();
    if (tid < TH) {
        float a = 0.f;
        for (int l = 0; l < TL; ++l) a += sc[l] * V[(size_t)(b * TL + l) * TH + tid];
        g[b * TH + tid] = a;
    }
}

// merged 4x scores over bf16 features
__global__ __launch_bounds__(256) void k_scores4(
        const unsigned short* __restrict__ f0, const float* __restrict__ v0, float* __restrict__ o0, int n0,
        const unsigned short* __restrict__ f1, const float* __restrict__ v1, float* __restrict__ o1, int n1,
        const unsigned short* __restrict__ f2, const float* __restrict__ v2, float* __restrict__ o2, int n2,
        const unsigned short* __restrict__ f3, const float* __restrict__ v3, float* __restrict__ o3, int n3) {
    int t = blockIdx.x * 256 + threadIdx.x;
    const unsigned short* f; const float* vec; float* o;
    if (t < n0 * 4) { f = f0; vec = v0; o = o0; }
    else {
        t -= n0 * 4;
        if (t < n1 * 4) { f = f1; vec = v1; o = o1; }
        else {
            t -= n1 * 4;
            if (t < n2 * 4) { f = f2; vec = v2; o = o2; }
            else {
                t -= n2 * 4;
                if (t >= n3 * 4) return;
                f = f3; vec = v3; o = o3;
            }
        }
    }
    int node = t >> 2, k = t & 3;
    const unsigned short* fp = f + (size_t)node * TH + k * TD;
    const float* vp = vec + k * TD;
    float a = 0.f;
#pragma unroll
    for (int q = 0; q < 4; ++q) {
        uint4 u = *(const uint4*)(fp + q * 8);
        unsigned int ws[4] = {u.x, u.y, u.z, u.w};
#pragma unroll
        for (int p = 0; p < 4; ++p) {
            a += __uint_as_float(ws[p] << 16) * vp[q * 8 + p * 2];
            a += __uint_as_float(ws[p] & 0xffff0000u) * vp[q * 8 + p * 2 + 1];
        }
    }
    o[t] = a;
}

// fused per-dst-node GAT; cur bf16, fs bf16, nxt bf16 out, ACC f32
__global__ __launch_bounds__(128) void k_gat(const unsigned short* __restrict__ tax_cur,
                                             const unsigned short* __restrict__ fs_i, const float* __restrict__ el_i,
                                             const float* __restrict__ er_i, const int* __restrict__ src_i,
                                             const float* __restrict__ bi,
                                             const unsigned short* __restrict__ fs_t, const float* __restrict__ el_t,
                                             const float* __restrict__ er_t, const int* __restrict__ src_t,
                                             const float* __restrict__ bt,
                                             unsigned short* __restrict__ tax_nxt,
                                             float* __restrict__ acc, int hop) {
    int n = blockIdx.x, h = threadIdx.x, k = h >> 5;
    float cur = bfu_to_f(tax_cur[(size_t)n * TH + h]);
    float ti, tt2;
    {
        float er = er_i[n * 4 + k];
        int s[4]; float e[4]; float m = -INFINITY;
#pragma unroll
        for (int j = 0; j < 4; ++j) {
            s[j] = src_i[n * 4 + j];
            float xx = el_i[s[j] * 4 + k] + er;
            e[j] = xx > 0.f ? xx : 0.2f * xx;
            m = fmaxf(m, e[j]);
        }
        float ssum = 0.f, av = 0.f;
#pragma unroll
        for (int j = 0; j < 4; ++j) {
            float a = expf(e[j] - m);
            ssum += a;
            av += a * bfu_to_f(fs_i[(size_t)s[j] * TH + h]);
        }
        ti = fmaxf(av / ssum + cur + bi[h], 0.f);
    }
    {
        float er = er_t[n * 4 + k];
        int s[2]; float e[2]; float m = -INFINITY;
#pragma unroll
        for (int j = 0; j < 2; ++j) {
            s[j] = src_t[n * 2 + j];
            float xx = el_t[s[j] * 4 + k] + er;
            e[j] = xx > 0.f ? xx : 0.2f * xx;
            m = fmaxf(m, e[j]);
        }
        float ssum = 0.f, av = 0.f;
#pragma unroll
        for (int j = 0; j < 2; ++j) {
            float a = expf(e[j] - m);
            ssum += a;
            av += a * bfu_to_f(fs_t[(size_t)s[j] * TH + h]);
        }
        tt2 = fmaxf(av / ssum + cur + bt[h], 0.f);
    }
    float nx = ti + tt2;
    size_t ai = (size_t)n * TH + h;
    tax_nxt[ai] = to_bf16u(nx);
    acc[ai] = (hop == 0) ? nx : acc[ai] + nx;
}

// fused local-gather + mul + LN/softmax/LN + @uni_w -> PB bf16
__global__ __launch_bounds__(128) void k_locfuse(const int* __restrict__ root, const float* __restrict__ acc,
                                                 const float* __restrict__ g,
                                                 const float* __restrict__ liw_g, const float* __restrict__ liw_b,
                                                 const float* __restrict__ int_g, const float* __restrict__ int_b,
                                                 const float* __restrict__ uni_w,
                                                 unsigned short* __restrict__ PB) {
    __shared__ float loc[TFT][TH];
    __shared__ float lm[TFT], wv_[TFT], inten[TH];
    __shared__ float red[2];
    int b = blockIdx.x, tid = threadIdx.x;
    float gv = g[b * TH + tid];
    for (int f = 0; f < TFT; ++f) {
        int r = root[b * TFT + f];
        float v = 0.f;
        if (r != -1) v = acc[(size_t)(b * TTP + (r < 0 ? 0 : r)) * TH + tid] * 0.5f;
        loc[f][tid] = v;
        float s = block_reduce_sum(v * gv, red);
        if (tid == 0) lm[f] = s;
    }
    __syncthreads();
    if (tid < TFT) {
        float mean = 0.f;
        for (int f = 0; f < TFT; ++f) mean += lm[f];
        mean *= (1.f / TFT);
        float var = 0.f;
        for (int f = 0; f < TFT; ++f) { float d = lm[f] - mean; var += d * d; }
        var *= (1.f / TFT);
        float ln = (lm[tid] - mean) * rsqrtf(var + 1e-8f) * liw_g[tid] + liw_b[tid];
        wv_[tid] = (lm[tid] != 0.f) ? ln : -INFINITY;
    }
    __syncthreads();
    if (tid < TFT) {
        float mx = -INFINITY;
        for (int f = 0; f < TFT; ++f) mx = fmaxf(mx, wv_[f]);
        float s = 0.f;
        for (int f = 0; f < TFT; ++f) s += expf(wv_[f] - mx);
        lm[tid] = expf(wv_[tid] - mx) / s;
    }
    __syncthreads();
    float ip = gv;
    for (int f = 0; f < TFT; ++f) ip += lm[f] * loc[f][tid];
    float mean = block_reduce_sum(ip, red) * (1.f / TH);
    float d = ip - mean;
    float var = block_reduce_sum(d * d, red) * (1.f / TH);
    inten[tid] = d * rsqrtf(var + 1e-8f) * int_g[tid] + int_b[tid];
    __syncthreads();
    float a = 0.f;
    for (int hp = 0; hp < TH; ++hp) a += inten[hp] * uni_w[hp * TH + tid];
    PB[(size_t)b * TH + tid] = to_bf16u(a);
}

// E f32 -> EB bf16, rows padded to TIPAD
__global__ __launch_bounds__(256) void k_ebc(const float* __restrict__ E,
                                             unsigned short* __restrict__ EB) {
    int t = blockIdx.x * 256 + threadIdx.x;
    if (t >= TIPAD * TH / 8) return;
    size_t base = (size_t)t * 8;
    int row = (int)(base >> 7);
    float4 a = {0.f, 0.f, 0.f, 0.f}, b = {0.f, 0.f, 0.f, 0.f};
    if (row < TITEMS) {
        a = *(const float4*)(E + base);
        b = *(const float4*)(E + base + 4);
    }
    ushort4 u0, u1;
    u0.x = to_bf16u(a.x); u0.y = to_bf16u(a.y); u0.z = to_bf16u(a.z); u0.w = to_bf16u(a.w);
    u1.x = to_bf16u(b.x); u1.y = to_bf16u(b.y); u1.z = to_bf16u(b.z); u1.w = to_bf16u(b.w);
    *(ushort4*)(EB + base) = u0;
    *(ushort4*)(EB + base + 4) = u1;
}

// out[b,i] = PB[b,:] . EB[i,:]  (bf16 MFMA; A-frags direct from global PB)
__global__ __launch_bounds__(256) void k_final_m(const unsigned short* __restrict__ PB,
                                                 const unsigned short* __restrict__ EB,
                                                 float* __restrict__ out) {
    __shared__ unsigned short Bs[128][136];
    int tid = threadIdx.x;
    int i0 = blockIdx.x * 128, b0 = blockIdx.y * 128;
    for (int i = tid; i < 2048; i += 256) {
        int r = i >> 4, q = i & 15;
        *(uint4*)&Bs[r][q * 8] = *(const uint4*)(EB + (size_t)(i0 + r) * TH + q * 8);
    }
    __syncthreads();
    int lane = tid & 63, wid = tid >> 6;
    int mw = wid >> 1, nw = wid & 1;
    f32x4 acc[4][4];
#pragma unroll
    for (int i = 0; i < 4; ++i)
#pragma unroll
        for (int j = 0; j < 4; ++j) acc[i][j] = (f32x4){0.f, 0.f, 0.f, 0.f};
#pragma unroll
    for (int kc = 0; kc < 4; ++kc) {
        int ko = kc * 32 + (lane >> 4) * 8;
        short8v af[4], bfr[4];
#pragma unroll
        for (int t = 0; t < 4; ++t) {
            af[t] = *(const short8v*)(PB + (size_t)(b0 + mw * 64 + t * 16 + (lane & 15)) * TH + ko);
            bfr[t] = *(const short8v*)&Bs[nw * 64 + t * 16 + (lane & 15)][ko];
        }
#pragma unroll
        for (int i = 0; i < 4; ++i)
#pragma unroll
            for (int j = 0; j < 4; ++j)
                acc[i][j] = __builtin_amdgcn_mfma_f32_16x16x32_bf16(af[i], bfr[j], acc[i][j], 0, 0, 0);
    }
    int rbase = (lane >> 4) * 4, col = lane & 15;
#pragma unroll
    for (int i = 0; i < 4; ++i)
#pragma unroll
        for (int j = 0; j < 4; ++j) {
            int ii = i0 + nw * 64 + j * 16 + col;
            if (ii < TITEMS) {
#pragma unroll
                for (int r = 0; r < 4; ++r)
                    out[(size_t)(b0 + mw * 64 + i * 16 + rbase + r) * TITEMS + ii] = acc[i][j][r];
            }
        }
}

extern "C" void kernel_launch(void* const* d_in, const int* in_sizes, int n_in,
                              void* d_out, int out_size, void* d_ws, size_t ws_size,
                              hipStream_t stream) {
    const int*   seq        = (const int*)d_in[0];
    const int*   root       = (const int*)d_in[1];
    const int*   i2t_src    = (const int*)d_in[3];
    const int*   t2t_src    = (const int*)d_in[5];
    const int*   item_ids   = (const int*)d_in[6];
    const int*   tax_ids    = (const int*)d_in[7];
    const float* item_embed = (const float*)d_in[8];
    const float* tax_embed  = (const float*)d_in[9];
    const float* scb_ln_g   = (const float*)d_in[10];
    const float* scb_ln_b   = (const float*)d_in[11];
    const float* scb_w1     = (const float*)d_in[12];
    const float* scb_w2     = (const float*)d_in[13];
    const float* fcb_ln_g   = (const float*)d_in[14];
    const float* fcb_ln_b   = (const float*)d_in[15];
    const float* fcb_w1     = (const float*)d_in[16];
    const float* fcb_w2     = (const float*)d_in[17];
    const float* fcb_w3     = (const float*)d_in[18];
    const float* wv         = (const float*)d_in[19];
    const float* gi_w       = (const float*)d_in[20];
    const float* gi_al      = (const float*)d_in[21];
    const float* gi_ar      = (const float*)d_in[22];
    const float* gi_b       = (const float*)d_in[23];
    const float* gt_w       = (const float*)d_in[24];
    const float* gt_al      = (const float*)d_in[25];
    const float* gt_ar      = (const float*)d_in[26];
    const float* gt_b       = (const float*)d_in[27];
    const float* liw_g      = (const float*)d_in[28];
    const float* liw_b      = (const float*)d_in[29];
    const float* int_g      = (const float*)d_in[30];
    const float* int_b      = (const float*)d_in[31];
    const float* uni_w      = (const float*)d_in[32];

    char* w = (char*)d_ws;
    float* V     = (float*)(w + 0);           // 52.4MB (V / FSIB)
    float* NV    = (float*)(w + 52428800);    // 52.4MB (nv / ITEMHB)
    unsigned short* FSIB   = (unsigned short*)(w + 0);
    unsigned short* ITEMHB = (unsigned short*)(w + 52428800);
    // mixer-scb phase:
    unsigned short* NVT = (unsigned short*)(w + 104857600);  // 29.4MB
    unsigned short* T   = (unsigned short*)(w + 134217728);  // 33.6MB
    unsigned short* W1T = (unsigned short*)(w + 167772160);  // 229KB
    unsigned short* W2T = (unsigned short*)(w + 168001536);  // 213KB -> ends 168214528
    unsigned short* MfT = (unsigned short*)(w + 168230912);  // 512KB (2 nb), mixer phase only
    // GAT phase:
    unsigned short* TAXB0 = (unsigned short*)(w + 104857600);
    unsigned short* TAXB1 = (unsigned short*)(w + 113246208);
    float* ACC   = (float*)(w + 138412032);
    unsigned short* FDIB = (unsigned short*)(w + 155189248);
    unsigned short* FSTB = (unsigned short*)(w + 171966464);
    float* ELI   = (float*)(w + 188743680);
    float* ERI   = (float*)(w + 190382080);
    float* ELT   = (float*)(w + 190906368);
    float* ERT   = (float*)(w + 191430656);
    float* G     = (float*)(w + 200343552);
    unsigned short* WB = (unsigned short*)(w + 191954944);   // 262KB converted weights
    // final phase:
    unsigned short* EB = (unsigned short*)(w + 155189248);   // 25.6MB (aliases FDIB+FSTB+MfT, dead)
    unsigned short* PB = (unsigned short*)(w + 200671232);   // 128KB
    if (ws_size < 200933376ull) return;

    // one-time conversions
    k_wcvt<<<512, 256, 0, stream>>>(fcb_w1, fcb_w2, fcb_w3, gi_w, gt_w, WB);
    k_mprep<<<2048, 128, 0, stream>>>(fcb_w2, fcb_w3, MfT);

    // ---- global intention (mixer) ----
    k_gather<<<(TB * TL * 32 + 255) / 256, 256, 0, stream>>>(item_embed, seq, V, TB * TL);
    for (int nb = 0; nb < 2; ++nb) {
        k_lnt<<<dim3(4, TB), 128, 0, stream>>>(V, scb_ln_g + nb * TH, scb_ln_b + nb * TH, NV, NVT);
        k_wscb<<<720, 256, 0, stream>>>(scb_w1 + nb * TL * TSH, scb_w2 + nb * TSH * TL, W1T, W2T);
        for (int bh = 0; bh < 2; ++bh) {
            k_mm1<<<dim3(4, 256), 256, 0, stream>>>(NVT, W1T, T, bh);
            k_mm2l<<<dim3(4, 256), 256, 0, stream>>>(T, W2T, NV,
                                                     fcb_ln_g + nb * TH, fcb_ln_b + nb * TH, bh);
        }
        // full fcb in one kernel (w2@w3 folded into MfT)
        k_ffuse2<<<TB * TL / 64, 256, 0, stream>>>(NV, WB + nb * 8192,
                                                   MfT + (size_t)nb * 131072, V);
    }
    k_pool<<<TB, 256, 0, stream>>>(V, wv, G);

    // ---- local intention (GAT, bf16 features) ----
    k_gather_bf<<<(TNI * 16 + 255) / 256, 256, 0, stream>>>(item_embed, item_ids, ITEMHB, TNI);
    k_gather_bf<<<(TNT * 16 + 255) / 256, 256, 0, stream>>>(tax_embed, tax_ids, TAXB0, TNT);

    unsigned short* curb = TAXB0;
    unsigned short* nxtb = TAXB1;
    for (int hop = 0; hop < 2; ++hop) {
        const unsigned short* WiB = WB + 65536 + hop * 16384;
        const unsigned short* WtB = WB + 98304 + hop * 16384;
        k_gmm_bb<<<TNI / 128, 256, 0, stream>>>(ITEMHB, WiB, FSIB);
        k_gmm_bb<<<TNT / 128, 256, 0, stream>>>(curb, WiB, FDIB);
        k_gmm_bb<<<TNT / 128, 256, 0, stream>>>(curb, WtB, FSTB);
        int total = (TNI + 3 * TNT) * TNH;
        k_scores4<<<(total + 255) / 256, 256, 0, stream>>>(
            FSIB, gi_al + hop * TH, ELI, TNI,
            FDIB, gi_ar + hop * TH, ERI, TNT,
            FSTB, gt_al + hop * TH, ELT, TNT,
            FSTB, gt_ar + hop * TH, ERT, TNT);
        k_gat<<<TNT, 128, 0, stream>>>(curb, FSIB, ELI, ERI, i2t_src, gi_b + hop * TH,
                                       FSTB, ELT, ERT, t2t_src, gt_b + hop * TH, nxtb, ACC, hop);
        unsigned short* tmp = curb; curb = nxtb; nxtb = tmp;
    }

    // ---- fuse + final ----
    k_locfuse<<<TB, 128, 0, stream>>>(root, ACC, G, liw_g, liw_b, int_g, int_b, uni_w, PB);
    k_ebc<<<(TIPAD * TH / 8 + 255) / 256, 256, 0, stream>>>(item_embed, EB);
    k_final_m<<<dim3(TIPAD / 128, TB / 128), 256, 0, stream>>>(PB, EB, (float*)d_out);
}

// Round 12
// 1027.937 us; speedup vs baseline: 1.0525x; 1.0525x over previous
//
#include <hip/hip_runtime.h>
#include <hip/hip_bf16.h>

// ---- model dims ----
constexpr int TB = 512, TL = 200, TH = 128, TNH = 4, TD = 32;
constexpr int TFT = 32, TTP = 64, TIP = 200;
constexpr int TSH = 512, TFH = 256;
constexpr int TITEMS = 100001;
constexpr int TNT = TB * TTP;   // 32768
constexpr int TNI = TB * TIP;   // 102400
constexpr int TLP = 224;        // L padded (K of scb GEMM1)
constexpr int TIPAD = 100096;   // items padded to 128

typedef __attribute__((ext_vector_type(8))) short short8v;
typedef __attribute__((ext_vector_type(4))) float f32x4;

// tanh-form gelu, |err| <= ~3e-4 (below bf16 quantization of the result)
__device__ inline float gelu_fast(float x) {
    float u = x + 0.044715f * x * x * x;
    float e = exp2f(-2.302208f * u);
    return x / (1.0f + e);
}
__device__ inline unsigned short to_bf16u(float x) {
    __hip_bfloat16 h = __float2bfloat16(x);
    return *reinterpret_cast<unsigned short*>(&h);
}
__device__ inline float bfu_to_f(unsigned short u) {
    unsigned int x = ((unsigned int)u) << 16;
    return __uint_as_float(x);
}

__device__ inline float block_reduce_sum(float v, float* red) {
    for (int o = 32; o > 0; o >>= 1) v += __shfl_down(v, o, 64);
    int nw = blockDim.x >> 6;
    if ((threadIdx.x & 63) == 0) red[threadIdx.x >> 6] = v;
    __syncthreads();
    float r = 0.f;
    for (int w = 0; w < nw; ++w) r += red[w];
    __syncthreads();
    return r;
}

// out[r,:] = bf16(table[idx[r],:])
__global__ __launch_bounds__(256) void k_gather_bf(const float* __restrict__ tab,
                                                   const int* __restrict__ idx,
                                                   unsigned short* __restrict__ out, int nrows) {
    int e = blockIdx.x * blockDim.x + threadIdx.x;
    if (e >= nrows * 16) return;
    int r = e >> 4, c = e & 15;
    const float4 a = ((const float4*)tab)[(size_t)idx[r] * 32 + c * 2];
    const float4 b = ((const float4*)tab)[(size_t)idx[r] * 32 + c * 2 + 1];
    uint4 u;
    u.x = (unsigned int)to_bf16u(a.x) | ((unsigned int)to_bf16u(a.y) << 16);
    u.y = (unsigned int)to_bf16u(a.z) | ((unsigned int)to_bf16u(a.w) << 16);
    u.z = (unsigned int)to_bf16u(b.x) | ((unsigned int)to_bf16u(b.y) << 16);
    u.w = (unsigned int)to_bf16u(b.z) | ((unsigned int)to_bf16u(b.w) << 16);
    *(uint4*)(out + (size_t)e * 8) = u;
}

// one-time conversion of small weights to bf16, pre-transposed to [n][k]
__global__ __launch_bounds__(256) void k_wcvt(const float* __restrict__ fw1, const float* __restrict__ fw2,
                                              const float* __restrict__ fw3, const float* __restrict__ giw,
                                              const float* __restrict__ gtw, unsigned short* __restrict__ WB) {
    int idx = blockIdx.x * 256 + threadIdx.x;  // 0..131071
    float v;
    if (idx < 16384) {           // fw1b[nb][n=256][k=32]
        int nb = idx >> 13, r = idx & 8191, n = r >> 5, k = r & 31;
        v = fw1[(size_t)nb * 8192 + k * 256 + n];
    } else if (idx < 32768) {    // fw2b[nb][n=32][k=256]
        int t = idx - 16384;
        int nb = t >> 13, r = t & 8191, n = r >> 8, k = r & 255;
        v = fw2[(size_t)nb * 8192 + k * 32 + n];
    } else if (idx < 65536) {    // fw3b[nb][n=128][k=128]
        int t = idx - 32768;
        int nb = t >> 14, r = t & 16383, n = r >> 7, k = r & 127;
        v = fw3[(size_t)nb * 16384 + k * 128 + n];
    } else if (idx < 98304) {    // giwb[hop][n][k]
        int t = idx - 65536;
        int hop = t >> 14, r = t & 16383, n = r >> 7, k = r & 127;
        v = giw[(size_t)hop * 16384 + k * 128 + n];
    } else {                     // gtwb[hop][n][k]
        int t = idx - 98304;
        int hop = t >> 14, r = t & 16383, n = r >> 7, k = r & 127;
        v = gtw[(size_t)hop * 16384 + k * 128 + n];
    }
    WB[idx] = to_bf16u(v);
}

// fused [gather +] LN + bf16 transpose: src -> NV f32 (LN'd) + NVT[b][h][lp] bf16
__global__ __launch_bounds__(128) void k_lnt(const float* __restrict__ V,
                                             const int* __restrict__ seqp, const float* __restrict__ tab,
                                             const float* __restrict__ g, const float* __restrict__ b,
                                             float* __restrict__ NV, unsigned short* __restrict__ NVT) {
    __shared__ float tl[64][129];
    __shared__ float mrow[64], irow[64];
    int bb = blockIdx.y, l0 = blockIdx.x * 64, tid = threadIdx.x;
    for (int i = tid; i < 2048; i += 128) {
        int r = i >> 5, c = i & 31;
        int l = l0 + r;
        float4 v = {0.f, 0.f, 0.f, 0.f};
        if (l < TL) {
            const float* src = seqp ? (tab + (size_t)seqp[bb * TL + l] * TH)
                                    : (V + ((size_t)bb * TL + l) * TH);
            v = *(const float4*)(src + c * 4);
        }
        tl[r][c * 4 + 0] = v.x; tl[r][c * 4 + 1] = v.y;
        tl[r][c * 4 + 2] = v.z; tl[r][c * 4 + 3] = v.w;
    }
    __syncthreads();
    {
        int row = tid >> 1, half = tid & 1;
        float s = 0.f, sq = 0.f;
        for (int k = 0; k < 64; ++k) {
            float v = tl[row][half * 64 + k];
            s += v; sq += v * v;
        }
        s += __shfl_xor(s, 1);
        sq += __shfl_xor(sq, 1);
        if (half == 0) {
            float mean = s * (1.f / 128.f);
            mrow[row] = mean;
            irow[row] = rsqrtf(sq * (1.f / 128.f) - mean * mean + 1e-8f);
        }
    }
    __syncthreads();
    for (int i = tid; i < 2048; i += 128) {
        int r = i >> 5, c = i & 31;
        int l = l0 + r;
        float4 o = {0.f, 0.f, 0.f, 0.f};
        if (l < TL) {
            float4 v = *(float4*)&tl[r][c * 4];
            float m = mrow[r], inv = irow[r];
            const float4 gg = ((const float4*)g)[c];
            const float4 bv = ((const float4*)b)[c];
            o.x = (v.x - m) * inv * gg.x + bv.x;
            o.y = (v.y - m) * inv * gg.y + bv.y;
            o.z = (v.z - m) * inv * gg.z + bv.z;
            o.w = (v.w - m) * inv * gg.w + bv.w;
            *(float4*)(NV + ((size_t)bb * TL + l) * TH + c * 4) = o;
        }
        *(float4*)&tl[r][c * 4] = o;
    }
    __syncthreads();
    int h = tid;
    int ng = (l0 + 64 > TLP) ? (TLP - l0) / 8 : 8;
    for (int lg = 0; lg < ng; ++lg) {
        uint4 u;
        unsigned int p[4];
#pragma unroll
        for (int q = 0; q < 4; ++q) {
            unsigned short ua = to_bf16u(tl[lg * 8 + q * 2 + 0][h]);
            unsigned short ub = to_bf16u(tl[lg * 8 + q * 2 + 1][h]);
            p[q] = (unsigned int)ua | ((unsigned int)ub << 16);
        }
        u.x = p[0]; u.y = p[1]; u.z = p[2]; u.w = p[3];
        *(uint4*)(NVT + ((size_t)bb * TH + h) * TLP + l0 + lg * 8) = u;
    }
}

// merged scb weight transposes
__global__ __launch_bounds__(256) void k_wscb(const float* __restrict__ w1, const float* __restrict__ w2,
                                              unsigned short* __restrict__ W1T,
                                              unsigned short* __restrict__ W2T) {
    int bx = blockIdx.x;
    if (bx < TSH) {
        int s = bx, l = threadIdx.x;
        if (l < TLP) W1T[(size_t)s * TLP + l] = to_bf16u(l < TL ? w1[(size_t)l * TSH + s] : 0.f);
    } else {
        int l = bx - TSH;   // 0..207
        for (int it = 0; it < 2; ++it) {
            int s = it * 256 + threadIdx.x;
            W2T[(size_t)l * TSH + s] = to_bf16u(l < TL ? w2[(size_t)s * TL + l] : 0.f);
        }
    }
}

// scb GEMM1: T[b][h][s] = gelu( sum_l NVT[b][h][l] * w1[l][s] ); packed T stores
__global__ __launch_bounds__(256) void k_mm1(const unsigned short* __restrict__ NVT,
                                             const unsigned short* __restrict__ W1T,
                                             unsigned short* __restrict__ T, int bh) {
    __shared__ unsigned short As[128][40];
    __shared__ unsigned short Bs[128][40];
    int tid = threadIdx.x;
    int b_local = blockIdx.y, b = bh * 256 + b_local;
    int s0 = blockIdx.x * 128;
    int lane = tid & 63, wid = tid >> 6;
    int mw = wid >> 1, nw = wid & 1;
    f32x4 accT[4][4];   // [j][i]: D[s][h] (swapped operands)
#pragma unroll
    for (int j = 0; j < 4; ++j)
#pragma unroll
        for (int i = 0; i < 4; ++i) accT[j][i] = (f32x4){0.f, 0.f, 0.f, 0.f};
    const unsigned short* Abase = NVT + (size_t)b * TH * TLP;
    const unsigned short* Bbase = W1T + (size_t)s0 * TLP;
    for (int kc = 0; kc < 7; ++kc) {
        __syncthreads();
        for (int i = tid; i < 512; i += 256) {
            int r = i >> 2, q = i & 3;
            *(uint4*)&As[r][q * 8] = *(const uint4*)(Abase + (size_t)r * TLP + kc * 32 + q * 8);
            *(uint4*)&Bs[r][q * 8] = *(const uint4*)(Bbase + (size_t)r * TLP + kc * 32 + q * 8);
        }
        __syncthreads();
        int ko = (lane >> 4) * 8;
        short8v af[4], bfr[4];
#pragma unroll
        for (int t = 0; t < 4; ++t) {
            af[t] = *(const short8v*)&As[mw * 64 + t * 16 + (lane & 15)][ko];
            bfr[t] = *(const short8v*)&Bs[nw * 64 + t * 16 + (lane & 15)][ko];
        }
#pragma unroll
        for (int j = 0; j < 4; ++j)
#pragma unroll
            for (int i = 0; i < 4; ++i)
                accT[j][i] = __builtin_amdgcn_mfma_f32_16x16x32_bf16(bfr[j], af[i], accT[j][i], 0, 0, 0);
    }
    int rbase = (lane >> 4) * 4, col = lane & 15;
#pragma unroll
    for (int i = 0; i < 4; ++i)
#pragma unroll
        for (int j = 0; j < 4; ++j) {
            int h = mw * 64 + i * 16 + col;
            int sb = s0 + nw * 64 + j * 16 + rbase;
            ushort4 pk;
            pk.x = to_bf16u(gelu_fast(accT[j][i][0]));
            pk.y = to_bf16u(gelu_fast(accT[j][i][1]));
            pk.z = to_bf16u(gelu_fast(accT[j][i][2]));
            pk.w = to_bf16u(gelu_fast(accT[j][i][3]));
            *(ushort4*)(T + ((size_t)b_local * TH + h) * TSH + sb) = pk;
        }
}

// scb GEMM2 + fcb LN fused: vs = NV + T@w2; NV <- LN(vs) in place
__global__ __launch_bounds__(256) void k_mm2l(const unsigned short* __restrict__ T,
                                              const unsigned short* __restrict__ W2T,
                                              float* __restrict__ NV,
                                              const float* __restrict__ lg, const float* __restrict__ lb,
                                              int bh) {
    __shared__ unsigned short As[128][40];
    __shared__ unsigned short Bs[64][40];
    __shared__ float vsl[64][132];
    __shared__ float mrow[64], irow[64];
    int tid = threadIdx.x;
    int b_local = blockIdx.y, b = bh * 256 + b_local;
    int l0 = blockIdx.x * 64;
    int lane = tid & 63, wid = tid >> 6;
    f32x4 acc[2][4];
#pragma unroll
    for (int i = 0; i < 2; ++i)
#pragma unroll
        for (int j = 0; j < 4; ++j) acc[i][j] = (f32x4){0.f, 0.f, 0.f, 0.f};
    const unsigned short* Abase = T + (size_t)b_local * TH * TSH;
    for (int kc = 0; kc < 16; ++kc) {
        __syncthreads();
        for (int i = tid; i < 512; i += 256) {
            int r = i >> 2, q = i & 3;
            *(uint4*)&As[r][q * 8] = *(const uint4*)(Abase + (size_t)r * TSH + kc * 32 + q * 8);
        }
        {
            int r = tid >> 2, q = tid & 3;
            int l = l0 + r;
            uint4 v = {0u, 0u, 0u, 0u};
            if (l < 208) v = *(const uint4*)(W2T + (size_t)l * TSH + kc * 32 + q * 8);
            *(uint4*)&Bs[r][q * 8] = v;
        }
        __syncthreads();
        int ko = (lane >> 4) * 8;
        short8v af[2], bfr[4];
#pragma unroll
        for (int t = 0; t < 2; ++t)
            af[t] = *(const short8v*)&As[wid * 32 + t * 16 + (lane & 15)][ko];
#pragma unroll
        for (int j = 0; j < 4; ++j)
            bfr[j] = *(const short8v*)&Bs[j * 16 + (lane & 15)][ko];
#pragma unroll
        for (int i = 0; i < 2; ++i)
#pragma unroll
            for (int j = 0; j < 4; ++j)
                acc[i][j] = __builtin_amdgcn_mfma_f32_16x16x32_bf16(af[i], bfr[j], acc[i][j], 0, 0, 0);
    }
    int rbase = (lane >> 4) * 4, col = lane & 15;
#pragma unroll
    for (int i = 0; i < 2; ++i)
#pragma unroll
        for (int j = 0; j < 4; ++j) {
            int l = l0 + j * 16 + col;
            int h0 = wid * 32 + i * 16 + rbase;
            float4 res = {0.f, 0.f, 0.f, 0.f};
            if (l < TL) res = *(const float4*)(NV + ((size_t)b * TL + l) * TH + h0);
            float4 o;
            o.x = acc[i][j][0] + res.x;
            o.y = acc[i][j][1] + res.y;
            o.z = acc[i][j][2] + res.z;
            o.w = acc[i][j][3] + res.w;
            *(float4*)&vsl[j * 16 + col][h0] = o;
        }
    __syncthreads();
    int row = tid >> 2, q = tid & 3;
    {
        float s = 0.f, sq = 0.f;
        for (int k = 0; k < 32; ++k) {
            float v = vsl[row][q * 32 + k];
            s += v; sq += v * v;
        }
        s += __shfl_xor(s, 1); s += __shfl_xor(s, 2);
        sq += __shfl_xor(sq, 1); sq += __shfl_xor(sq, 2);
        if (q == 0) {
            float mean = s * (1.f / 128.f);
            mrow[row] = mean;
            irow[row] = rsqrtf(sq * (1.f / 128.f) - mean * mean + 1e-8f);
        }
    }
    __syncthreads();
    {
        int l = l0 + row;
        if (l < TL) {
            float mean = mrow[row], inv = irow[row];
            float* dst = NV + ((size_t)b * TL + l) * TH + q * 32;
#pragma unroll
            for (int k4 = 0; k4 < 8; ++k4) {
                float4 v = *(float4*)&vsl[row][q * 32 + k4 * 4];
                const float4 gg = ((const float4*)lg)[q * 8 + k4];
                const float4 bv = ((const float4*)lb)[q * 8 + k4];
                float4 o;
                o.x = (v.x - mean) * inv * gg.x + bv.x;
                o.y = (v.y - mean) * inv * gg.y + bv.y;
                o.z = (v.z - mean) * inv * gg.z + bv.z;
                o.w = (v.w - mean) * inv * gg.w + bv.w;
                *(float4*)(dst + k4 * 4) = o;
            }
        }
    }
}

// fused fcb stage1+2; packed swizzled Yl stores (swapped-operand f1)
__global__ __launch_bounds__(256) void k_ffuse(const float* __restrict__ NV,
                                               const unsigned short* __restrict__ FW1B,
                                               const unsigned short* __restrict__ FW2B,
                                               unsigned short* __restrict__ Z) {
    __shared__ unsigned short As[64][40];
    __shared__ unsigned short BsBuf[256 * 40];     // f1: [256][40]; f2: [32][264]
    __shared__ unsigned short Yl[64 * 264];
    int tid = threadIdx.x;
    int m0 = blockIdx.x * 64;   // rows-of-32
    int lane = tid & 63, wid = tid >> 6;
    int col = lane & 15, rbase = (lane >> 4) * 4, ko = (lane >> 4) * 8;
    for (int i = tid; i < 512; i += 256) {
        int r = i >> 3, q = i & 7;
        const float4 v = *(const float4*)(NV + (size_t)(m0 + r) * 32 + q * 4);
        ushort4 u;
        u.x = to_bf16u(v.x); u.y = to_bf16u(v.y); u.z = to_bf16u(v.z); u.w = to_bf16u(v.w);
        *(ushort4*)&As[r][q * 4] = u;
    }
    for (int i = tid; i < 1024; i += 256) {
        int r = i >> 2, q = i & 3;
        *(uint4*)&BsBuf[r * 40 + q * 8] = *(const uint4*)(FW1B + r * 32 + q * 8);
    }
    __syncthreads();
    // f1 fragment loads (Bs1 dead after this)
    short8v af[4], bfr[4];
#pragma unroll
    for (int t = 0; t < 4; ++t) {
        af[t] = *(const short8v*)&As[t * 16 + col][ko];
        bfr[t] = *(const short8v*)&BsBuf[(wid * 64 + t * 16 + col) * 40 + ko];
    }
    __syncthreads();
    // f1 MFMA (swapped) + gelu + packed swizzled Yl store
    {
        f32x4 yt[4][4];   // [j][i]: D[n][m]
#pragma unroll
        for (int j = 0; j < 4; ++j)
#pragma unroll
            for (int i = 0; i < 4; ++i) yt[j][i] = (f32x4){0.f, 0.f, 0.f, 0.f};
#pragma unroll
        for (int j = 0; j < 4; ++j)
#pragma unroll
            for (int i = 0; i < 4; ++i)
                yt[j][i] = __builtin_amdgcn_mfma_f32_16x16x32_bf16(bfr[j], af[i], yt[j][i], 0, 0, 0);
#pragma unroll
        for (int i = 0; i < 4; ++i)
#pragma unroll
            for (int j = 0; j < 4; ++j) {
                int m = i * 16 + col;
                int n0 = wid * 64 + j * 16 + rbase;
                ushort4 pk;
                pk.x = to_bf16u(gelu_fast(yt[j][i][0]));
                pk.y = to_bf16u(gelu_fast(yt[j][i][1]));
                pk.z = to_bf16u(gelu_fast(yt[j][i][2]));
                pk.w = to_bf16u(gelu_fast(yt[j][i][3]));
                int idx = (m * 264 + n0) ^ (((m >> 2) & 7) << 3);
                *(ushort4*)&Yl[idx] = pk;
            }
    }
    // stage B2: FW2B[32][256] -> BsBuf[n'][k] stride 264
    for (int i = tid; i < 1024; i += 256) {
        int r = i >> 5, q = i & 31;
        *(uint4*)&BsBuf[r * 264 + q * 8] = *(const uint4*)(FW2B + r * 256 + q * 8);
    }
    __syncthreads();
    // f2: Z[m][n'] = Y @ W2, K=256
    {
        f32x4 acc2[2];
        acc2[0] = (f32x4){0.f, 0.f, 0.f, 0.f};
        acc2[1] = (f32x4){0.f, 0.f, 0.f, 0.f};
        int mrow = wid * 16 + col;
        int sw = ((mrow >> 2) & 7) << 3;
        for (int kc = 0; kc < 8; ++kc) {
            int ko2 = kc * 32 + ko;
            short8v a2 = *(const short8v*)&Yl[(mrow * 264 + ko2) ^ sw];
            short8v b0 = *(const short8v*)&BsBuf[col * 264 + ko2];
            short8v b1 = *(const short8v*)&BsBuf[(16 + col) * 264 + ko2];
            acc2[0] = __builtin_amdgcn_mfma_f32_16x16x32_bf16(a2, b0, acc2[0], 0, 0, 0);
            acc2[1] = __builtin_amdgcn_mfma_f32_16x16x32_bf16(a2, b1, acc2[1], 0, 0, 0);
        }
#pragma unroll
        for (int j = 0; j < 2; ++j)
#pragma unroll
            for (int r = 0; r < 4; ++r)
                Z[(size_t)(m0 + wid * 16 + rbase + r) * 32 + j * 16 + col] =
                    to_bf16u(acc2[j][r]);
    }
}

// C f32 [N,128] = A[N,128](bf16) @ WB[n][k](bf16) (+R f32); N mult of 128
__global__ __launch_bounds__(256) void k_gmm_b(const unsigned short* __restrict__ A,
                                               const unsigned short* __restrict__ WB,
                                               const float* __restrict__ R,
                                               float* __restrict__ C) {
    __shared__ unsigned short As[128][40];
    __shared__ unsigned short Bs[128][40];
    int tid = threadIdx.x;
    int m0 = blockIdx.x * 128;
    int lane = tid & 63, wid = tid >> 6;
    int mw = wid >> 1, nw = wid & 1;
    f32x4 acc[4][4];
#pragma unroll
    for (int i = 0; i < 4; ++i)
#pragma unroll
        for (int j = 0; j < 4; ++j) acc[i][j] = (f32x4){0.f, 0.f, 0.f, 0.f};
    for (int kc = 0; kc < 4; ++kc) {
        __syncthreads();
        for (int i = tid; i < 512; i += 256) {
            int r = i >> 2, q = i & 3;
            *(uint4*)&As[r][q * 8] = *(const uint4*)(A + (size_t)(m0 + r) * TH + kc * 32 + q * 8);
            *(uint4*)&Bs[r][q * 8] = *(const uint4*)(WB + (size_t)r * TH + kc * 32 + q * 8);
        }
        __syncthreads();
        int ko = (lane >> 4) * 8;
        short8v af[4], bfr[4];
#pragma unroll
        for (int t = 0; t < 4; ++t) {
            af[t] = *(const short8v*)&As[mw * 64 + t * 16 + (lane & 15)][ko];
            bfr[t] = *(const short8v*)&Bs[nw * 64 + t * 16 + (lane & 15)][ko];
        }
#pragma unroll
        for (int i = 0; i < 4; ++i)
#pragma unroll
            for (int j = 0; j < 4; ++j)
                acc[i][j] = __builtin_amdgcn_mfma_f32_16x16x32_bf16(af[i], bfr[j], acc[i][j], 0, 0, 0);
    }
    int rbase = (lane >> 4) * 4, col = lane & 15;
#pragma unroll
    for (int i = 0; i < 4; ++i)
#pragma unroll
        for (int j = 0; j < 4; ++j) {
            int n = nw * 64 + j * 16 + col;
#pragma unroll
            for (int r = 0; r < 4; ++r) {
                size_t off = (size_t)(m0 + mw * 64 + i * 16 + rbase + r) * TH + n;
                float v = acc[i][j][r];
                if (R) v += R[off];
                C[off] = v;
            }
        }
}

// C bf16 [N,128] = A[N,128](bf16) @ WB[n][k](bf16); packed stores (GAT features)
__global__ __launch_bounds__(256) void k_gmm_bb(const unsigned short* __restrict__ A,
                                                const unsigned short* __restrict__ WB,
                                                unsigned short* __restrict__ C) {
    __shared__ unsigned short As[128][40];
    __shared__ unsigned short Bs[128][40];
    int tid = threadIdx.x;
    int m0 = blockIdx.x * 128;
    int lane = tid & 63, wid = tid >> 6;
    int mw = wid >> 1, nw = wid & 1;
    f32x4 accT[4][4];   // [j][i]: D[n][m]
#pragma unroll
    for (int j = 0; j < 4; ++j)
#pragma unroll
        for (int i = 0; i < 4; ++i) accT[j][i] = (f32x4){0.f, 0.f, 0.f, 0.f};
    for (int kc = 0; kc < 4; ++kc) {
        __syncthreads();
        for (int i = tid; i < 512; i += 256) {
            int r = i >> 2, q = i & 3;
            *(uint4*)&As[r][q * 8] = *(const uint4*)(A + (size_t)(m0 + r) * TH + kc * 32 + q * 8);
            *(uint4*)&Bs[r][q * 8] = *(const uint4*)(WB + (size_t)r * TH + kc * 32 + q * 8);
        }
        __syncthreads();
        int ko = (lane >> 4) * 8;
        short8v af[4], bfr[4];
#pragma unroll
        for (int t = 0; t < 4; ++t) {
            af[t] = *(const short8v*)&As[mw * 64 + t * 16 + (lane & 15)][ko];
            bfr[t] = *(const short8v*)&Bs[nw * 64 + t * 16 + (lane & 15)][ko];
        }
#pragma unroll
        for (int j = 0; j < 4; ++j)
#pragma unroll
            for (int i = 0; i < 4; ++i)
                accT[j][i] = __builtin_amdgcn_mfma_f32_16x16x32_bf16(bfr[j], af[i], accT[j][i], 0, 0, 0);
    }
    int rbase = (lane >> 4) * 4, col = lane & 15;
#pragma unroll
    for (int i = 0; i < 4; ++i)
#pragma unroll
        for (int j = 0; j < 4; ++j) {
            int m = m0 + mw * 64 + i * 16 + col;
            int n0 = nw * 64 + j * 16 + rbase;
            ushort4 pk;
            pk.x = to_bf16u(accT[j][i][0]);
            pk.y = to_bf16u(accT[j][i][1]);
            pk.z = to_bf16u(accT[j][i][2]);
            pk.w = to_bf16u(accT[j][i][3]);
            *(ushort4*)(C + (size_t)m * TH + n0) = pk;
        }
}

// alpha = softmax(V@wv over L); g = sum_l alpha*V; coalesced pass-1
__global__ __launch_bounds__(256) void k_pool(const float* __restrict__ V, const float* __restrict__ wv,
                                              float* __restrict__ g) {
    __shared__ float sc[TL];
    __shared__ float red[4];
    int b = blockIdx.x, tid = threadIdx.x;
    int lane = tid & 63, w = tid >> 6;
    // pass 1: wave-per-row dot (coalesced float2 loads)
    for (int l = w; l < TL; l += 4) {
        const float2 v = ((const float2*)(V + (size_t)(b * TL + l) * TH))[lane];
        float a = v.x * wv[2 * lane] + v.y * wv[2 * lane + 1];
        for (int o = 32; o > 0; o >>= 1) a += __shfl_down(a, o, 64);
        if (lane == 0) sc[l] = a;
    }
    __syncthreads();
    float m = (tid < TL) ? sc[tid] : -INFINITY;
    for (int o = 32; o > 0; o >>= 1) m = fmaxf(m, __shfl_down(m, o, 64));
    if ((tid & 63) == 0) red[tid >> 6] = m;
    __syncthreads();
    m = fmaxf(fmaxf(red[0], red[1]), fmaxf(red[2], red[3]));
    __syncthreads();
    float e = (tid < TL) ? expf(sc[tid] - m) : 0.f;
    float s = block_reduce_sum(e, red);
    if (tid < TL) sc[tid] = e / s;
    __syncthreads();
    if (tid < TH) {
        float a = 0.f;
        for (int l = 0; l < TL; ++l) a += sc[l] * V[(size_t)(b * TL + l) * TH + tid];
        g[b * TH + tid] = a;
    }
}

// merged 4x scores over bf16 features
__global__ __launch_bounds__(256) void k_scores4(
        const unsigned short* __restrict__ f0, const float* __restrict__ v0, float* __restrict__ o0, int n0,
        const unsigned short* __restrict__ f1, const float* __restrict__ v1, float* __restrict__ o1, int n1,
        const unsigned short* __restrict__ f2, const float* __restrict__ v2, float* __restrict__ o2, int n2,
        const unsigned short* __restrict__ f3, const float* __restrict__ v3, float* __restrict__ o3, int n3) {
    int t = blockIdx.x * 256 + threadIdx.x;
    const unsigned short* f; const float* vec; float* o;
    if (t < n0 * 4) { f = f0; vec = v0; o = o0; }
    else {
        t -= n0 * 4;
        if (t < n1 * 4) { f = f1; vec = v1; o = o1; }
        else {
            t -= n1 * 4;
            if (t < n2 * 4) { f = f2; vec = v2; o = o2; }
            else {
                t -= n2 * 4;
                if (t >= n3 * 4) return;
                f = f3; vec = v3; o = o3;
            }
        }
    }
    int node = t >> 2, k = t & 3;
    const unsigned short* fp = f + (size_t)node * TH + k * TD;
    const float* vp = vec + k * TD;
    float a = 0.f;
#pragma unroll
    for (int q = 0; q < 4; ++q) {
        uint4 u = *(const uint4*)(fp + q * 8);
        unsigned int ws[4] = {u.x, u.y, u.z, u.w};
#pragma unroll
        for (int p = 0; p < 4; ++p) {
            a += __uint_as_float(ws[p] << 16) * vp[q * 8 + p * 2];
            a += __uint_as_float(ws[p] & 0xffff0000u) * vp[q * 8 + p * 2 + 1];
        }
    }
    o[t] = a;
}

// fused per-dst-node GAT; cur bf16, fs bf16, nxt bf16 out, ACC f32
__global__ __launch_bounds__(128) void k_gat(const unsigned short* __restrict__ tax_cur,
                                             const unsigned short* __restrict__ fs_i, const float* __restrict__ el_i,
                                             const float* __restrict__ er_i, const int* __restrict__ src_i,
                                             const float* __restrict__ bi,
                                             const unsigned short* __restrict__ fs_t, const float* __restrict__ el_t,
                                             const float* __restrict__ er_t, const int* __restrict__ src_t,
                                             const float* __restrict__ bt,
                                             unsigned short* __restrict__ tax_nxt,
                                             float* __restrict__ acc, int hop) {
    int n = blockIdx.x, h = threadIdx.x, k = h >> 5;
    float cur = bfu_to_f(tax_cur[(size_t)n * TH + h]);
    float ti, tt2;
    {
        float er = er_i[n * 4 + k];
        int s[4]; float e[4]; float m = -INFINITY;
#pragma unroll
        for (int j = 0; j < 4; ++j) {
            s[j] = src_i[n * 4 + j];
            float xx = el_i[s[j] * 4 + k] + er;
            e[j] = xx > 0.f ? xx : 0.2f * xx;
            m = fmaxf(m, e[j]);
        }
        float ssum = 0.f, av = 0.f;
#pragma unroll
        for (int j = 0; j < 4; ++j) {
            float a = expf(e[j] - m);
            ssum += a;
            av += a * bfu_to_f(fs_i[(size_t)s[j] * TH + h]);
        }
        ti = fmaxf(av / ssum + cur + bi[h], 0.f);
    }
    {
        float er = er_t[n * 4 + k];
        int s[2]; float e[2]; float m = -INFINITY;
#pragma unroll
        for (int j = 0; j < 2; ++j) {
            s[j] = src_t[n * 2 + j];
            float xx = el_t[s[j] * 4 + k] + er;
            e[j] = xx > 0.f ? xx : 0.2f * xx;
            m = fmaxf(m, e[j]);
        }
        float ssum = 0.f, av = 0.f;
#pragma unroll
        for (int j = 0; j < 2; ++j) {
            float a = expf(e[j] - m);
            ssum += a;
            av += a * bfu_to_f(fs_t[(size_t)s[j] * TH + h]);
        }
        tt2 = fmaxf(av / ssum + cur + bt[h], 0.f);
    }
    float nx = ti + tt2;
    size_t ai = (size_t)n * TH + h;
    tax_nxt[ai] = to_bf16u(nx);
    acc[ai] = (hop == 0) ? nx : acc[ai] + nx;
}

// fused local-gather + mul + LN/softmax/LN + @uni_w -> PB bf16
__global__ __launch_bounds__(128) void k_locfuse(const int* __restrict__ root, const float* __restrict__ acc,
                                                 const float* __restrict__ g,
                                                 const float* __restrict__ liw_g, const float* __restrict__ liw_b,
                                                 const float* __restrict__ int_g, const float* __restrict__ int_b,
                                                 const float* __restrict__ uni_w,
                                                 unsigned short* __restrict__ PB) {
    __shared__ float loc[TFT][TH];
    __shared__ float lm[TFT], wv_[TFT], inten[TH];
    __shared__ float red[2];
    int b = blockIdx.x, tid = threadIdx.x;
    float gv = g[b * TH + tid];
    for (int f = 0; f < TFT; ++f) {
        int r = root[b * TFT + f];
        float v = 0.f;
        if (r != -1) v = acc[(size_t)(b * TTP + (r < 0 ? 0 : r)) * TH + tid] * 0.5f;
        loc[f][tid] = v;
        float s = block_reduce_sum(v * gv, red);
        if (tid == 0) lm[f] = s;
    }
    __syncthreads();
    if (tid < TFT) {
        float mean = 0.f;
        for (int f = 0; f < TFT; ++f) mean += lm[f];
        mean *= (1.f / TFT);
        float var = 0.f;
        for (int f = 0; f < TFT; ++f) { float d = lm[f] - mean; var += d * d; }
        var *= (1.f / TFT);
        float ln = (lm[tid] - mean) * rsqrtf(var + 1e-8f) * liw_g[tid] + liw_b[tid];
        wv_[tid] = (lm[tid] != 0.f) ? ln : -INFINITY;
    }
    __syncthreads();
    if (tid < TFT) {
        float mx = -INFINITY;
        for (int f = 0; f < TFT; ++f) mx = fmaxf(mx, wv_[f]);
        float s = 0.f;
        for (int f = 0; f < TFT; ++f) s += expf(wv_[f] - mx);
        lm[tid] = expf(wv_[tid] - mx) / s;
    }
    __syncthreads();
    float ip = gv;
    for (int f = 0; f < TFT; ++f) ip += lm[f] * loc[f][tid];
    float mean = block_reduce_sum(ip, red) * (1.f / TH);
    float d = ip - mean;
    float var = block_reduce_sum(d * d, red) * (1.f / TH);
    inten[tid] = d * rsqrtf(var + 1e-8f) * int_g[tid] + int_b[tid];
    __syncthreads();
    float a = 0.f;
    for (int hp = 0; hp < TH; ++hp) a += inten[hp] * uni_w[hp * TH + tid];
    PB[(size_t)b * TH + tid] = to_bf16u(a);
}

// E f32 -> EB bf16, rows padded to TIPAD
__global__ __launch_bounds__(256) void k_ebc(const float* __restrict__ E,
                                             unsigned short* __restrict__ EB) {
    int t = blockIdx.x * 256 + threadIdx.x;
    if (t >= TIPAD * TH / 8) return;
    size_t base = (size_t)t * 8;
    int row = (int)(base >> 7);
    float4 a = {0.f, 0.f, 0.f, 0.f}, b = {0.f, 0.f, 0.f, 0.f};
    if (row < TITEMS) {
        a = *(const float4*)(E + base);
        b = *(const float4*)(E + base + 4);
    }
    ushort4 u0, u1;
    u0.x = to_bf16u(a.x); u0.y = to_bf16u(a.y); u0.z = to_bf16u(a.z); u0.w = to_bf16u(a.w);
    u1.x = to_bf16u(b.x); u1.y = to_bf16u(b.y); u1.z = to_bf16u(b.z); u1.w = to_bf16u(b.w);
    *(ushort4*)(EB + base) = u0;
    *(ushort4*)(EB + base + 4) = u1;
}

// out[b,i] = PB[b,:] . EB[i,:]  (bf16 MFMA; A-frags direct from global PB)
__global__ __launch_bounds__(256) void k_final_m(const unsigned short* __restrict__ PB,
                                                 const unsigned short* __restrict__ EB,
                                                 float* __restrict__ out) {
    __shared__ unsigned short Bs[128][136];
    int tid = threadIdx.x;
    int i0 = blockIdx.x * 128, b0 = blockIdx.y * 128;
    for (int i = tid; i < 2048; i += 256) {
        int r = i >> 4, q = i & 15;
        *(uint4*)&Bs[r][q * 8] = *(const uint4*)(EB + (size_t)(i0 + r) * TH + q * 8);
    }
    __syncthreads();
    int lane = tid & 63, wid = tid >> 6;
    int mw = wid >> 1, nw = wid & 1;
    f32x4 acc[4][4];
#pragma unroll
    for (int i = 0; i < 4; ++i)
#pragma unroll
        for (int j = 0; j < 4; ++j) acc[i][j] = (f32x4){0.f, 0.f, 0.f, 0.f};
#pragma unroll
    for (int kc = 0; kc < 4; ++kc) {
        int ko = kc * 32 + (lane >> 4) * 8;
        short8v af[4], bfr[4];
#pragma unroll
        for (int t = 0; t < 4; ++t) {
            af[t] = *(const short8v*)(PB + (size_t)(b0 + mw * 64 + t * 16 + (lane & 15)) * TH + ko);
            bfr[t] = *(const short8v*)&Bs[nw * 64 + t * 16 + (lane & 15)][ko];
        }
#pragma unroll
        for (int i = 0; i < 4; ++i)
#pragma unroll
            for (int j = 0; j < 4; ++j)
                acc[i][j] = __builtin_amdgcn_mfma_f32_16x16x32_bf16(af[i], bfr[j], acc[i][j], 0, 0, 0);
    }
    int rbase = (lane >> 4) * 4, col = lane & 15;
#pragma unroll
    for (int i = 0; i < 4; ++i)
#pragma unroll
        for (int j = 0; j < 4; ++j) {
            int ii = i0 + nw * 64 + j * 16 + col;
            if (ii < TITEMS) {
#pragma unroll
                for (int r = 0; r < 4; ++r)
                    out[(size_t)(b0 + mw * 64 + i * 16 + rbase + r) * TITEMS + ii] = acc[i][j][r];
            }
        }
}

extern "C" void kernel_launch(void* const* d_in, const int* in_sizes, int n_in,
                              void* d_out, int out_size, void* d_ws, size_t ws_size,
                              hipStream_t stream) {
    const int*   seq        = (const int*)d_in[0];
    const int*   root       = (const int*)d_in[1];
    const int*   i2t_src    = (const int*)d_in[3];
    const int*   t2t_src    = (const int*)d_in[5];
    const int*   item_ids   = (const int*)d_in[6];
    const int*   tax_ids    = (const int*)d_in[7];
    const float* item_embed = (const float*)d_in[8];
    const float* tax_embed  = (const float*)d_in[9];
    const float* scb_ln_g   = (const float*)d_in[10];
    const float* scb_ln_b   = (const float*)d_in[11];
    const float* scb_w1     = (const float*)d_in[12];
    const float* scb_w2     = (const float*)d_in[13];
    const float* fcb_ln_g   = (const float*)d_in[14];
    const float* fcb_ln_b   = (const float*)d_in[15];
    const float* fcb_w1     = (const float*)d_in[16];
    const float* fcb_w2     = (const float*)d_in[17];
    const float* fcb_w3     = (const float*)d_in[18];
    const float* wv         = (const float*)d_in[19];
    const float* gi_w       = (const float*)d_in[20];
    const float* gi_al      = (const float*)d_in[21];
    const float* gi_ar      = (const float*)d_in[22];
    const float* gi_b       = (const float*)d_in[23];
    const float* gt_w       = (const float*)d_in[24];
    const float* gt_al      = (const float*)d_in[25];
    const float* gt_ar      = (const float*)d_in[26];
    const float* gt_b       = (const float*)d_in[27];
    const float* liw_g      = (const float*)d_in[28];
    const float* liw_b      = (const float*)d_in[29];
    const float* int_g      = (const float*)d_in[30];
    const float* int_b      = (const float*)d_in[31];
    const float* uni_w      = (const float*)d_in[32];

    char* w = (char*)d_ws;
    float* V     = (float*)(w + 0);           // 52.4MB (V / FSIB)
    float* NV    = (float*)(w + 52428800);    // 52.4MB (nv / ITEMHB)
    unsigned short* FSIB   = (unsigned short*)(w + 0);
    unsigned short* ITEMHB = (unsigned short*)(w + 52428800);
    // mixer-scb phase:
    unsigned short* NVT = (unsigned short*)(w + 104857600);  // 29.4MB
    unsigned short* T   = (unsigned short*)(w + 134217728);  // 33.6MB
    unsigned short* W1T = (unsigned short*)(w + 167772160);  // 229KB
    unsigned short* W2T = (unsigned short*)(w + 168001536);  // 213KB
    // mixer-fcb phase:
    unsigned short* ZB  = (unsigned short*)(w + 104857600);  // 26.2MB (aliases NVT, dead)
    // GAT phase:
    unsigned short* TAXB0 = (unsigned short*)(w + 104857600);
    unsigned short* TAXB1 = (unsigned short*)(w + 113246208);
    float* ACC   = (float*)(w + 138412032);
    unsigned short* FDIB = (unsigned short*)(w + 155189248);
    unsigned short* FSTB = (unsigned short*)(w + 171966464);
    float* ELI   = (float*)(w + 188743680);
    float* ERI   = (float*)(w + 190382080);
    float* ELT   = (float*)(w + 190906368);
    float* ERT   = (float*)(w + 191430656);
    float* G     = (float*)(w + 200343552);
    unsigned short* WB = (unsigned short*)(w + 191954944);   // 262KB converted weights
    // final phase:
    unsigned short* EB = (unsigned short*)(w + 155189248);   // 25.6MB (aliases FDIB+FSTB)
    unsigned short* PB = (unsigned short*)(w + 200671232);   // 128KB
    if (ws_size < 200933376ull) return;

    // one-time weight conversion
    k_wcvt<<<512, 256, 0, stream>>>(fcb_w1, fcb_w2, fcb_w3, gi_w, gt_w, WB);

    // ---- global intention (mixer) ----
    for (int nb = 0; nb < 2; ++nb) {
        // nb=0: gather fused into lnt (reads item_embed[seq]); nb=1: reads V
        k_lnt<<<dim3(4, TB), 128, 0, stream>>>(V, nb == 0 ? seq : nullptr, item_embed,
                                               scb_ln_g + nb * TH, scb_ln_b + nb * TH, NV, NVT);
        k_wscb<<<720, 256, 0, stream>>>(scb_w1 + nb * TL * TSH, scb_w2 + nb * TSH * TL, W1T, W2T);
        for (int bh = 0; bh < 2; ++bh) {
            k_mm1<<<dim3(4, 256), 256, 0, stream>>>(NVT, W1T, T, bh);
            k_mm2l<<<dim3(4, 256), 256, 0, stream>>>(T, W2T, NV,
                                                     fcb_ln_g + nb * TH, fcb_ln_b + nb * TH, bh);
        }
        k_ffuse<<<TB * TL * 4 / 64, 256, 0, stream>>>(NV, WB + nb * 8192, WB + 16384 + nb * 8192, ZB);
        k_gmm_b<<<TB * TL / 128, 256, 0, stream>>>(ZB, WB + 32768 + nb * 16384, NV, V);
    }
    k_pool<<<TB, 256, 0, stream>>>(V, wv, G);

    // ---- local intention (GAT, bf16 features) ----
    k_gather_bf<<<(TNI * 16 + 255) / 256, 256, 0, stream>>>(item_embed, item_ids, ITEMHB, TNI);
    k_gather_bf<<<(TNT * 16 + 255) / 256, 256, 0, stream>>>(tax_embed, tax_ids, TAXB0, TNT);

    unsigned short* curb = TAXB0;
    unsigned short* nxtb = TAXB1;
    for (int hop = 0; hop < 2; ++hop) {
        const unsigned short* WiB = WB + 65536 + hop * 16384;
        const unsigned short* WtB = WB + 98304 + hop * 16384;
        k_gmm_bb<<<TNI / 128, 256, 0, stream>>>(ITEMHB, WiB, FSIB);
        k_gmm_bb<<<TNT / 128, 256, 0, stream>>>(curb, WiB, FDIB);
        k_gmm_bb<<<TNT / 128, 256, 0, stream>>>(curb, WtB, FSTB);
        int total = (TNI + 3 * TNT) * TNH;
        k_scores4<<<(total + 255) / 256, 256, 0, stream>>>(
            FSIB, gi_al + hop * TH, ELI, TNI,
            FDIB, gi_ar + hop * TH, ERI, TNT,
            FSTB, gt_al + hop * TH, ELT, TNT,
            FSTB, gt_ar + hop * TH, ERT, TNT);
        k_gat<<<TNT, 128, 0, stream>>>(curb, FSIB, ELI, ERI, i2t_src, gi_b + hop * TH,
                                       FSTB, ELT, ERT, t2t_src, gt_b + hop * TH, nxtb, ACC, hop);
        unsigned short* tmp = curb; curb = nxtb; nxtb = tmp;
    }

    // ---- fuse + final ----
    k_locfuse<<<TB, 128, 0, stream>>>(root, ACC, G, liw_g, liw_b, int_g, int_b, uni_w, PB);
    k_ebc<<<(TIPAD * TH / 8 + 255) / 256, 256, 0, stream>>>(item_embed, EB);
    k_final_m<<<dim3(TIPAD / 128, TB / 128), 256, 0, stream>>>(PB, EB, (float*)d_out);
}

// Round 13
// 1001.732 us; speedup vs baseline: 1.0800x; 1.0262x over previous
//
#include <hip/hip_runtime.h>
#include <hip/hip_bf16.h>

// ---- model dims ----
constexpr int TB = 512, TL = 200, TH = 128, TNH = 4, TD = 32;
constexpr int TFT = 32, TTP = 64, TIP = 200;
constexpr int TSH = 512, TFH = 256;
constexpr int TITEMS = 100001;
constexpr int TNT = TB * TTP;   // 32768
constexpr int TNI = TB * TIP;   // 102400
constexpr int TLP = 224;        // L padded (K of scb GEMM1)
constexpr int TIPAD = 100096;   // items padded to 128

typedef __attribute__((ext_vector_type(8))) short short8v;
typedef __attribute__((ext_vector_type(4))) float f32x4;

// tanh-form gelu, |err| <= ~3e-4 (below bf16 quantization of the result)
__device__ inline float gelu_fast(float x) {
    float u = x + 0.044715f * x * x * x;
    float e = exp2f(-2.302208f * u);
    return x / (1.0f + e);
}
__device__ inline unsigned short to_bf16u(float x) {
    __hip_bfloat16 h = __float2bfloat16(x);
    return *reinterpret_cast<unsigned short*>(&h);
}
__device__ inline float bfu_to_f(unsigned short u) {
    unsigned int x = ((unsigned int)u) << 16;
    return __uint_as_float(x);
}

__device__ inline float block_reduce_sum(float v, float* red) {
    for (int o = 32; o > 0; o >>= 1) v += __shfl_down(v, o, 64);
    int nw = blockDim.x >> 6;
    if ((threadIdx.x & 63) == 0) red[threadIdx.x >> 6] = v;
    __syncthreads();
    float r = 0.f;
    for (int w = 0; w < nw; ++w) r += red[w];
    __syncthreads();
    return r;
}

// out[r,:] = bf16(table[idx[r],:])
__global__ __launch_bounds__(256) void k_gather_bf(const float* __restrict__ tab,
                                                   const int* __restrict__ idx,
                                                   unsigned short* __restrict__ out, int nrows) {
    int e = blockIdx.x * blockDim.x + threadIdx.x;
    if (e >= nrows * 16) return;
    int r = e >> 4, c = e & 15;
    const float4 a = ((const float4*)tab)[(size_t)idx[r] * 32 + c * 2];
    const float4 b = ((const float4*)tab)[(size_t)idx[r] * 32 + c * 2 + 1];
    uint4 u;
    u.x = (unsigned int)to_bf16u(a.x) | ((unsigned int)to_bf16u(a.y) << 16);
    u.y = (unsigned int)to_bf16u(a.z) | ((unsigned int)to_bf16u(a.w) << 16);
    u.z = (unsigned int)to_bf16u(b.x) | ((unsigned int)to_bf16u(b.y) << 16);
    u.w = (unsigned int)to_bf16u(b.z) | ((unsigned int)to_bf16u(b.w) << 16);
    *(uint4*)(out + (size_t)e * 8) = u;
}

// one-time conversion of small weights to bf16, pre-transposed to [n][k]
__global__ __launch_bounds__(256) void k_wcvt(const float* __restrict__ fw1, const float* __restrict__ fw2,
                                              const float* __restrict__ fw3, const float* __restrict__ giw,
                                              const float* __restrict__ gtw, unsigned short* __restrict__ WB) {
    int idx = blockIdx.x * 256 + threadIdx.x;  // 0..131071
    float v;
    if (idx < 16384) {           // fw1b[nb][n=256][k=32]
        int nb = idx >> 13, r = idx & 8191, n = r >> 5, k = r & 31;
        v = fw1[(size_t)nb * 8192 + k * 256 + n];
    } else if (idx < 32768) {    // fw2b[nb][n=32][k=256]
        int t = idx - 16384;
        int nb = t >> 13, r = t & 8191, n = r >> 8, k = r & 255;
        v = fw2[(size_t)nb * 8192 + k * 32 + n];
    } else if (idx < 65536) {    // fw3b[nb][n=128][k=128]
        int t = idx - 32768;
        int nb = t >> 14, r = t & 16383, n = r >> 7, k = r & 127;
        v = fw3[(size_t)nb * 16384 + k * 128 + n];
    } else if (idx < 98304) {    // giwb[hop][n][k]
        int t = idx - 65536;
        int hop = t >> 14, r = t & 16383, n = r >> 7, k = r & 127;
        v = giw[(size_t)hop * 16384 + k * 128 + n];
    } else {                     // gtwb[hop][n][k]
        int t = idx - 98304;
        int hop = t >> 14, r = t & 16383, n = r >> 7, k = r & 127;
        v = gtw[(size_t)hop * 16384 + k * 128 + n];
    }
    WB[idx] = to_bf16u(v);
}

// fused [gather +] LN + bf16 transpose: src -> NV f32 (LN'd) + NVT[b][h][lp] bf16
__global__ __launch_bounds__(128) void k_lnt(const float* __restrict__ V,
                                             const int* __restrict__ seqp, const float* __restrict__ tab,
                                             const float* __restrict__ g, const float* __restrict__ b,
                                             float* __restrict__ NV, unsigned short* __restrict__ NVT) {
    __shared__ float tl[64][129];
    __shared__ float mrow[64], irow[64];
    int bb = blockIdx.y, l0 = blockIdx.x * 64, tid = threadIdx.x;
    for (int i = tid; i < 2048; i += 128) {
        int r = i >> 5, c = i & 31;
        int l = l0 + r;
        float4 v = {0.f, 0.f, 0.f, 0.f};
        if (l < TL) {
            const float* src = seqp ? (tab + (size_t)seqp[bb * TL + l] * TH)
                                    : (V + ((size_t)bb * TL + l) * TH);
            v = *(const float4*)(src + c * 4);
        }
        tl[r][c * 4 + 0] = v.x; tl[r][c * 4 + 1] = v.y;
        tl[r][c * 4 + 2] = v.z; tl[r][c * 4 + 3] = v.w;
    }
    __syncthreads();
    {
        int row = tid >> 1, half = tid & 1;
        float s = 0.f, sq = 0.f;
        for (int k = 0; k < 64; ++k) {
            float v = tl[row][half * 64 + k];
            s += v; sq += v * v;
        }
        s += __shfl_xor(s, 1);
        sq += __shfl_xor(sq, 1);
        if (half == 0) {
            float mean = s * (1.f / 128.f);
            mrow[row] = mean;
            irow[row] = rsqrtf(sq * (1.f / 128.f) - mean * mean + 1e-8f);
        }
    }
    __syncthreads();
    for (int i = tid; i < 2048; i += 128) {
        int r = i >> 5, c = i & 31;
        int l = l0 + r;
        float4 o = {0.f, 0.f, 0.f, 0.f};
        if (l < TL) {
            float4 v = *(float4*)&tl[r][c * 4];
            float m = mrow[r], inv = irow[r];
            const float4 gg = ((const float4*)g)[c];
            const float4 bv = ((const float4*)b)[c];
            o.x = (v.x - m) * inv * gg.x + bv.x;
            o.y = (v.y - m) * inv * gg.y + bv.y;
            o.z = (v.z - m) * inv * gg.z + bv.z;
            o.w = (v.w - m) * inv * gg.w + bv.w;
            *(float4*)(NV + ((size_t)bb * TL + l) * TH + c * 4) = o;
        }
        *(float4*)&tl[r][c * 4] = o;
    }
    __syncthreads();
    int h = tid;
    int ng = (l0 + 64 > TLP) ? (TLP - l0) / 8 : 8;
    for (int lg = 0; lg < ng; ++lg) {
        uint4 u;
        unsigned int p[4];
#pragma unroll
        for (int q = 0; q < 4; ++q) {
            unsigned short ua = to_bf16u(tl[lg * 8 + q * 2 + 0][h]);
            unsigned short ub = to_bf16u(tl[lg * 8 + q * 2 + 1][h]);
            p[q] = (unsigned int)ua | ((unsigned int)ub << 16);
        }
        u.x = p[0]; u.y = p[1]; u.z = p[2]; u.w = p[3];
        *(uint4*)(NVT + ((size_t)bb * TH + h) * TLP + l0 + lg * 8) = u;
    }
}

// merged scb weight transposes
__global__ __launch_bounds__(256) void k_wscb(const float* __restrict__ w1, const float* __restrict__ w2,
                                              unsigned short* __restrict__ W1T,
                                              unsigned short* __restrict__ W2T) {
    int bx = blockIdx.x;
    if (bx < TSH) {
        int s = bx, l = threadIdx.x;
        if (l < TLP) W1T[(size_t)s * TLP + l] = to_bf16u(l < TL ? w1[(size_t)l * TSH + s] : 0.f);
    } else {
        int l = bx - TSH;   // 0..207
        for (int it = 0; it < 2; ++it) {
            int s = it * 256 + threadIdx.x;
            W2T[(size_t)l * TSH + s] = to_bf16u(l < TL ? w2[(size_t)s * TL + l] : 0.f);
        }
    }
}

// scb GEMM1: T[b][h][s] = gelu( sum_l NVT[b][h][l] * w1[l][s] ); packed T stores
__global__ __launch_bounds__(256) void k_mm1(const unsigned short* __restrict__ NVT,
                                             const unsigned short* __restrict__ W1T,
                                             unsigned short* __restrict__ T, int bh) {
    __shared__ unsigned short As[128][40];
    __shared__ unsigned short Bs[128][40];
    int tid = threadIdx.x;
    int b_local = blockIdx.y, b = bh * 256 + b_local;
    int s0 = blockIdx.x * 128;
    int lane = tid & 63, wid = tid >> 6;
    int mw = wid >> 1, nw = wid & 1;
    f32x4 accT[4][4];   // [j][i]: D[s][h] (swapped operands)
#pragma unroll
    for (int j = 0; j < 4; ++j)
#pragma unroll
        for (int i = 0; i < 4; ++i) accT[j][i] = (f32x4){0.f, 0.f, 0.f, 0.f};
    const unsigned short* Abase = NVT + (size_t)b * TH * TLP;
    const unsigned short* Bbase = W1T + (size_t)s0 * TLP;
    for (int kc = 0; kc < 7; ++kc) {
        __syncthreads();
        for (int i = tid; i < 512; i += 256) {
            int r = i >> 2, q = i & 3;
            *(uint4*)&As[r][q * 8] = *(const uint4*)(Abase + (size_t)r * TLP + kc * 32 + q * 8);
            *(uint4*)&Bs[r][q * 8] = *(const uint4*)(Bbase + (size_t)r * TLP + kc * 32 + q * 8);
        }
        __syncthreads();
        int ko = (lane >> 4) * 8;
        short8v af[4], bfr[4];
#pragma unroll
        for (int t = 0; t < 4; ++t) {
            af[t] = *(const short8v*)&As[mw * 64 + t * 16 + (lane & 15)][ko];
            bfr[t] = *(const short8v*)&Bs[nw * 64 + t * 16 + (lane & 15)][ko];
        }
#pragma unroll
        for (int j = 0; j < 4; ++j)
#pragma unroll
            for (int i = 0; i < 4; ++i)
                accT[j][i] = __builtin_amdgcn_mfma_f32_16x16x32_bf16(bfr[j], af[i], accT[j][i], 0, 0, 0);
    }
    int rbase = (lane >> 4) * 4, col = lane & 15;
#pragma unroll
    for (int i = 0; i < 4; ++i)
#pragma unroll
        for (int j = 0; j < 4; ++j) {
            int h = mw * 64 + i * 16 + col;
            int sb = s0 + nw * 64 + j * 16 + rbase;
            ushort4 pk;
            pk.x = to_bf16u(gelu_fast(accT[j][i][0]));
            pk.y = to_bf16u(gelu_fast(accT[j][i][1]));
            pk.z = to_bf16u(gelu_fast(accT[j][i][2]));
            pk.w = to_bf16u(gelu_fast(accT[j][i][3]));
            *(ushort4*)(T + ((size_t)b_local * TH + h) * TSH + sb) = pk;
        }
}

// scb GEMM2 + fcb LN fused: vs = NV + T@w2; NV <- LN(vs) in place
__global__ __launch_bounds__(256) void k_mm2l(const unsigned short* __restrict__ T,
                                              const unsigned short* __restrict__ W2T,
                                              float* __restrict__ NV,
                                              const float* __restrict__ lg, const float* __restrict__ lb,
                                              int bh) {
    __shared__ unsigned short As[128][40];
    __shared__ unsigned short Bs[64][40];
    __shared__ float vsl[64][132];
    __shared__ float mrow[64], irow[64];
    int tid = threadIdx.x;
    int b_local = blockIdx.y, b = bh * 256 + b_local;
    int l0 = blockIdx.x * 64;
    int lane = tid & 63, wid = tid >> 6;
    f32x4 acc[2][4];
#pragma unroll
    for (int i = 0; i < 2; ++i)
#pragma unroll
        for (int j = 0; j < 4; ++j) acc[i][j] = (f32x4){0.f, 0.f, 0.f, 0.f};
    const unsigned short* Abase = T + (size_t)b_local * TH * TSH;
    for (int kc = 0; kc < 16; ++kc) {
        __syncthreads();
        for (int i = tid; i < 512; i += 256) {
            int r = i >> 2, q = i & 3;
            *(uint4*)&As[r][q * 8] = *(const uint4*)(Abase + (size_t)r * TSH + kc * 32 + q * 8);
        }
        {
            int r = tid >> 2, q = tid & 3;
            int l = l0 + r;
            uint4 v = {0u, 0u, 0u, 0u};
            if (l < 208) v = *(const uint4*)(W2T + (size_t)l * TSH + kc * 32 + q * 8);
            *(uint4*)&Bs[r][q * 8] = v;
        }
        __syncthreads();
        int ko = (lane >> 4) * 8;
        short8v af[2], bfr[4];
#pragma unroll
        for (int t = 0; t < 2; ++t)
            af[t] = *(const short8v*)&As[wid * 32 + t * 16 + (lane & 15)][ko];
#pragma unroll
        for (int j = 0; j < 4; ++j)
            bfr[j] = *(const short8v*)&Bs[j * 16 + (lane & 15)][ko];
#pragma unroll
        for (int i = 0; i < 2; ++i)
#pragma unroll
            for (int j = 0; j < 4; ++j)
                acc[i][j] = __builtin_amdgcn_mfma_f32_16x16x32_bf16(af[i], bfr[j], acc[i][j], 0, 0, 0);
    }
    int rbase = (lane >> 4) * 4, col = lane & 15;
#pragma unroll
    for (int i = 0; i < 2; ++i)
#pragma unroll
        for (int j = 0; j < 4; ++j) {
            int l = l0 + j * 16 + col;
            int h0 = wid * 32 + i * 16 + rbase;
            float4 res = {0.f, 0.f, 0.f, 0.f};
            if (l < TL) res = *(const float4*)(NV + ((size_t)b * TL + l) * TH + h0);
            float4 o;
            o.x = acc[i][j][0] + res.x;
            o.y = acc[i][j][1] + res.y;
            o.z = acc[i][j][2] + res.z;
            o.w = acc[i][j][3] + res.w;
            *(float4*)&vsl[j * 16 + col][h0] = o;
        }
    __syncthreads();
    int row = tid >> 2, q = tid & 3;
    {
        float s = 0.f, sq = 0.f;
        for (int k = 0; k < 32; ++k) {
            float v = vsl[row][q * 32 + k];
            s += v; sq += v * v;
        }
        s += __shfl_xor(s, 1); s += __shfl_xor(s, 2);
        sq += __shfl_xor(sq, 1); sq += __shfl_xor(sq, 2);
        if (q == 0) {
            float mean = s * (1.f / 128.f);
            mrow[row] = mean;
            irow[row] = rsqrtf(sq * (1.f / 128.f) - mean * mean + 1e-8f);
        }
    }
    __syncthreads();
    {
        int l = l0 + row;
        if (l < TL) {
            float mean = mrow[row], inv = irow[row];
            float* dst = NV + ((size_t)b * TL + l) * TH + q * 32;
#pragma unroll
            for (int k4 = 0; k4 < 8; ++k4) {
                float4 v = *(float4*)&vsl[row][q * 32 + k4 * 4];
                const float4 gg = ((const float4*)lg)[q * 8 + k4];
                const float4 bv = ((const float4*)lb)[q * 8 + k4];
                float4 o;
                o.x = (v.x - mean) * inv * gg.x + bv.x;
                o.y = (v.y - mean) * inv * gg.y + bv.y;
                o.z = (v.z - mean) * inv * gg.z + bv.z;
                o.w = (v.w - mean) * inv * gg.w + bv.w;
                *(float4*)(dst + k4 * 4) = o;
            }
        }
    }
}

// fused fcb stage1+2; PERSISTENT grid-stride over 64-row tiles; weights staged once
__global__ __launch_bounds__(256) void k_ffuse(const float* __restrict__ NV,
                                               const unsigned short* __restrict__ FW1B,
                                               const unsigned short* __restrict__ FW2B,
                                               unsigned short* __restrict__ Z, int ntiles) {
    __shared__ unsigned short As[64][40];        // 5.1KB
    __shared__ unsigned short Bs2[32 * 264];     // 16.9KB (f2 weights, stride 264)
    __shared__ unsigned short Yl[64 * 264];      // 33.8KB (also scratch for f1 wt staging)
    int tid = threadIdx.x;
    int lane = tid & 63, wid = tid >> 6;
    int col = lane & 15, rbase = (lane >> 4) * 4, ko = (lane >> 4) * 8;
    // stage FW1B into Yl scratch (stride 40), load f1 weight fragments into VGPRs
    for (int i = tid; i < 1024; i += 256) {
        int r = i >> 2, q = i & 3;
        *(uint4*)&Yl[r * 40 + q * 8] = *(const uint4*)(FW1B + r * 32 + q * 8);
    }
    // stage FW2B into Bs2 (stride 264)
    for (int i = tid; i < 1024; i += 256) {
        int r = i >> 5, q = i & 31;
        *(uint4*)&Bs2[r * 264 + q * 8] = *(const uint4*)(FW2B + r * 256 + q * 8);
    }
    __syncthreads();
    short8v bfr[4];
#pragma unroll
    for (int t = 0; t < 4; ++t)
        bfr[t] = *(const short8v*)&Yl[(wid * 64 + t * 16 + col) * 40 + ko];
    __syncthreads();   // Yl free now
    int mrow = wid * 16 + col;
    int sw2 = ((mrow >> 2) & 7) << 3;
    for (int tile = blockIdx.x; tile < ntiles; tile += gridDim.x) {
        int m0 = tile * 64;
        // stage As (64 x 32, f32 -> bf16)
        for (int i = tid; i < 512; i += 256) {
            int r = i >> 3, q = i & 7;
            const float4 v = *(const float4*)(NV + (size_t)(m0 + r) * 32 + q * 4);
            ushort4 u;
            u.x = to_bf16u(v.x); u.y = to_bf16u(v.y); u.z = to_bf16u(v.z); u.w = to_bf16u(v.w);
            *(ushort4*)&As[r][q * 4] = u;
        }
        __syncthreads();   // b1: As ready
        // f1 MFMA (swapped) + gelu + packed swizzled Yl store
        {
            short8v af[4];
#pragma unroll
            for (int t = 0; t < 4; ++t)
                af[t] = *(const short8v*)&As[t * 16 + col][ko];
            f32x4 yt[4][4];   // [j][i]: D[n][m]
#pragma unroll
            for (int j = 0; j < 4; ++j)
#pragma unroll
                for (int i = 0; i < 4; ++i) yt[j][i] = (f32x4){0.f, 0.f, 0.f, 0.f};
#pragma unroll
            for (int j = 0; j < 4; ++j)
#pragma unroll
                for (int i = 0; i < 4; ++i)
                    yt[j][i] = __builtin_amdgcn_mfma_f32_16x16x32_bf16(bfr[j], af[i], yt[j][i], 0, 0, 0);
#pragma unroll
            for (int i = 0; i < 4; ++i)
#pragma unroll
                for (int j = 0; j < 4; ++j) {
                    int m = i * 16 + col;
                    int n0 = wid * 64 + j * 16 + rbase;
                    ushort4 pk;
                    pk.x = to_bf16u(gelu_fast(yt[j][i][0]));
                    pk.y = to_bf16u(gelu_fast(yt[j][i][1]));
                    pk.z = to_bf16u(gelu_fast(yt[j][i][2]));
                    pk.w = to_bf16u(gelu_fast(yt[j][i][3]));
                    int idx = (m * 264 + n0) ^ (((m >> 2) & 7) << 3);
                    *(ushort4*)&Yl[idx] = pk;
                }
        }
        __syncthreads();   // b2: Yl ready
        // f2: Z[m][n'] = Y @ W2, K=256
        {
            f32x4 acc2[2];
            acc2[0] = (f32x4){0.f, 0.f, 0.f, 0.f};
            acc2[1] = (f32x4){0.f, 0.f, 0.f, 0.f};
            for (int kc = 0; kc < 8; ++kc) {
                int ko2 = kc * 32 + ko;
                short8v a2 = *(const short8v*)&Yl[(mrow * 264 + ko2) ^ sw2];
                short8v b0 = *(const short8v*)&Bs2[col * 264 + ko2];
                short8v b1 = *(const short8v*)&Bs2[(16 + col) * 264 + ko2];
                acc2[0] = __builtin_amdgcn_mfma_f32_16x16x32_bf16(a2, b0, acc2[0], 0, 0, 0);
                acc2[1] = __builtin_amdgcn_mfma_f32_16x16x32_bf16(a2, b1, acc2[1], 0, 0, 0);
            }
#pragma unroll
            for (int j = 0; j < 2; ++j)
#pragma unroll
                for (int r = 0; r < 4; ++r)
                    Z[(size_t)(m0 + wid * 16 + rbase + r) * 32 + j * 16 + col] =
                        to_bf16u(acc2[j][r]);
        }
        __syncthreads();   // b3: protect Yl/As before next tile
    }
}

// C f32 [N,128] = A[N,128](bf16) @ WB[n][k](bf16) (+R f32); N mult of 128
__global__ __launch_bounds__(256) void k_gmm_b(const unsigned short* __restrict__ A,
                                               const unsigned short* __restrict__ WB,
                                               const float* __restrict__ R,
                                               float* __restrict__ C) {
    __shared__ unsigned short As[128][40];
    __shared__ unsigned short Bs[128][40];
    int tid = threadIdx.x;
    int m0 = blockIdx.x * 128;
    int lane = tid & 63, wid = tid >> 6;
    int mw = wid >> 1, nw = wid & 1;
    f32x4 acc[4][4];
#pragma unroll
    for (int i = 0; i < 4; ++i)
#pragma unroll
        for (int j = 0; j < 4; ++j) acc[i][j] = (f32x4){0.f, 0.f, 0.f, 0.f};
    for (int kc = 0; kc < 4; ++kc) {
        __syncthreads();
        for (int i = tid; i < 512; i += 256) {
            int r = i >> 2, q = i & 3;
            *(uint4*)&As[r][q * 8] = *(const uint4*)(A + (size_t)(m0 + r) * TH + kc * 32 + q * 8);
            *(uint4*)&Bs[r][q * 8] = *(const uint4*)(WB + (size_t)r * TH + kc * 32 + q * 8);
        }
        __syncthreads();
        int ko = (lane >> 4) * 8;
        short8v af[4], bfr[4];
#pragma unroll
        for (int t = 0; t < 4; ++t) {
            af[t] = *(const short8v*)&As[mw * 64 + t * 16 + (lane & 15)][ko];
            bfr[t] = *(const short8v*)&Bs[nw * 64 + t * 16 + (lane & 15)][ko];
        }
#pragma unroll
        for (int i = 0; i < 4; ++i)
#pragma unroll
            for (int j = 0; j < 4; ++j)
                acc[i][j] = __builtin_amdgcn_mfma_f32_16x16x32_bf16(af[i], bfr[j], acc[i][j], 0, 0, 0);
    }
    int rbase = (lane >> 4) * 4, col = lane & 15;
#pragma unroll
    for (int i = 0; i < 4; ++i)
#pragma unroll
        for (int j = 0; j < 4; ++j) {
            int n = nw * 64 + j * 16 + col;
#pragma unroll
            for (int r = 0; r < 4; ++r) {
                size_t off = (size_t)(m0 + mw * 64 + i * 16 + rbase + r) * TH + n;
                float v = acc[i][j][r];
                if (R) v += R[off];
                C[off] = v;
            }
        }
}

// merged 3x GAT feature GEMMs: C bf16 = A @ WB (packed stores)
__global__ __launch_bounds__(256) void k_gmm3(
        const unsigned short* __restrict__ A0, const unsigned short* __restrict__ W0,
        unsigned short* __restrict__ C0, int nb0,
        const unsigned short* __restrict__ A1, const unsigned short* __restrict__ W1,
        unsigned short* __restrict__ C1, int nb1,
        const unsigned short* __restrict__ A2, const unsigned short* __restrict__ W2,
        unsigned short* __restrict__ C2) {
    __shared__ unsigned short As[128][40];
    __shared__ unsigned short Bs[128][40];
    int bx = blockIdx.x;
    const unsigned short *A, *WBp;
    unsigned short* C;
    if (bx < nb0) { A = A0; WBp = W0; C = C0; }
    else if (bx - nb0 < nb1) { bx -= nb0; A = A1; WBp = W1; C = C1; }
    else { bx -= nb0 + nb1; A = A2; WBp = W2; C = C2; }
    int tid = threadIdx.x;
    int m0 = bx * 128;
    int lane = tid & 63, wid = tid >> 6;
    int mw = wid >> 1, nw = wid & 1;
    f32x4 accT[4][4];   // [j][i]: D[n][m]
#pragma unroll
    for (int j = 0; j < 4; ++j)
#pragma unroll
        for (int i = 0; i < 4; ++i) accT[j][i] = (f32x4){0.f, 0.f, 0.f, 0.f};
    for (int kc = 0; kc < 4; ++kc) {
        __syncthreads();
        for (int i = tid; i < 512; i += 256) {
            int r = i >> 2, q = i & 3;
            *(uint4*)&As[r][q * 8] = *(const uint4*)(A + (size_t)(m0 + r) * TH + kc * 32 + q * 8);
            *(uint4*)&Bs[r][q * 8] = *(const uint4*)(WBp + (size_t)r * TH + kc * 32 + q * 8);
        }
        __syncthreads();
        int ko = (lane >> 4) * 8;
        short8v af[4], bfr[4];
#pragma unroll
        for (int t = 0; t < 4; ++t) {
            af[t] = *(const short8v*)&As[mw * 64 + t * 16 + (lane & 15)][ko];
            bfr[t] = *(const short8v*)&Bs[nw * 64 + t * 16 + (lane & 15)][ko];
        }
#pragma unroll
        for (int j = 0; j < 4; ++j)
#pragma unroll
            for (int i = 0; i < 4; ++i)
                accT[j][i] = __builtin_amdgcn_mfma_f32_16x16x32_bf16(bfr[j], af[i], accT[j][i], 0, 0, 0);
    }
    int rbase = (lane >> 4) * 4, col = lane & 15;
#pragma unroll
    for (int i = 0; i < 4; ++i)
#pragma unroll
        for (int j = 0; j < 4; ++j) {
            int m = m0 + mw * 64 + i * 16 + col;
            int n0 = nw * 64 + j * 16 + rbase;
            ushort4 pk;
            pk.x = to_bf16u(accT[j][i][0]);
            pk.y = to_bf16u(accT[j][i][1]);
            pk.z = to_bf16u(accT[j][i][2]);
            pk.w = to_bf16u(accT[j][i][3]);
            *(ushort4*)(C + (size_t)m * TH + n0) = pk;
        }
}

// alpha = softmax(V@wv over L); g = sum_l alpha*V; coalesced pass-1
__global__ __launch_bounds__(256) void k_pool(const float* __restrict__ V, const float* __restrict__ wv,
                                              float* __restrict__ g) {
    __shared__ float sc[TL];
    __shared__ float red[4];
    int b = blockIdx.x, tid = threadIdx.x;
    int lane = tid & 63, w = tid >> 6;
    for (int l = w; l < TL; l += 4) {
        const float2 v = ((const float2*)(V + (size_t)(b * TL + l) * TH))[lane];
        float a = v.x * wv[2 * lane] + v.y * wv[2 * lane + 1];
        for (int o = 32; o > 0; o >>= 1) a += __shfl_down(a, o, 64);
        if (lane == 0) sc[l] = a;
    }
    __syncthreads();
    float m = (tid < TL) ? sc[tid] : -INFINITY;
    for (int o = 32; o > 0; o >>= 1) m = fmaxf(m, __shfl_down(m, o, 64));
    if ((tid & 63) == 0) red[tid >> 6] = m;
    __syncthreads();
    m = fmaxf(fmaxf(red[0], red[1]), fmaxf(red[2], red[3]));
    __syncthreads();
    float e = (tid < TL) ? expf(sc[tid] - m) : 0.f;
    float s = block_reduce_sum(e, red);
    if (tid < TL) sc[tid] = e / s;
    __syncthreads();
    if (tid < TH) {
        float a = 0.f;
        for (int l = 0; l < TL; ++l) a += sc[l] * V[(size_t)(b * TL + l) * TH + tid];
        g[b * TH + tid] = a;
    }
}

// merged 4x scores over bf16 features
__global__ __launch_bounds__(256) void k_scores4(
        const unsigned short* __restrict__ f0, const float* __restrict__ v0, float* __restrict__ o0, int n0,
        const unsigned short* __restrict__ f1, const float* __restrict__ v1, float* __restrict__ o1, int n1,
        const unsigned short* __restrict__ f2, const float* __restrict__ v2, float* __restrict__ o2, int n2,
        const unsigned short* __restrict__ f3, const float* __restrict__ v3, float* __restrict__ o3, int n3) {
    int t = blockIdx.x * 256 + threadIdx.x;
    const unsigned short* f; const float* vec; float* o;
    if (t < n0 * 4) { f = f0; vec = v0; o = o0; }
    else {
        t -= n0 * 4;
        if (t < n1 * 4) { f = f1; vec = v1; o = o1; }
        else {
            t -= n1 * 4;
            if (t < n2 * 4) { f = f2; vec = v2; o = o2; }
            else {
                t -= n2 * 4;
                if (t >= n3 * 4) return;
                f = f3; vec = v3; o = o3;
            }
        }
    }
    int node = t >> 2, k = t & 3;
    const unsigned short* fp = f + (size_t)node * TH + k * TD;
    const float* vp = vec + k * TD;
    float a = 0.f;
#pragma unroll
    for (int q = 0; q < 4; ++q) {
        uint4 u = *(const uint4*)(fp + q * 8);
        unsigned int ws[4] = {u.x, u.y, u.z, u.w};
#pragma unroll
        for (int p = 0; p < 4; ++p) {
            a += __uint_as_float(ws[p] << 16) * vp[q * 8 + p * 2];
            a += __uint_as_float(ws[p] & 0xffff0000u) * vp[q * 8 + p * 2 + 1];
        }
    }
    o[t] = a;
}

// fused per-dst-node GAT; cur bf16, fs bf16, nxt bf16 out, ACC f32
__global__ __launch_bounds__(128) void k_gat(const unsigned short* __restrict__ tax_cur,
                                             const unsigned short* __restrict__ fs_i, const float* __restrict__ el_i,
                                             const float* __restrict__ er_i, const int* __restrict__ src_i,
                                             const float* __restrict__ bi,
                                             const unsigned short* __restrict__ fs_t, const float* __restrict__ el_t,
                                             const float* __restrict__ er_t, const int* __restrict__ src_t,
                                             const float* __restrict__ bt,
                                             unsigned short* __restrict__ tax_nxt,
                                             float* __restrict__ acc, int hop) {
    int n = blockIdx.x, h = threadIdx.x, k = h >> 5;
    float cur = bfu_to_f(tax_cur[(size_t)n * TH + h]);
    float ti, tt2;
    {
        float er = er_i[n * 4 + k];
        int s[4]; float e[4]; float m = -INFINITY;
#pragma unroll
        for (int j = 0; j < 4; ++j) {
            s[j] = src_i[n * 4 + j];
            float xx = el_i[s[j] * 4 + k] + er;
            e[j] = xx > 0.f ? xx : 0.2f * xx;
            m = fmaxf(m, e[j]);
        }
        float ssum = 0.f, av = 0.f;
#pragma unroll
        for (int j = 0; j < 4; ++j) {
            float a = expf(e[j] - m);
            ssum += a;
            av += a * bfu_to_f(fs_i[(size_t)s[j] * TH + h]);
        }
        ti = fmaxf(av / ssum + cur + bi[h], 0.f);
    }
    {
        float er = er_t[n * 4 + k];
        int s[2]; float e[2]; float m = -INFINITY;
#pragma unroll
        for (int j = 0; j < 2; ++j) {
            s[j] = src_t[n * 2 + j];
            float xx = el_t[s[j] * 4 + k] + er;
            e[j] = xx > 0.f ? xx : 0.2f * xx;
            m = fmaxf(m, e[j]);
        }
        float ssum = 0.f, av = 0.f;
#pragma unroll
        for (int j = 0; j < 2; ++j) {
            float a = expf(e[j] - m);
            ssum += a;
            av += a * bfu_to_f(fs_t[(size_t)s[j] * TH + h]);
        }
        tt2 = fmaxf(av / ssum + cur + bt[h], 0.f);
    }
    float nx = ti + tt2;
    size_t ai = (size_t)n * TH + h;
    tax_nxt[ai] = to_bf16u(nx);
    acc[ai] = (hop == 0) ? nx : acc[ai] + nx;
}

// fused local-gather + mul + LN/softmax/LN + @uni_w -> PB bf16
__global__ __launch_bounds__(128) void k_locfuse(const int* __restrict__ root, const float* __restrict__ acc,
                                                 const float* __restrict__ g,
                                                 const float* __restrict__ liw_g, const float* __restrict__ liw_b,
                                                 const float* __restrict__ int_g, const float* __restrict__ int_b,
                                                 const float* __restrict__ uni_w,
                                                 unsigned short* __restrict__ PB) {
    __shared__ float loc[TFT][TH];
    __shared__ float lm[TFT], wv_[TFT], inten[TH];
    __shared__ float red[2];
    int b = blockIdx.x, tid = threadIdx.x;
    float gv = g[b * TH + tid];
    for (int f = 0; f < TFT; ++f) {
        int r = root[b * TFT + f];
        float v = 0.f;
        if (r != -1) v = acc[(size_t)(b * TTP + (r < 0 ? 0 : r)) * TH + tid] * 0.5f;
        loc[f][tid] = v;
        float s = block_reduce_sum(v * gv, red);
        if (tid == 0) lm[f] = s;
    }
    __syncthreads();
    if (tid < TFT) {
        float mean = 0.f;
        for (int f = 0; f < TFT; ++f) mean += lm[f];
        mean *= (1.f / TFT);
        float var = 0.f;
        for (int f = 0; f < TFT; ++f) { float d = lm[f] - mean; var += d * d; }
        var *= (1.f / TFT);
        float ln = (lm[tid] - mean) * rsqrtf(var + 1e-8f) * liw_g[tid] + liw_b[tid];
        wv_[tid] = (lm[tid] != 0.f) ? ln : -INFINITY;
    }
    __syncthreads();
    if (tid < TFT) {
        float mx = -INFINITY;
        for (int f = 0; f < TFT; ++f) mx = fmaxf(mx, wv_[f]);
        float s = 0.f;
        for (int f = 0; f < TFT; ++f) s += expf(wv_[f] - mx);
        lm[tid] = expf(wv_[tid] - mx) / s;
    }
    __syncthreads();
    float ip = gv;
    for (int f = 0; f < TFT; ++f) ip += lm[f] * loc[f][tid];
    float mean = block_reduce_sum(ip, red) * (1.f / TH);
    float d = ip - mean;
    float var = block_reduce_sum(d * d, red) * (1.f / TH);
    inten[tid] = d * rsqrtf(var + 1e-8f) * int_g[tid] + int_b[tid];
    __syncthreads();
    float a = 0.f;
    for (int hp = 0; hp < TH; ++hp) a += inten[hp] * uni_w[hp * TH + tid];
    PB[(size_t)b * TH + tid] = to_bf16u(a);
}

// out[b,i] = PB[b,:] . E[i,:]; E converted in-LDS; full batch swept per item-tile
__global__ __launch_bounds__(256) void k_final_m2(const unsigned short* __restrict__ PB,
                                                  const float* __restrict__ E,
                                                  float* __restrict__ out) {
    __shared__ unsigned short Bs[128][136];
    int tid = threadIdx.x;
    int i0 = blockIdx.x * 128;
    for (int i = tid; i < 2048; i += 256) {
        int r = i >> 4, q = i & 15;
        int it = i0 + r;
        float4 a = {0.f, 0.f, 0.f, 0.f}, b = {0.f, 0.f, 0.f, 0.f};
        if (it < TITEMS) {
            a = *(const float4*)(E + (size_t)it * TH + q * 8);
            b = *(const float4*)(E + (size_t)it * TH + q * 8 + 4);
        }
        ushort4 u0, u1;
        u0.x = to_bf16u(a.x); u0.y = to_bf16u(a.y); u0.z = to_bf16u(a.z); u0.w = to_bf16u(a.w);
        u1.x = to_bf16u(b.x); u1.y = to_bf16u(b.y); u1.z = to_bf16u(b.z); u1.w = to_bf16u(b.w);
        *(ushort4*)&Bs[r][q * 8] = u0;
        *(ushort4*)&Bs[r][q * 8 + 4] = u1;
    }
    __syncthreads();
    int lane = tid & 63, wid = tid >> 6;
    int mw = wid >> 1, nw = wid & 1;
    int rbase = (lane >> 4) * 4, col = lane & 15;
#pragma unroll 1
    for (int b0 = 0; b0 < TB; b0 += 128) {
        f32x4 acc[4][4];
#pragma unroll
        for (int i = 0; i < 4; ++i)
#pragma unroll
            for (int j = 0; j < 4; ++j) acc[i][j] = (f32x4){0.f, 0.f, 0.f, 0.f};
#pragma unroll
        for (int kc = 0; kc < 4; ++kc) {
            int ko = kc * 32 + (lane >> 4) * 8;
            short8v af[4], bfr[4];
#pragma unroll
            for (int t = 0; t < 4; ++t) {
                af[t] = *(const short8v*)(PB + (size_t)(b0 + mw * 64 + t * 16 + (lane & 15)) * TH + ko);
                bfr[t] = *(const short8v*)&Bs[nw * 64 + t * 16 + (lane & 15)][ko];
            }
#pragma unroll
            for (int i = 0; i < 4; ++i)
#pragma unroll
                for (int j = 0; j < 4; ++j)
                    acc[i][j] = __builtin_amdgcn_mfma_f32_16x16x32_bf16(af[i], bfr[j], acc[i][j], 0, 0, 0);
        }
#pragma unroll
        for (int i = 0; i < 4; ++i)
#pragma unroll
            for (int j = 0; j < 4; ++j) {
                int ii = i0 + nw * 64 + j * 16 + col;
                if (ii < TITEMS) {
#pragma unroll
                    for (int r = 0; r < 4; ++r)
                        out[(size_t)(b0 + mw * 64 + i * 16 + rbase + r) * TITEMS + ii] = acc[i][j][r];
                }
            }
    }
}

extern "C" void kernel_launch(void* const* d_in, const int* in_sizes, int n_in,
                              void* d_out, int out_size, void* d_ws, size_t ws_size,
                              hipStream_t stream) {
    const int*   seq        = (const int*)d_in[0];
    const int*   root       = (const int*)d_in[1];
    const int*   i2t_src    = (const int*)d_in[3];
    const int*   t2t_src    = (const int*)d_in[5];
    const int*   item_ids   = (const int*)d_in[6];
    const int*   tax_ids    = (const int*)d_in[7];
    const float* item_embed = (const float*)d_in[8];
    const float* tax_embed  = (const float*)d_in[9];
    const float* scb_ln_g   = (const float*)d_in[10];
    const float* scb_ln_b   = (const float*)d_in[11];
    const float* scb_w1     = (const float*)d_in[12];
    const float* scb_w2     = (const float*)d_in[13];
    const float* fcb_ln_g   = (const float*)d_in[14];
    const float* fcb_ln_b   = (const float*)d_in[15];
    const float* fcb_w1     = (const float*)d_in[16];
    const float* fcb_w2     = (const float*)d_in[17];
    const float* fcb_w3     = (const float*)d_in[18];
    const float* wv         = (const float*)d_in[19];
    const float* gi_w       = (const float*)d_in[20];
    const float* gi_al      = (const float*)d_in[21];
    const float* gi_ar      = (const float*)d_in[22];
    const float* gi_b       = (const float*)d_in[23];
    const float* gt_w       = (const float*)d_in[24];
    const float* gt_al      = (const float*)d_in[25];
    const float* gt_ar      = (const float*)d_in[26];
    const float* gt_b       = (const float*)d_in[27];
    const float* liw_g      = (const float*)d_in[28];
    const float* liw_b      = (const float*)d_in[29];
    const float* int_g      = (const float*)d_in[30];
    const float* int_b      = (const float*)d_in[31];
    const float* uni_w      = (const float*)d_in[32];

    char* w = (char*)d_ws;
    float* V     = (float*)(w + 0);           // 52.4MB (V / FSIB)
    float* NV    = (float*)(w + 52428800);    // 52.4MB (nv / ITEMHB)
    unsigned short* FSIB   = (unsigned short*)(w + 0);
    unsigned short* ITEMHB = (unsigned short*)(w + 52428800);
    // mixer-scb phase:
    unsigned short* NVT = (unsigned short*)(w + 104857600);  // 29.4MB
    unsigned short* T   = (unsigned short*)(w + 134217728);  // 33.6MB
    unsigned short* W1T = (unsigned short*)(w + 167772160);  // 229KB
    unsigned short* W2T = (unsigned short*)(w + 168001536);  // 213KB
    // mixer-fcb phase:
    unsigned short* ZB  = (unsigned short*)(w + 104857600);  // 26.2MB (aliases NVT, dead)
    // GAT phase:
    unsigned short* TAXB0 = (unsigned short*)(w + 104857600);
    unsigned short* TAXB1 = (unsigned short*)(w + 113246208);
    float* ACC   = (float*)(w + 138412032);
    unsigned short* FDIB = (unsigned short*)(w + 155189248);
    unsigned short* FSTB = (unsigned short*)(w + 171966464);
    float* ELI   = (float*)(w + 188743680);
    float* ERI   = (float*)(w + 190382080);
    float* ELT   = (float*)(w + 190906368);
    float* ERT   = (float*)(w + 191430656);
    float* G     = (float*)(w + 200343552);
    unsigned short* WB = (unsigned short*)(w + 191954944);   // 262KB converted weights
    unsigned short* PB = (unsigned short*)(w + 200671232);   // 128KB
    if (ws_size < 200933376ull) return;

    // one-time weight conversion
    k_wcvt<<<512, 256, 0, stream>>>(fcb_w1, fcb_w2, fcb_w3, gi_w, gt_w, WB);

    // ---- global intention (mixer) ----
    for (int nb = 0; nb < 2; ++nb) {
        // nb=0: gather fused into lnt (reads item_embed[seq]); nb=1: reads V
        k_lnt<<<dim3(4, TB), 128, 0, stream>>>(V, nb == 0 ? seq : nullptr, item_embed,
                                               scb_ln_g + nb * TH, scb_ln_b + nb * TH, NV, NVT);
        k_wscb<<<720, 256, 0, stream>>>(scb_w1 + nb * TL * TSH, scb_w2 + nb * TSH * TL, W1T, W2T);
        for (int bh = 0; bh < 2; ++bh) {
            k_mm1<<<dim3(4, 256), 256, 0, stream>>>(NVT, W1T, T, bh);
            k_mm2l<<<dim3(4, 256), 256, 0, stream>>>(T, W2T, NV,
                                                     fcb_ln_g + nb * TH, fcb_ln_b + nb * TH, bh);
        }
        k_ffuse<<<1024, 256, 0, stream>>>(NV, WB + nb * 8192, WB + 16384 + nb * 8192, ZB,
                                          TB * TL * 4 / 64);
        k_gmm_b<<<TB * TL / 128, 256, 0, stream>>>(ZB, WB + 32768 + nb * 16384, NV, V);
    }
    k_pool<<<TB, 256, 0, stream>>>(V, wv, G);

    // ---- local intention (GAT, bf16 features) ----
    k_gather_bf<<<(TNI * 16 + 255) / 256, 256, 0, stream>>>(item_embed, item_ids, ITEMHB, TNI);
    k_gather_bf<<<(TNT * 16 + 255) / 256, 256, 0, stream>>>(tax_embed, tax_ids, TAXB0, TNT);

    unsigned short* curb = TAXB0;
    unsigned short* nxtb = TAXB1;
    for (int hop = 0; hop < 2; ++hop) {
        const unsigned short* WiB = WB + 65536 + hop * 16384;
        const unsigned short* WtB = WB + 98304 + hop * 16384;
        k_gmm3<<<TNI / 128 + 2 * (TNT / 128), 256, 0, stream>>>(
            ITEMHB, WiB, FSIB, TNI / 128,
            curb, WiB, FDIB, TNT / 128,
            curb, WtB, FSTB);
        int total = (TNI + 3 * TNT) * TNH;
        k_scores4<<<(total + 255) / 256, 256, 0, stream>>>(
            FSIB, gi_al + hop * TH, ELI, TNI,
            FDIB, gi_ar + hop * TH, ERI, TNT,
            FSTB, gt_al + hop * TH, ELT, TNT,
            FSTB, gt_ar + hop * TH, ERT, TNT);
        k_gat<<<TNT, 128, 0, stream>>>(curb, FSIB, ELI, ERI, i2t_src, gi_b + hop * TH,
                                       FSTB, ELT, ERT, t2t_src, gt_b + hop * TH, nxtb, ACC, hop);
        unsigned short* tmp = curb; curb = nxtb; nxtb = tmp;
    }

    // ---- fuse + final ----
    k_locfuse<<<TB, 128, 0, stream>>>(root, ACC, G, liw_g, liw_b, int_g, int_b, uni_w, PB);
    k_final_m2<<<TIPAD / 128, 256, 0, stream>>>(PB, item_embed, (float*)d_out);
}

// Round 14
// 951.005 us; speedup vs baseline: 1.1376x; 1.0533x over previous
//
#include <hip/hip_runtime.h>
#include <hip/hip_bf16.h>

// ---- model dims ----
constexpr int TB = 512, TL = 200, TH = 128, TNH = 4, TD = 32;
constexpr int TFT = 32, TTP = 64, TIP = 200;
constexpr int TSH = 512, TFH = 256;
constexpr int TITEMS = 100001;
constexpr int TNT = TB * TTP;   // 32768
constexpr int TNI = TB * TIP;   // 102400
constexpr int TLP = 224;        // L padded (K of scb GEMM1)
constexpr int TIPAD = 100096;   // items padded to 128

typedef __attribute__((ext_vector_type(8))) short short8v;
typedef __attribute__((ext_vector_type(4))) float f32x4;

// tanh-form gelu, |err| <= ~3e-4 (below bf16 quantization of the result)
__device__ inline float gelu_fast(float x) {
    float u = x + 0.044715f * x * x * x;
    float e = exp2f(-2.302208f * u);
    return x / (1.0f + e);
}
__device__ inline unsigned short to_bf16u(float x) {
    __hip_bfloat16 h = __float2bfloat16(x);
    return *reinterpret_cast<unsigned short*>(&h);
}
__device__ inline float bfu_to_f(unsigned short u) {
    unsigned int x = ((unsigned int)u) << 16;
    return __uint_as_float(x);
}

__device__ inline float block_reduce_sum(float v, float* red) {
    for (int o = 32; o > 0; o >>= 1) v += __shfl_down(v, o, 64);
    int nw = blockDim.x >> 6;
    if ((threadIdx.x & 63) == 0) red[threadIdx.x >> 6] = v;
    __syncthreads();
    float r = 0.f;
    for (int w = 0; w < nw; ++w) r += red[w];
    __syncthreads();
    return r;
}

// merged double gather: out[r,:] = bf16(table[idx[r],:]) for two tables
__global__ __launch_bounds__(256) void k_gather2(const float* __restrict__ tab0,
                                                 const int* __restrict__ idx0,
                                                 unsigned short* __restrict__ out0, int n0,
                                                 const float* __restrict__ tab1,
                                                 const int* __restrict__ idx1,
                                                 unsigned short* __restrict__ out1, int n1) {
    int e = blockIdx.x * 256 + threadIdx.x;
    const float* tab; const int* idx; unsigned short* out;
    if (e < n0 * 16) { tab = tab0; idx = idx0; out = out0; }
    else {
        e -= n0 * 16;
        if (e >= n1 * 16) return;
        tab = tab1; idx = idx1; out = out1;
    }
    int r = e >> 4, c = e & 15;
    const float4 a = ((const float4*)tab)[(size_t)idx[r] * 32 + c * 2];
    const float4 b = ((const float4*)tab)[(size_t)idx[r] * 32 + c * 2 + 1];
    uint4 u;
    u.x = (unsigned int)to_bf16u(a.x) | ((unsigned int)to_bf16u(a.y) << 16);
    u.y = (unsigned int)to_bf16u(a.z) | ((unsigned int)to_bf16u(a.w) << 16);
    u.z = (unsigned int)to_bf16u(b.x) | ((unsigned int)to_bf16u(b.y) << 16);
    u.w = (unsigned int)to_bf16u(b.z) | ((unsigned int)to_bf16u(b.w) << 16);
    *(uint4*)(out + (size_t)e * 8) = u;
}

// one-time conversion of small weights to bf16, pre-transposed to [n][k]
__global__ __launch_bounds__(256) void k_wcvt(const float* __restrict__ fw1, const float* __restrict__ fw2,
                                              const float* __restrict__ fw3, const float* __restrict__ giw,
                                              const float* __restrict__ gtw, unsigned short* __restrict__ WB) {
    int idx = blockIdx.x * 256 + threadIdx.x;  // 0..131071
    float v;
    if (idx < 16384) {           // fw1b[nb][n=256][k=32]
        int nb = idx >> 13, r = idx & 8191, n = r >> 5, k = r & 31;
        v = fw1[(size_t)nb * 8192 + k * 256 + n];
    } else if (idx < 32768) {    // fw2b[nb][n=32][k=256]
        int t = idx - 16384;
        int nb = t >> 13, r = t & 8191, n = r >> 8, k = r & 255;
        v = fw2[(size_t)nb * 8192 + k * 32 + n];
    } else if (idx < 65536) {    // fw3b[nb][n=128][k=128]
        int t = idx - 32768;
        int nb = t >> 14, r = t & 16383, n = r >> 7, k = r & 127;
        v = fw3[(size_t)nb * 16384 + k * 128 + n];
    } else if (idx < 98304) {    // giwb[hop][n][k]
        int t = idx - 65536;
        int hop = t >> 14, r = t & 16383, n = r >> 7, k = r & 127;
        v = giw[(size_t)hop * 16384 + k * 128 + n];
    } else {                     // gtwb[hop][n][k]
        int t = idx - 98304;
        int hop = t >> 14, r = t & 16383, n = r >> 7, k = r & 127;
        v = gtw[(size_t)hop * 16384 + k * 128 + n];
    }
    WB[idx] = to_bf16u(v);
}

// both nb scb weight transposes upfront
__global__ __launch_bounds__(256) void k_wscb2(const float* __restrict__ w1, const float* __restrict__ w2,
                                               unsigned short* __restrict__ W1T,
                                               unsigned short* __restrict__ W2T) {
    int bx = blockIdx.x;
    if (bx < 1024) {
        int nb = bx >> 9, s = bx & 511, l = threadIdx.x;
        if (l < TLP)
            W1T[(size_t)nb * 114688 + (size_t)s * TLP + l] =
                to_bf16u(l < TL ? w1[(size_t)nb * 102400 + l * TSH + s] : 0.f);
    } else {
        int t = bx - 1024;           // 0..415
        int nb = t / 208, l = t % 208;
        for (int it = 0; it < 2; ++it) {
            int s = it * 256 + threadIdx.x;
            W2T[(size_t)nb * 106496 + (size_t)l * TSH + s] =
                to_bf16u(l < TL ? w2[(size_t)nb * 102400 + s * TL + l] : 0.f);
        }
    }
}

// fused [gather +] LN + bf16 transpose: src -> NV f32 (LN'd, in-place safe) + NVT bf16
__global__ __launch_bounds__(128) void k_lnt(const float* __restrict__ V,
                                             const int* __restrict__ seqp, const float* __restrict__ tab,
                                             const float* __restrict__ g, const float* __restrict__ b,
                                             float* __restrict__ NV, unsigned short* __restrict__ NVT) {
    __shared__ float tl[64][129];
    __shared__ float mrow[64], irow[64];
    int bb = blockIdx.y, l0 = blockIdx.x * 64, tid = threadIdx.x;
    for (int i = tid; i < 2048; i += 128) {
        int r = i >> 5, c = i & 31;
        int l = l0 + r;
        float4 v = {0.f, 0.f, 0.f, 0.f};
        if (l < TL) {
            const float* src = seqp ? (tab + (size_t)seqp[bb * TL + l] * TH)
                                    : (V + ((size_t)bb * TL + l) * TH);
            v = *(const float4*)(src + c * 4);
        }
        tl[r][c * 4 + 0] = v.x; tl[r][c * 4 + 1] = v.y;
        tl[r][c * 4 + 2] = v.z; tl[r][c * 4 + 3] = v.w;
    }
    __syncthreads();
    {
        int row = tid >> 1, half = tid & 1;
        float s = 0.f, sq = 0.f;
        for (int k = 0; k < 64; ++k) {
            float v = tl[row][half * 64 + k];
            s += v; sq += v * v;
        }
        s += __shfl_xor(s, 1);
        sq += __shfl_xor(sq, 1);
        if (half == 0) {
            float mean = s * (1.f / 128.f);
            mrow[row] = mean;
            irow[row] = rsqrtf(sq * (1.f / 128.f) - mean * mean + 1e-8f);
        }
    }
    __syncthreads();
    for (int i = tid; i < 2048; i += 128) {
        int r = i >> 5, c = i & 31;
        int l = l0 + r;
        float4 o = {0.f, 0.f, 0.f, 0.f};
        if (l < TL) {
            float4 v = *(float4*)&tl[r][c * 4];
            float m = mrow[r], inv = irow[r];
            const float4 gg = ((const float4*)g)[c];
            const float4 bv = ((const float4*)b)[c];
            o.x = (v.x - m) * inv * gg.x + bv.x;
            o.y = (v.y - m) * inv * gg.y + bv.y;
            o.z = (v.z - m) * inv * gg.z + bv.z;
            o.w = (v.w - m) * inv * gg.w + bv.w;
            *(float4*)(NV + ((size_t)bb * TL + l) * TH + c * 4) = o;
        }
        *(float4*)&tl[r][c * 4] = o;
    }
    __syncthreads();
    int h = tid;
    int ng = (l0 + 64 > TLP) ? (TLP - l0) / 8 : 8;
    for (int lg = 0; lg < ng; ++lg) {
        uint4 u;
        unsigned int p[4];
#pragma unroll
        for (int q = 0; q < 4; ++q) {
            unsigned short ua = to_bf16u(tl[lg * 8 + q * 2 + 0][h]);
            unsigned short ub = to_bf16u(tl[lg * 8 + q * 2 + 1][h]);
            p[q] = (unsigned int)ua | ((unsigned int)ub << 16);
        }
        u.x = p[0]; u.y = p[1]; u.z = p[2]; u.w = p[3];
        *(uint4*)(NVT + ((size_t)bb * TH + h) * TLP + l0 + lg * 8) = u;
    }
}

// scb GEMM1 (full batch grid): T[b][h][s] = gelu( sum_l NVT[b][h][l] * w1[l][s] )
__global__ __launch_bounds__(256) void k_mm1(const unsigned short* __restrict__ NVT,
                                             const unsigned short* __restrict__ W1T,
                                             unsigned short* __restrict__ T) {
    __shared__ unsigned short As[128][40];
    __shared__ unsigned short Bs[128][40];
    int tid = threadIdx.x;
    int b = blockIdx.y;
    int s0 = blockIdx.x * 128;
    int lane = tid & 63, wid = tid >> 6;
    int mw = wid >> 1, nw = wid & 1;
    f32x4 accT[4][4];   // [j][i]: D[s][h] (swapped operands)
#pragma unroll
    for (int j = 0; j < 4; ++j)
#pragma unroll
        for (int i = 0; i < 4; ++i) accT[j][i] = (f32x4){0.f, 0.f, 0.f, 0.f};
    const unsigned short* Abase = NVT + (size_t)b * TH * TLP;
    const unsigned short* Bbase = W1T + (size_t)s0 * TLP;
    for (int kc = 0; kc < 7; ++kc) {
        __syncthreads();
        for (int i = tid; i < 512; i += 256) {
            int r = i >> 2, q = i & 3;
            *(uint4*)&As[r][q * 8] = *(const uint4*)(Abase + (size_t)r * TLP + kc * 32 + q * 8);
            *(uint4*)&Bs[r][q * 8] = *(const uint4*)(Bbase + (size_t)r * TLP + kc * 32 + q * 8);
        }
        __syncthreads();
        int ko = (lane >> 4) * 8;
        short8v af[4], bfr[4];
#pragma unroll
        for (int t = 0; t < 4; ++t) {
            af[t] = *(const short8v*)&As[mw * 64 + t * 16 + (lane & 15)][ko];
            bfr[t] = *(const short8v*)&Bs[nw * 64 + t * 16 + (lane & 15)][ko];
        }
#pragma unroll
        for (int j = 0; j < 4; ++j)
#pragma unroll
            for (int i = 0; i < 4; ++i)
                accT[j][i] = __builtin_amdgcn_mfma_f32_16x16x32_bf16(bfr[j], af[i], accT[j][i], 0, 0, 0);
    }
    int rbase = (lane >> 4) * 4, col = lane & 15;
#pragma unroll
    for (int i = 0; i < 4; ++i)
#pragma unroll
        for (int j = 0; j < 4; ++j) {
            int h = mw * 64 + i * 16 + col;
            int sb = s0 + nw * 64 + j * 16 + rbase;
            ushort4 pk;
            pk.x = to_bf16u(gelu_fast(accT[j][i][0]));
            pk.y = to_bf16u(gelu_fast(accT[j][i][1]));
            pk.z = to_bf16u(gelu_fast(accT[j][i][2]));
            pk.w = to_bf16u(gelu_fast(accT[j][i][3]));
            *(ushort4*)(T + ((size_t)b * TH + h) * TSH + sb) = pk;
        }
}

// scb GEMM2 + fcb LN fused (full batch grid): vs = NV + T@w2; NV <- LN(vs) in place
__global__ __launch_bounds__(256) void k_mm2l(const unsigned short* __restrict__ T,
                                              const unsigned short* __restrict__ W2T,
                                              float* __restrict__ NV,
                                              const float* __restrict__ lg, const float* __restrict__ lb) {
    __shared__ unsigned short As[128][40];
    __shared__ unsigned short Bs[64][40];
    __shared__ float vsl[64][132];
    __shared__ float mrow[64], irow[64];
    int tid = threadIdx.x;
    int b = blockIdx.y;
    int l0 = blockIdx.x * 64;
    int lane = tid & 63, wid = tid >> 6;
    f32x4 acc[2][4];
#pragma unroll
    for (int i = 0; i < 2; ++i)
#pragma unroll
        for (int j = 0; j < 4; ++j) acc[i][j] = (f32x4){0.f, 0.f, 0.f, 0.f};
    const unsigned short* Abase = T + (size_t)b * TH * TSH;
    for (int kc = 0; kc < 16; ++kc) {
        __syncthreads();
        for (int i = tid; i < 512; i += 256) {
            int r = i >> 2, q = i & 3;
            *(uint4*)&As[r][q * 8] = *(const uint4*)(Abase + (size_t)r * TSH + kc * 32 + q * 8);
        }
        {
            int r = tid >> 2, q = tid & 3;
            int l = l0 + r;
            uint4 v = {0u, 0u, 0u, 0u};
            if (l < 208) v = *(const uint4*)(W2T + (size_t)l * TSH + kc * 32 + q * 8);
            *(uint4*)&Bs[r][q * 8] = v;
        }
        __syncthreads();
        int ko = (lane >> 4) * 8;
        short8v af[2], bfr[4];
#pragma unroll
        for (int t = 0; t < 2; ++t)
            af[t] = *(const short8v*)&As[wid * 32 + t * 16 + (lane & 15)][ko];
#pragma unroll
        for (int j = 0; j < 4; ++j)
            bfr[j] = *(const short8v*)&Bs[j * 16 + (lane & 15)][ko];
#pragma unroll
        for (int i = 0; i < 2; ++i)
#pragma unroll
            for (int j = 0; j < 4; ++j)
                acc[i][j] = __builtin_amdgcn_mfma_f32_16x16x32_bf16(af[i], bfr[j], acc[i][j], 0, 0, 0);
    }
    int rbase = (lane >> 4) * 4, col = lane & 15;
#pragma unroll
    for (int i = 0; i < 2; ++i)
#pragma unroll
        for (int j = 0; j < 4; ++j) {
            int l = l0 + j * 16 + col;
            int h0 = wid * 32 + i * 16 + rbase;
            float4 res = {0.f, 0.f, 0.f, 0.f};
            if (l < TL) res = *(const float4*)(NV + ((size_t)b * TL + l) * TH + h0);
            float4 o;
            o.x = acc[i][j][0] + res.x;
            o.y = acc[i][j][1] + res.y;
            o.z = acc[i][j][2] + res.z;
            o.w = acc[i][j][3] + res.w;
            *(float4*)&vsl[j * 16 + col][h0] = o;
        }
    __syncthreads();
    int row = tid >> 2, q = tid & 3;
    {
        float s = 0.f, sq = 0.f;
        for (int k = 0; k < 32; ++k) {
            float v = vsl[row][q * 32 + k];
            s += v; sq += v * v;
        }
        s += __shfl_xor(s, 1); s += __shfl_xor(s, 2);
        sq += __shfl_xor(sq, 1); sq += __shfl_xor(sq, 2);
        if (q == 0) {
            float mean = s * (1.f / 128.f);
            mrow[row] = mean;
            irow[row] = rsqrtf(sq * (1.f / 128.f) - mean * mean + 1e-8f);
        }
    }
    __syncthreads();
    {
        int l = l0 + row;
        if (l < TL) {
            float mean = mrow[row], inv = irow[row];
            float* dst = NV + ((size_t)b * TL + l) * TH + q * 32;
#pragma unroll
            for (int k4 = 0; k4 < 8; ++k4) {
                float4 v = *(float4*)&vsl[row][q * 32 + k4 * 4];
                const float4 gg = ((const float4*)lg)[q * 8 + k4];
                const float4 bv = ((const float4*)lb)[q * 8 + k4];
                float4 o;
                o.x = (v.x - mean) * inv * gg.x + bv.x;
                o.y = (v.y - mean) * inv * gg.y + bv.y;
                o.z = (v.z - mean) * inv * gg.z + bv.z;
                o.w = (v.w - mean) * inv * gg.w + bv.w;
                *(float4*)(dst + k4 * 4) = o;
            }
        }
    }
}

// fused fcb stage1+2; PERSISTENT grid-stride over 64-row tiles; weights staged once
__global__ __launch_bounds__(256) void k_ffuse(const float* __restrict__ NV,
                                               const unsigned short* __restrict__ FW1B,
                                               const unsigned short* __restrict__ FW2B,
                                               unsigned short* __restrict__ Z, int ntiles) {
    __shared__ unsigned short As[64][40];
    __shared__ unsigned short Bs2[32 * 264];
    __shared__ unsigned short Yl[64 * 264];
    int tid = threadIdx.x;
    int lane = tid & 63, wid = tid >> 6;
    int col = lane & 15, rbase = (lane >> 4) * 4, ko = (lane >> 4) * 8;
    for (int i = tid; i < 1024; i += 256) {
        int r = i >> 2, q = i & 3;
        *(uint4*)&Yl[r * 40 + q * 8] = *(const uint4*)(FW1B + r * 32 + q * 8);
    }
    for (int i = tid; i < 1024; i += 256) {
        int r = i >> 5, q = i & 31;
        *(uint4*)&Bs2[r * 264 + q * 8] = *(const uint4*)(FW2B + r * 256 + q * 8);
    }
    __syncthreads();
    short8v bfr[4];
#pragma unroll
    for (int t = 0; t < 4; ++t)
        bfr[t] = *(const short8v*)&Yl[(wid * 64 + t * 16 + col) * 40 + ko];
    __syncthreads();
    int mrow = wid * 16 + col;
    int sw2 = ((mrow >> 2) & 7) << 3;
    for (int tile = blockIdx.x; tile < ntiles; tile += gridDim.x) {
        int m0 = tile * 64;
        for (int i = tid; i < 512; i += 256) {
            int r = i >> 3, q = i & 7;
            const float4 v = *(const float4*)(NV + (size_t)(m0 + r) * 32 + q * 4);
            ushort4 u;
            u.x = to_bf16u(v.x); u.y = to_bf16u(v.y); u.z = to_bf16u(v.z); u.w = to_bf16u(v.w);
            *(ushort4*)&As[r][q * 4] = u;
        }
        __syncthreads();
        {
            short8v af[4];
#pragma unroll
            for (int t = 0; t < 4; ++t)
                af[t] = *(const short8v*)&As[t * 16 + col][ko];
            f32x4 yt[4][4];
#pragma unroll
            for (int j = 0; j < 4; ++j)
#pragma unroll
                for (int i = 0; i < 4; ++i) yt[j][i] = (f32x4){0.f, 0.f, 0.f, 0.f};
#pragma unroll
            for (int j = 0; j < 4; ++j)
#pragma unroll
                for (int i = 0; i < 4; ++i)
                    yt[j][i] = __builtin_amdgcn_mfma_f32_16x16x32_bf16(bfr[j], af[i], yt[j][i], 0, 0, 0);
#pragma unroll
            for (int i = 0; i < 4; ++i)
#pragma unroll
                for (int j = 0; j < 4; ++j) {
                    int m = i * 16 + col;
                    int n0 = wid * 64 + j * 16 + rbase;
                    ushort4 pk;
                    pk.x = to_bf16u(gelu_fast(yt[j][i][0]));
                    pk.y = to_bf16u(gelu_fast(yt[j][i][1]));
                    pk.z = to_bf16u(gelu_fast(yt[j][i][2]));
                    pk.w = to_bf16u(gelu_fast(yt[j][i][3]));
                    int idx = (m * 264 + n0) ^ (((m >> 2) & 7) << 3);
                    *(ushort4*)&Yl[idx] = pk;
                }
        }
        __syncthreads();
        {
            f32x4 acc2[2];
            acc2[0] = (f32x4){0.f, 0.f, 0.f, 0.f};
            acc2[1] = (f32x4){0.f, 0.f, 0.f, 0.f};
            for (int kc = 0; kc < 8; ++kc) {
                int ko2 = kc * 32 + ko;
                short8v a2 = *(const short8v*)&Yl[(mrow * 264 + ko2) ^ sw2];
                short8v b0 = *(const short8v*)&Bs2[col * 264 + ko2];
                short8v b1 = *(const short8v*)&Bs2[(16 + col) * 264 + ko2];
                acc2[0] = __builtin_amdgcn_mfma_f32_16x16x32_bf16(a2, b0, acc2[0], 0, 0, 0);
                acc2[1] = __builtin_amdgcn_mfma_f32_16x16x32_bf16(a2, b1, acc2[1], 0, 0, 0);
            }
#pragma unroll
            for (int j = 0; j < 2; ++j)
#pragma unroll
                for (int r = 0; r < 4; ++r)
                    Z[(size_t)(m0 + wid * 16 + rbase + r) * 32 + j * 16 + col] =
                        to_bf16u(acc2[j][r]);
        }
        __syncthreads();
    }
}

// C f32 [N,128] = A[N,128](bf16) @ WB[n][k](bf16) (+R f32, in-place safe C==R)
__global__ __launch_bounds__(256) void k_gmm_b(const unsigned short* __restrict__ A,
                                               const unsigned short* __restrict__ WB,
                                               const float* __restrict__ R,
                                               float* __restrict__ C) {
    __shared__ unsigned short As[128][40];
    __shared__ unsigned short Bs[128][40];
    int tid = threadIdx.x;
    int m0 = blockIdx.x * 128;
    int lane = tid & 63, wid = tid >> 6;
    int mw = wid >> 1, nw = wid & 1;
    f32x4 acc[4][4];
#pragma unroll
    for (int i = 0; i < 4; ++i)
#pragma unroll
        for (int j = 0; j < 4; ++j) acc[i][j] = (f32x4){0.f, 0.f, 0.f, 0.f};
    for (int kc = 0; kc < 4; ++kc) {
        __syncthreads();
        for (int i = tid; i < 512; i += 256) {
            int r = i >> 2, q = i & 3;
            *(uint4*)&As[r][q * 8] = *(const uint4*)(A + (size_t)(m0 + r) * TH + kc * 32 + q * 8);
            *(uint4*)&Bs[r][q * 8] = *(const uint4*)(WB + (size_t)r * TH + kc * 32 + q * 8);
        }
        __syncthreads();
        int ko = (lane >> 4) * 8;
        short8v af[4], bfr[4];
#pragma unroll
        for (int t = 0; t < 4; ++t) {
            af[t] = *(const short8v*)&As[mw * 64 + t * 16 + (lane & 15)][ko];
            bfr[t] = *(const short8v*)&Bs[nw * 64 + t * 16 + (lane & 15)][ko];
        }
#pragma unroll
        for (int i = 0; i < 4; ++i)
#pragma unroll
            for (int j = 0; j < 4; ++j)
                acc[i][j] = __builtin_amdgcn_mfma_f32_16x16x32_bf16(af[i], bfr[j], acc[i][j], 0, 0, 0);
    }
    int rbase = (lane >> 4) * 4, col = lane & 15;
#pragma unroll
    for (int i = 0; i < 4; ++i)
#pragma unroll
        for (int j = 0; j < 4; ++j) {
            int n = nw * 64 + j * 16 + col;
#pragma unroll
            for (int r = 0; r < 4; ++r) {
                size_t off = (size_t)(m0 + mw * 64 + i * 16 + rbase + r) * TH + n;
                float v = acc[i][j][r];
                if (R) v += R[off];
                C[off] = v;
            }
        }
}

// merged 3x GAT feature GEMMs: C bf16 = A @ WB (packed stores)
__global__ __launch_bounds__(256) void k_gmm3(
        const unsigned short* __restrict__ A0, const unsigned short* __restrict__ W0,
        unsigned short* __restrict__ C0, int nb0,
        const unsigned short* __restrict__ A1, const unsigned short* __restrict__ W1,
        unsigned short* __restrict__ C1, int nb1,
        const unsigned short* __restrict__ A2, const unsigned short* __restrict__ W2,
        unsigned short* __restrict__ C2) {
    __shared__ unsigned short As[128][40];
    __shared__ unsigned short Bs[128][40];
    int bx = blockIdx.x;
    const unsigned short *A, *WBp;
    unsigned short* C;
    if (bx < nb0) { A = A0; WBp = W0; C = C0; }
    else if (bx - nb0 < nb1) { bx -= nb0; A = A1; WBp = W1; C = C1; }
    else { bx -= nb0 + nb1; A = A2; WBp = W2; C = C2; }
    int tid = threadIdx.x;
    int m0 = bx * 128;
    int lane = tid & 63, wid = tid >> 6;
    int mw = wid >> 1, nw = wid & 1;
    f32x4 accT[4][4];   // [j][i]: D[n][m]
#pragma unroll
    for (int j = 0; j < 4; ++j)
#pragma unroll
        for (int i = 0; i < 4; ++i) accT[j][i] = (f32x4){0.f, 0.f, 0.f, 0.f};
    for (int kc = 0; kc < 4; ++kc) {
        __syncthreads();
        for (int i = tid; i < 512; i += 256) {
            int r = i >> 2, q = i & 3;
            *(uint4*)&As[r][q * 8] = *(const uint4*)(A + (size_t)(m0 + r) * TH + kc * 32 + q * 8);
            *(uint4*)&Bs[r][q * 8] = *(const uint4*)(WBp + (size_t)r * TH + kc * 32 + q * 8);
        }
        __syncthreads();
        int ko = (lane >> 4) * 8;
        short8v af[4], bfr[4];
#pragma unroll
        for (int t = 0; t < 4; ++t) {
            af[t] = *(const short8v*)&As[mw * 64 + t * 16 + (lane & 15)][ko];
            bfr[t] = *(const short8v*)&Bs[nw * 64 + t * 16 + (lane & 15)][ko];
        }
#pragma unroll
        for (int j = 0; j < 4; ++j)
#pragma unroll
            for (int i = 0; i < 4; ++i)
                accT[j][i] = __builtin_amdgcn_mfma_f32_16x16x32_bf16(bfr[j], af[i], accT[j][i], 0, 0, 0);
    }
    int rbase = (lane >> 4) * 4, col = lane & 15;
#pragma unroll
    for (int i = 0; i < 4; ++i)
#pragma unroll
        for (int j = 0; j < 4; ++j) {
            int m = m0 + mw * 64 + i * 16 + col;
            int n0 = nw * 64 + j * 16 + rbase;
            ushort4 pk;
            pk.x = to_bf16u(accT[j][i][0]);
            pk.y = to_bf16u(accT[j][i][1]);
            pk.z = to_bf16u(accT[j][i][2]);
            pk.w = to_bf16u(accT[j][i][3]);
            *(ushort4*)(C + (size_t)m * TH + n0) = pk;
        }
}

// alpha = softmax(V@wv over L); g = sum_l alpha*V
__global__ __launch_bounds__(256) void k_pool(const float* __restrict__ V, const float* __restrict__ wv,
                                              float* __restrict__ g) {
    __shared__ float sc[TL];
    __shared__ float red[4];
    __shared__ float part[TH];
    int b = blockIdx.x, tid = threadIdx.x;
    int lane = tid & 63, w = tid >> 6;
    for (int l = w; l < TL; l += 4) {
        const float2 v = ((const float2*)(V + (size_t)(b * TL + l) * TH))[lane];
        float a = v.x * wv[2 * lane] + v.y * wv[2 * lane + 1];
        for (int o = 32; o > 0; o >>= 1) a += __shfl_down(a, o, 64);
        if (lane == 0) sc[l] = a;
    }
    __syncthreads();
    float m = (tid < TL) ? sc[tid] : -INFINITY;
    for (int o = 32; o > 0; o >>= 1) m = fmaxf(m, __shfl_down(m, o, 64));
    if ((tid & 63) == 0) red[tid >> 6] = m;
    __syncthreads();
    m = fmaxf(fmaxf(red[0], red[1]), fmaxf(red[2], red[3]));
    __syncthreads();
    float e = (tid < TL) ? expf(sc[tid] - m) : 0.f;
    float s = block_reduce_sum(e, red);
    if (tid < TL) sc[tid] = e / s;
    __syncthreads();
    {
        int h = tid & 127, half = tid >> 7;
        float a = 0.f;
        for (int l = half * 100; l < half * 100 + 100; ++l)
            a += sc[l] * V[(size_t)(b * TL + l) * TH + h];
        if (half) part[h] = a;
        __syncthreads();
        if (!half) g[b * TH + h] = a + part[h];
    }
}

// merged 4x scores over bf16 features
__global__ __launch_bounds__(256) void k_scores4(
        const unsigned short* __restrict__ f0, const float* __restrict__ v0, float* __restrict__ o0, int n0,
        const unsigned short* __restrict__ f1, const float* __restrict__ v1, float* __restrict__ o1, int n1,
        const unsigned short* __restrict__ f2, const float* __restrict__ v2, float* __restrict__ o2, int n2,
        const unsigned short* __restrict__ f3, const float* __restrict__ v3, float* __restrict__ o3, int n3) {
    int t = blockIdx.x * 256 + threadIdx.x;
    const unsigned short* f; const float* vec; float* o;
    if (t < n0 * 4) { f = f0; vec = v0; o = o0; }
    else {
        t -= n0 * 4;
        if (t < n1 * 4) { f = f1; vec = v1; o = o1; }
        else {
            t -= n1 * 4;
            if (t < n2 * 4) { f = f2; vec = v2; o = o2; }
            else {
                t -= n2 * 4;
                if (t >= n3 * 4) return;
                f = f3; vec = v3; o = o3;
            }
        }
    }
    int node = t >> 2, k = t & 3;
    const unsigned short* fp = f + (size_t)node * TH + k * TD;
    const float* vp = vec + k * TD;
    float a = 0.f;
#pragma unroll
    for (int q = 0; q < 4; ++q) {
        uint4 u = *(const uint4*)(fp + q * 8);
        unsigned int ws[4] = {u.x, u.y, u.z, u.w};
#pragma unroll
        for (int p = 0; p < 4; ++p) {
            a += __uint_as_float(ws[p] << 16) * vp[q * 8 + p * 2];
            a += __uint_as_float(ws[p] & 0xffff0000u) * vp[q * 8 + p * 2 + 1];
        }
    }
    o[t] = a;
}

// fused per-dst-node GAT; cur bf16, fs bf16, nxt bf16 out, ACC f32
__global__ __launch_bounds__(128) void k_gat(const unsigned short* __restrict__ tax_cur,
                                             const unsigned short* __restrict__ fs_i, const float* __restrict__ el_i,
                                             const float* __restrict__ er_i, const int* __restrict__ src_i,
                                             const float* __restrict__ bi,
                                             const unsigned short* __restrict__ fs_t, const float* __restrict__ el_t,
                                             const float* __restrict__ er_t, const int* __restrict__ src_t,
                                             const float* __restrict__ bt,
                                             unsigned short* __restrict__ tax_nxt,
                                             float* __restrict__ acc, int hop) {
    int n = blockIdx.x, h = threadIdx.x, k = h >> 5;
    float cur = bfu_to_f(tax_cur[(size_t)n * TH + h]);
    float ti, tt2;
    {
        float er = er_i[n * 4 + k];
        int s[4]; float e[4]; float m = -INFINITY;
#pragma unroll
        for (int j = 0; j < 4; ++j) {
            s[j] = src_i[n * 4 + j];
            float xx = el_i[s[j] * 4 + k] + er;
            e[j] = xx > 0.f ? xx : 0.2f * xx;
            m = fmaxf(m, e[j]);
        }
        float ssum = 0.f, av = 0.f;
#pragma unroll
        for (int j = 0; j < 4; ++j) {
            float a = expf(e[j] - m);
            ssum += a;
            av += a * bfu_to_f(fs_i[(size_t)s[j] * TH + h]);
        }
        ti = fmaxf(av / ssum + cur + bi[h], 0.f);
    }
    {
        float er = er_t[n * 4 + k];
        int s[2]; float e[2]; float m = -INFINITY;
#pragma unroll
        for (int j = 0; j < 2; ++j) {
            s[j] = src_t[n * 2 + j];
            float xx = el_t[s[j] * 4 + k] + er;
            e[j] = xx > 0.f ? xx : 0.2f * xx;
            m = fmaxf(m, e[j]);
        }
        float ssum = 0.f, av = 0.f;
#pragma unroll
        for (int j = 0; j < 2; ++j) {
            float a = expf(e[j] - m);
            ssum += a;
            av += a * bfu_to_f(fs_t[(size_t)s[j] * TH + h]);
        }
        tt2 = fmaxf(av / ssum + cur + bt[h], 0.f);
    }
    float nx = ti + tt2;
    size_t ai = (size_t)n * TH + h;
    tax_nxt[ai] = to_bf16u(nx);
    acc[ai] = (hop == 0) ? nx : acc[ai] + nx;
}

// fused local-gather + mul + LN/softmax/LN + @uni_w -> PB bf16
__global__ __launch_bounds__(128) void k_locfuse(const int* __restrict__ root, const float* __restrict__ acc,
                                                 const float* __restrict__ g,
                                                 const float* __restrict__ liw_g, const float* __restrict__ liw_b,
                                                 const float* __restrict__ int_g, const float* __restrict__ int_b,
                                                 const float* __restrict__ uni_w,
                                                 unsigned short* __restrict__ PB) {
    __shared__ float loc[TFT][TH + 1];
    __shared__ float gsh[TH];
    __shared__ float lm[TFT], wv_[TFT], inten[TH];
    __shared__ float red[2];
    int b = blockIdx.x, tid = threadIdx.x;
    float gv = g[b * TH + tid];
    gsh[tid] = gv;
    for (int f = 0; f < TFT; ++f) {
        int r = root[b * TFT + f];
        float v = 0.f;
        if (r != -1) v = acc[(size_t)(b * TTP + (r < 0 ? 0 : r)) * TH + tid] * 0.5f;
        loc[f][tid] = v;
    }
    __syncthreads();
    {   // mul[f] = dot(loc[f], g): thread (f, quarter) handles 32 h, 4-lane reduce
        int f = tid >> 2, q = tid & 3;
        float a = 0.f;
        const float* lp = &loc[f][q * 32];
        const float* gp = &gsh[q * 32];
        for (int k = 0; k < 32; ++k) a += lp[k] * gp[k];
        a += __shfl_xor(a, 1);
        a += __shfl_xor(a, 2);
        if (q == 0) lm[f] = a;
    }
    __syncthreads();
    if (tid < TFT) {
        float mean = 0.f;
        for (int f = 0; f < TFT; ++f) mean += lm[f];
        mean *= (1.f / TFT);
        float var = 0.f;
        for (int f = 0; f < TFT; ++f) { float d = lm[f] - mean; var += d * d; }
        var *= (1.f / TFT);
        float ln = (lm[tid] - mean) * rsqrtf(var + 1e-8f) * liw_g[tid] + liw_b[tid];
        wv_[tid] = (lm[tid] != 0.f) ? ln : -INFINITY;
    }
    __syncthreads();
    if (tid < TFT) {
        float mx = -INFINITY;
        for (int f = 0; f < TFT; ++f) mx = fmaxf(mx, wv_[f]);
        float s = 0.f;
        for (int f = 0; f < TFT; ++f) s += expf(wv_[f] - mx);
        lm[tid] = expf(wv_[tid] - mx) / s;
    }
    __syncthreads();
    float ip = gv;
    for (int f = 0; f < TFT; ++f) ip += lm[f] * loc[f][tid];
    float mean = block_reduce_sum(ip, red) * (1.f / TH);
    float d = ip - mean;
    float var = block_reduce_sum(d * d, red) * (1.f / TH);
    inten[tid] = d * rsqrtf(var + 1e-8f) * int_g[tid] + int_b[tid];
    __syncthreads();
    float a = 0.f;
    for (int hp = 0; hp < TH; ++hp) a += inten[hp] * uni_w[hp * TH + tid];
    PB[(size_t)b * TH + tid] = to_bf16u(a);
}

// out[b,i] = PB[b,:] . E[i,:]; E converted in-LDS; full batch swept per item-tile
__global__ __launch_bounds__(256) void k_final_m2(const unsigned short* __restrict__ PB,
                                                  const float* __restrict__ E,
                                                  float* __restrict__ out) {
    __shared__ unsigned short Bs[128][136];
    int tid = threadIdx.x;
    int i0 = blockIdx.x * 128;
    for (int i = tid; i < 2048; i += 256) {
        int r = i >> 4, q = i & 15;
        int it = i0 + r;
        float4 a = {0.f, 0.f, 0.f, 0.f}, b = {0.f, 0.f, 0.f, 0.f};
        if (it < TITEMS) {
            a = *(const float4*)(E + (size_t)it * TH + q * 8);
            b = *(const float4*)(E + (size_t)it * TH + q * 8 + 4);
        }
        ushort4 u0, u1;
        u0.x = to_bf16u(a.x); u0.y = to_bf16u(a.y); u0.z = to_bf16u(a.z); u0.w = to_bf16u(a.w);
        u1.x = to_bf16u(b.x); u1.y = to_bf16u(b.y); u1.z = to_bf16u(b.z); u1.w = to_bf16u(b.w);
        *(ushort4*)&Bs[r][q * 8] = u0;
        *(ushort4*)&Bs[r][q * 8 + 4] = u1;
    }
    __syncthreads();
    int lane = tid & 63, wid = tid >> 6;
    int mw = wid >> 1, nw = wid & 1;
    int rbase = (lane >> 4) * 4, col = lane & 15;
#pragma unroll 1
    for (int b0 = 0; b0 < TB; b0 += 128) {
        f32x4 acc[4][4];
#pragma unroll
        for (int i = 0; i < 4; ++i)
#pragma unroll
            for (int j = 0; j < 4; ++j) acc[i][j] = (f32x4){0.f, 0.f, 0.f, 0.f};
#pragma unroll
        for (int kc = 0; kc < 4; ++kc) {
            int ko = kc * 32 + (lane >> 4) * 8;
            short8v af[4], bfr[4];
#pragma unroll
            for (int t = 0; t < 4; ++t) {
                af[t] = *(const short8v*)(PB + (size_t)(b0 + mw * 64 + t * 16 + (lane & 15)) * TH + ko);
                bfr[t] = *(const short8v*)&Bs[nw * 64 + t * 16 + (lane & 15)][ko];
            }
#pragma unroll
            for (int i = 0; i < 4; ++i)
#pragma unroll
                for (int j = 0; j < 4; ++j)
                    acc[i][j] = __builtin_amdgcn_mfma_f32_16x16x32_bf16(af[i], bfr[j], acc[i][j], 0, 0, 0);
        }
#pragma unroll
        for (int i = 0; i < 4; ++i)
#pragma unroll
            for (int j = 0; j < 4; ++j) {
                int ii = i0 + nw * 64 + j * 16 + col;
                if (ii < TITEMS) {
#pragma unroll
                    for (int r = 0; r < 4; ++r)
                        out[(size_t)(b0 + mw * 64 + i * 16 + rbase + r) * TITEMS + ii] = acc[i][j][r];
                }
            }
    }
}

extern "C" void kernel_launch(void* const* d_in, const int* in_sizes, int n_in,
                              void* d_out, int out_size, void* d_ws, size_t ws_size,
                              hipStream_t stream) {
    const int*   seq        = (const int*)d_in[0];
    const int*   root       = (const int*)d_in[1];
    const int*   i2t_src    = (const int*)d_in[3];
    const int*   t2t_src    = (const int*)d_in[5];
    const int*   item_ids   = (const int*)d_in[6];
    const int*   tax_ids    = (const int*)d_in[7];
    const float* item_embed = (const float*)d_in[8];
    const float* tax_embed  = (const float*)d_in[9];
    const float* scb_ln_g   = (const float*)d_in[10];
    const float* scb_ln_b   = (const float*)d_in[11];
    const float* scb_w1     = (const float*)d_in[12];
    const float* scb_w2     = (const float*)d_in[13];
    const float* fcb_ln_g   = (const float*)d_in[14];
    const float* fcb_ln_b   = (const float*)d_in[15];
    const float* fcb_w1     = (const float*)d_in[16];
    const float* fcb_w2     = (const float*)d_in[17];
    const float* fcb_w3     = (const float*)d_in[18];
    const float* wv         = (const float*)d_in[19];
    const float* gi_w       = (const float*)d_in[20];
    const float* gi_al      = (const float*)d_in[21];
    const float* gi_ar      = (const float*)d_in[22];
    const float* gi_b       = (const float*)d_in[23];
    const float* gt_w       = (const float*)d_in[24];
    const float* gt_al      = (const float*)d_in[25];
    const float* gt_ar      = (const float*)d_in[26];
    const float* gt_b       = (const float*)d_in[27];
    const float* liw_g      = (const float*)d_in[28];
    const float* liw_b      = (const float*)d_in[29];
    const float* int_g      = (const float*)d_in[30];
    const float* int_b      = (const float*)d_in[31];
    const float* uni_w      = (const float*)d_in[32];

    char* w = (char*)d_ws;
    // ---- mixer phase (V and NV merged into one in-place buffer) ----
    float* NV  = (float*)(w + 0);                            // 52.4MB (V == NV)
    unsigned short* NVT = (unsigned short*)(w + 52428800);   // 29.4MB (also ZB)
    unsigned short* ZB  = NVT;
    unsigned short* T   = (unsigned short*)(w + 81788928);   // 67.1MB (full 512 b)
    unsigned short* W1T2 = (unsigned short*)(w + 148897792); // 2x229KB
    unsigned short* W2T2 = (unsigned short*)(w + 149356544); // 2x213KB
    // ---- GAT phase (mixer buffers dead after k_pool) ----
    unsigned short* ITEMHB = (unsigned short*)(w + 0);           // 26.2MB
    unsigned short* FSIB   = (unsigned short*)(w + 26214400);    // 26.2MB
    unsigned short* TAXB0  = (unsigned short*)(w + 52428800);    // 8.4MB
    unsigned short* TAXB1  = (unsigned short*)(w + 60817408);    // 8.4MB
    float* ACC   = (float*)(w + 69206016);                       // 16.8MB
    unsigned short* FDIB = (unsigned short*)(w + 85983232);      // 8.4MB
    unsigned short* FSTB = (unsigned short*)(w + 94371840);      // 8.4MB
    float* ELI   = (float*)(w + 102760448);
    float* ERI   = (float*)(w + 104398848);
    float* ELT   = (float*)(w + 104923136);
    float* ERT   = (float*)(w + 105447424);
    // ---- stable tail ----
    unsigned short* WB = (unsigned short*)(w + 191954944);   // 262KB converted weights
    float* G     = (float*)(w + 200343552);
    unsigned short* PB = (unsigned short*)(w + 200671232);   // 128KB
    if (ws_size < 200933376ull) return;

    // one-time weight conversions (fcb + GAT weights; both nb scb weights)
    k_wcvt<<<512, 256, 0, stream>>>(fcb_w1, fcb_w2, fcb_w3, gi_w, gt_w, WB);
    k_wscb2<<<1440, 256, 0, stream>>>(scb_w1, scb_w2, W1T2, W2T2);

    // ---- global intention (mixer) ----
    for (int nb = 0; nb < 2; ++nb) {
        // nb=0: gather fused (reads item_embed[seq]); nb=1: in-place LN on NV
        k_lnt<<<dim3(4, TB), 128, 0, stream>>>(NV, nb == 0 ? seq : nullptr, item_embed,
                                               scb_ln_g + nb * TH, scb_ln_b + nb * TH, NV, NVT);
        k_mm1<<<dim3(4, TB), 256, 0, stream>>>(NVT, W1T2 + nb * 114688, T);
        k_mm2l<<<dim3(4, TB), 256, 0, stream>>>(T, W2T2 + nb * 106496, NV,
                                                fcb_ln_g + nb * TH, fcb_ln_b + nb * TH);
        k_ffuse<<<1024, 256, 0, stream>>>(NV, WB + nb * 8192, WB + 16384 + nb * 8192, ZB,
                                          TB * TL * 4 / 64);
        k_gmm_b<<<TB * TL / 128, 256, 0, stream>>>(ZB, WB + 32768 + nb * 16384, NV, NV);
    }
    k_pool<<<TB, 256, 0, stream>>>(NV, wv, G);

    // ---- local intention (GAT, bf16 features) ----
    k_gather2<<<(TNI * 16 + TNT * 16 + 255) / 256, 256, 0, stream>>>(
        item_embed, item_ids, ITEMHB, TNI, tax_embed, tax_ids, TAXB0, TNT);

    unsigned short* curb = TAXB0;
    unsigned short* nxtb = TAXB1;
    for (int hop = 0; hop < 2; ++hop) {
        const unsigned short* WiB = WB + 65536 + hop * 16384;
        const unsigned short* WtB = WB + 98304 + hop * 16384;
        k_gmm3<<<TNI / 128 + 2 * (TNT / 128), 256, 0, stream>>>(
            ITEMHB, WiB, FSIB, TNI / 128,
            curb, WiB, FDIB, TNT / 128,
            curb, WtB, FSTB);
        int total = (TNI + 3 * TNT) * TNH;
        k_scores4<<<(total + 255) / 256, 256, 0, stream>>>(
            FSIB, gi_al + hop * TH, ELI, TNI,
            FDIB, gi_ar + hop * TH, ERI, TNT,
            FSTB, gt_al + hop * TH, ELT, TNT,
            FSTB, gt_ar + hop * TH, ERT, TNT);
        k_gat<<<TNT, 128, 0, stream>>>(curb, FSIB, ELI, ERI, i2t_src, gi_b + hop * TH,
                                       FSTB, ELT, ERT, t2t_src, gt_b + hop * TH, nxtb, ACC, hop);
        unsigned short* tmp = curb; curb = nxtb; nxtb = tmp;
    }

    // ---- fuse + final ----
    k_locfuse<<<TB, 128, 0, stream>>>(root, ACC, G, liw_g, liw_b, int_g, int_b, uni_w, PB);
    k_final_m2<<<TIPAD / 128, 256, 0, stream>>>(PB, item_embed, (float*)d_out);
}

// Round 15
// 948.621 us; speedup vs baseline: 1.1404x; 1.0025x over previous
//
#include <hip/hip_runtime.h>
#include <hip/hip_bf16.h>

// ---- model dims ----
constexpr int TB = 512, TL = 200, TH = 128, TNH = 4, TD = 32;
constexpr int TFT = 32, TTP = 64, TIP = 200;
constexpr int TSH = 512, TFH = 256;
constexpr int TITEMS = 100001;
constexpr int TNT = TB * TTP;   // 32768
constexpr int TNI = TB * TIP;   // 102400
constexpr int TLP = 224;        // L padded (K of scb GEMM1)
constexpr int TIPAD = 100096;   // items padded to 128

typedef __attribute__((ext_vector_type(8))) short short8v;
typedef __attribute__((ext_vector_type(4))) float f32x4;

// tanh-form gelu, |err| <= ~3e-4 (below bf16 quantization of the result)
__device__ inline float gelu_fast(float x) {
    float u = x + 0.044715f * x * x * x;
    float e = exp2f(-2.302208f * u);
    return x / (1.0f + e);
}
__device__ inline unsigned short to_bf16u(float x) {
    __hip_bfloat16 h = __float2bfloat16(x);
    return *reinterpret_cast<unsigned short*>(&h);
}
__device__ inline float bfu_to_f(unsigned short u) {
    unsigned int x = ((unsigned int)u) << 16;
    return __uint_as_float(x);
}

__device__ inline float block_reduce_sum(float v, float* red) {
    for (int o = 32; o > 0; o >>= 1) v += __shfl_down(v, o, 64);
    int nw = blockDim.x >> 6;
    if ((threadIdx.x & 63) == 0) red[threadIdx.x >> 6] = v;
    __syncthreads();
    float r = 0.f;
    for (int w = 0; w < nw; ++w) r += red[w];
    __syncthreads();
    return r;
}

// merged double gather: out[r,:] = bf16(table[idx[r],:]) for two tables
__global__ __launch_bounds__(256) void k_gather2(const float* __restrict__ tab0,
                                                 const int* __restrict__ idx0,
                                                 unsigned short* __restrict__ out0, int n0,
                                                 const float* __restrict__ tab1,
                                                 const int* __restrict__ idx1,
                                                 unsigned short* __restrict__ out1, int n1) {
    int e = blockIdx.x * 256 + threadIdx.x;
    const float* tab; const int* idx; unsigned short* out;
    if (e < n0 * 16) { tab = tab0; idx = idx0; out = out0; }
    else {
        e -= n0 * 16;
        if (e >= n1 * 16) return;
        tab = tab1; idx = idx1; out = out1;
    }
    int r = e >> 4, c = e & 15;
    const float4 a = ((const float4*)tab)[(size_t)idx[r] * 32 + c * 2];
    const float4 b = ((const float4*)tab)[(size_t)idx[r] * 32 + c * 2 + 1];
    uint4 u;
    u.x = (unsigned int)to_bf16u(a.x) | ((unsigned int)to_bf16u(a.y) << 16);
    u.y = (unsigned int)to_bf16u(a.z) | ((unsigned int)to_bf16u(a.w) << 16);
    u.z = (unsigned int)to_bf16u(b.x) | ((unsigned int)to_bf16u(b.y) << 16);
    u.w = (unsigned int)to_bf16u(b.z) | ((unsigned int)to_bf16u(b.w) << 16);
    *(uint4*)(out + (size_t)e * 8) = u;
}

// merged one-time weight prep: blocks [0,512) = small-weight cvt; [512,1952) = scb transposes
__global__ __launch_bounds__(256) void k_wprep(const float* __restrict__ fw1, const float* __restrict__ fw2,
                                               const float* __restrict__ fw3, const float* __restrict__ giw,
                                               const float* __restrict__ gtw, unsigned short* __restrict__ WB,
                                               const float* __restrict__ sw1, const float* __restrict__ sw2,
                                               unsigned short* __restrict__ W1T,
                                               unsigned short* __restrict__ W2T) {
    int bxg = blockIdx.x;
    if (bxg < 512) {
        int idx = bxg * 256 + threadIdx.x;  // 0..131071
        float v;
        if (idx < 16384) {           // fw1b[nb][n=256][k=32]
            int nb = idx >> 13, r = idx & 8191, n = r >> 5, k = r & 31;
            v = fw1[(size_t)nb * 8192 + k * 256 + n];
        } else if (idx < 32768) {    // fw2b[nb][n=32][k=256]
            int t = idx - 16384;
            int nb = t >> 13, r = t & 8191, n = r >> 8, k = r & 255;
            v = fw2[(size_t)nb * 8192 + k * 32 + n];
        } else if (idx < 65536) {    // fw3b[nb][n=128][k=128]
            int t = idx - 32768;
            int nb = t >> 14, r = t & 16383, n = r >> 7, k = r & 127;
            v = fw3[(size_t)nb * 16384 + k * 128 + n];
        } else if (idx < 98304) {    // giwb[hop][n][k]
            int t = idx - 65536;
            int hop = t >> 14, r = t & 16383, n = r >> 7, k = r & 127;
            v = giw[(size_t)hop * 16384 + k * 128 + n];
        } else {                     // gtwb[hop][n][k]
            int t = idx - 98304;
            int hop = t >> 14, r = t & 16383, n = r >> 7, k = r & 127;
            v = gtw[(size_t)hop * 16384 + k * 128 + n];
        }
        WB[idx] = to_bf16u(v);
        return;
    }
    int bx = bxg - 512;
    if (bx < 1024) {
        int nb = bx >> 9, s = bx & 511, l = threadIdx.x;
        if (l < TLP)
            W1T[(size_t)nb * 114688 + (size_t)s * TLP + l] =
                to_bf16u(l < TL ? sw1[(size_t)nb * 102400 + l * TSH + s] : 0.f);
    } else {
        int t = bx - 1024;           // 0..415
        int nb = t / 208, l = t % 208;
        for (int it = 0; it < 2; ++it) {
            int s = it * 256 + threadIdx.x;
            W2T[(size_t)nb * 106496 + (size_t)l * TSH + s] =
                to_bf16u(l < TL ? sw2[(size_t)nb * 102400 + s * TL + l] : 0.f);
        }
    }
}

// fused [gather +] LN + bf16 transpose: src -> NV f32 (LN'd, in-place safe) + NVT bf16
__global__ __launch_bounds__(128) void k_lnt(const float* __restrict__ V,
                                             const int* __restrict__ seqp, const float* __restrict__ tab,
                                             const float* __restrict__ g, const float* __restrict__ b,
                                             float* __restrict__ NV, unsigned short* __restrict__ NVT) {
    __shared__ float tl[64][129];
    __shared__ float mrow[64], irow[64];
    int bb = blockIdx.y, l0 = blockIdx.x * 64, tid = threadIdx.x;
    for (int i = tid; i < 2048; i += 128) {
        int r = i >> 5, c = i & 31;
        int l = l0 + r;
        float4 v = {0.f, 0.f, 0.f, 0.f};
        if (l < TL) {
            const float* src = seqp ? (tab + (size_t)seqp[bb * TL + l] * TH)
                                    : (V + ((size_t)bb * TL + l) * TH);
            v = *(const float4*)(src + c * 4);
        }
        tl[r][c * 4 + 0] = v.x; tl[r][c * 4 + 1] = v.y;
        tl[r][c * 4 + 2] = v.z; tl[r][c * 4 + 3] = v.w;
    }
    __syncthreads();
    {
        int row = tid >> 1, half = tid & 1;
        float s = 0.f, sq = 0.f;
        for (int k = 0; k < 64; ++k) {
            float v = tl[row][half * 64 + k];
            s += v; sq += v * v;
        }
        s += __shfl_xor(s, 1);
        sq += __shfl_xor(sq, 1);
        if (half == 0) {
            float mean = s * (1.f / 128.f);
            mrow[row] = mean;
            irow[row] = rsqrtf(sq * (1.f / 128.f) - mean * mean + 1e-8f);
        }
    }
    __syncthreads();
    for (int i = tid; i < 2048; i += 128) {
        int r = i >> 5, c = i & 31;
        int l = l0 + r;
        float4 o = {0.f, 0.f, 0.f, 0.f};
        if (l < TL) {
            float4 v = *(float4*)&tl[r][c * 4];
            float m = mrow[r], inv = irow[r];
            const float4 gg = ((const float4*)g)[c];
            const float4 bv = ((const float4*)b)[c];
            o.x = (v.x - m) * inv * gg.x + bv.x;
            o.y = (v.y - m) * inv * gg.y + bv.y;
            o.z = (v.z - m) * inv * gg.z + bv.z;
            o.w = (v.w - m) * inv * gg.w + bv.w;
            *(float4*)(NV + ((size_t)bb * TL + l) * TH + c * 4) = o;
        }
        *(float4*)&tl[r][c * 4] = o;
    }
    __syncthreads();
    int h = tid;
    int ng = (l0 + 64 > TLP) ? (TLP - l0) / 8 : 8;
    for (int lg = 0; lg < ng; ++lg) {
        uint4 u;
        unsigned int p[4];
#pragma unroll
        for (int q = 0; q < 4; ++q) {
            unsigned short ua = to_bf16u(tl[lg * 8 + q * 2 + 0][h]);
            unsigned short ub = to_bf16u(tl[lg * 8 + q * 2 + 1][h]);
            p[q] = (unsigned int)ua | ((unsigned int)ub << 16);
        }
        u.x = p[0]; u.y = p[1]; u.z = p[2]; u.w = p[3];
        *(uint4*)(NVT + ((size_t)bb * TH + h) * TLP + l0 + lg * 8) = u;
    }
}

// scb GEMM1 (full batch grid): T[b][h][s] = gelu( sum_l NVT[b][h][l] * w1[l][s] )
__global__ __launch_bounds__(256) void k_mm1(const unsigned short* __restrict__ NVT,
                                             const unsigned short* __restrict__ W1T,
                                             unsigned short* __restrict__ T) {
    __shared__ unsigned short As[128][40];
    __shared__ unsigned short Bs[128][40];
    int tid = threadIdx.x;
    int b = blockIdx.y;
    int s0 = blockIdx.x * 128;
    int lane = tid & 63, wid = tid >> 6;
    int mw = wid >> 1, nw = wid & 1;
    f32x4 accT[4][4];   // [j][i]: D[s][h] (swapped operands)
#pragma unroll
    for (int j = 0; j < 4; ++j)
#pragma unroll
        for (int i = 0; i < 4; ++i) accT[j][i] = (f32x4){0.f, 0.f, 0.f, 0.f};
    const unsigned short* Abase = NVT + (size_t)b * TH * TLP;
    const unsigned short* Bbase = W1T + (size_t)s0 * TLP;
    for (int kc = 0; kc < 7; ++kc) {
        __syncthreads();
        for (int i = tid; i < 512; i += 256) {
            int r = i >> 2, q = i & 3;
            *(uint4*)&As[r][q * 8] = *(const uint4*)(Abase + (size_t)r * TLP + kc * 32 + q * 8);
            *(uint4*)&Bs[r][q * 8] = *(const uint4*)(Bbase + (size_t)r * TLP + kc * 32 + q * 8);
        }
        __syncthreads();
        int ko = (lane >> 4) * 8;
        short8v af[4], bfr[4];
#pragma unroll
        for (int t = 0; t < 4; ++t) {
            af[t] = *(const short8v*)&As[mw * 64 + t * 16 + (lane & 15)][ko];
            bfr[t] = *(const short8v*)&Bs[nw * 64 + t * 16 + (lane & 15)][ko];
        }
#pragma unroll
        for (int j = 0; j < 4; ++j)
#pragma unroll
            for (int i = 0; i < 4; ++i)
                accT[j][i] = __builtin_amdgcn_mfma_f32_16x16x32_bf16(bfr[j], af[i], accT[j][i], 0, 0, 0);
    }
    int rbase = (lane >> 4) * 4, col = lane & 15;
#pragma unroll
    for (int i = 0; i < 4; ++i)
#pragma unroll
        for (int j = 0; j < 4; ++j) {
            int h = mw * 64 + i * 16 + col;
            int sb = s0 + nw * 64 + j * 16 + rbase;
            ushort4 pk;
            pk.x = to_bf16u(gelu_fast(accT[j][i][0]));
            pk.y = to_bf16u(gelu_fast(accT[j][i][1]));
            pk.z = to_bf16u(gelu_fast(accT[j][i][2]));
            pk.w = to_bf16u(gelu_fast(accT[j][i][3]));
            *(ushort4*)(T + ((size_t)b * TH + h) * TSH + sb) = pk;
        }
}

// scb GEMM2 + fcb LN fused (full batch grid): vs = NV + T@w2; NV <- LN(vs) in place
__global__ __launch_bounds__(256) void k_mm2l(const unsigned short* __restrict__ T,
                                              const unsigned short* __restrict__ W2T,
                                              float* __restrict__ NV,
                                              const float* __restrict__ lg, const float* __restrict__ lb) {
    __shared__ unsigned short As[128][40];
    __shared__ unsigned short Bs[64][40];
    __shared__ float vsl[64][132];
    __shared__ float mrow[64], irow[64];
    int tid = threadIdx.x;
    int b = blockIdx.y;
    int l0 = blockIdx.x * 64;
    int lane = tid & 63, wid = tid >> 6;
    f32x4 acc[2][4];
#pragma unroll
    for (int i = 0; i < 2; ++i)
#pragma unroll
        for (int j = 0; j < 4; ++j) acc[i][j] = (f32x4){0.f, 0.f, 0.f, 0.f};
    const unsigned short* Abase = T + (size_t)b * TH * TSH;
    for (int kc = 0; kc < 16; ++kc) {
        __syncthreads();
        for (int i = tid; i < 512; i += 256) {
            int r = i >> 2, q = i & 3;
            *(uint4*)&As[r][q * 8] = *(const uint4*)(Abase + (size_t)r * TSH + kc * 32 + q * 8);
        }
        {
            int r = tid >> 2, q = tid & 3;
            int l = l0 + r;
            uint4 v = {0u, 0u, 0u, 0u};
            if (l < 208) v = *(const uint4*)(W2T + (size_t)l * TSH + kc * 32 + q * 8);
            *(uint4*)&Bs[r][q * 8] = v;
        }
        __syncthreads();
        int ko = (lane >> 4) * 8;
        short8v af[2], bfr[4];
#pragma unroll
        for (int t = 0; t < 2; ++t)
            af[t] = *(const short8v*)&As[wid * 32 + t * 16 + (lane & 15)][ko];
#pragma unroll
        for (int j = 0; j < 4; ++j)
            bfr[j] = *(const short8v*)&Bs[j * 16 + (lane & 15)][ko];
#pragma unroll
        for (int i = 0; i < 2; ++i)
#pragma unroll
            for (int j = 0; j < 4; ++j)
                acc[i][j] = __builtin_amdgcn_mfma_f32_16x16x32_bf16(af[i], bfr[j], acc[i][j], 0, 0, 0);
    }
    int rbase = (lane >> 4) * 4, col = lane & 15;
#pragma unroll
    for (int i = 0; i < 2; ++i)
#pragma unroll
        for (int j = 0; j < 4; ++j) {
            int l = l0 + j * 16 + col;
            int h0 = wid * 32 + i * 16 + rbase;
            float4 res = {0.f, 0.f, 0.f, 0.f};
            if (l < TL) res = *(const float4*)(NV + ((size_t)b * TL + l) * TH + h0);
            float4 o;
            o.x = acc[i][j][0] + res.x;
            o.y = acc[i][j][1] + res.y;
            o.z = acc[i][j][2] + res.z;
            o.w = acc[i][j][3] + res.w;
            *(float4*)&vsl[j * 16 + col][h0] = o;
        }
    __syncthreads();
    int row = tid >> 2, q = tid & 3;
    {
        float s = 0.f, sq = 0.f;
        for (int k = 0; k < 32; ++k) {
            float v = vsl[row][q * 32 + k];
            s += v; sq += v * v;
        }
        s += __shfl_xor(s, 1); s += __shfl_xor(s, 2);
        sq += __shfl_xor(sq, 1); sq += __shfl_xor(sq, 2);
        if (q == 0) {
            float mean = s * (1.f / 128.f);
            mrow[row] = mean;
            irow[row] = rsqrtf(sq * (1.f / 128.f) - mean * mean + 1e-8f);
        }
    }
    __syncthreads();
    {
        int l = l0 + row;
        if (l < TL) {
            float mean = mrow[row], inv = irow[row];
            float* dst = NV + ((size_t)b * TL + l) * TH + q * 32;
#pragma unroll
            for (int k4 = 0; k4 < 8; ++k4) {
                float4 v = *(float4*)&vsl[row][q * 32 + k4 * 4];
                const float4 gg = ((const float4*)lg)[q * 8 + k4];
                const float4 bv = ((const float4*)lb)[q * 8 + k4];
                float4 o;
                o.x = (v.x - mean) * inv * gg.x + bv.x;
                o.y = (v.y - mean) * inv * gg.y + bv.y;
                o.z = (v.z - mean) * inv * gg.z + bv.z;
                o.w = (v.w - mean) * inv * gg.w + bv.w;
                *(float4*)(dst + k4 * 4) = o;
            }
        }
    }
}

// fused fcb stage1+2; PERSISTENT grid-stride over 64-row tiles; weights staged once
__global__ __launch_bounds__(256) void k_ffuse(const float* __restrict__ NV,
                                               const unsigned short* __restrict__ FW1B,
                                               const unsigned short* __restrict__ FW2B,
                                               unsigned short* __restrict__ Z, int ntiles) {
    __shared__ unsigned short As[64][40];
    __shared__ unsigned short Bs2[32 * 264];
    __shared__ unsigned short Yl[64 * 264];
    int tid = threadIdx.x;
    int lane = tid & 63, wid = tid >> 6;
    int col = lane & 15, rbase = (lane >> 4) * 4, ko = (lane >> 4) * 8;
    for (int i = tid; i < 1024; i += 256) {
        int r = i >> 2, q = i & 3;
        *(uint4*)&Yl[r * 40 + q * 8] = *(const uint4*)(FW1B + r * 32 + q * 8);
    }
    for (int i = tid; i < 1024; i += 256) {
        int r = i >> 5, q = i & 31;
        *(uint4*)&Bs2[r * 264 + q * 8] = *(const uint4*)(FW2B + r * 256 + q * 8);
    }
    __syncthreads();
    short8v bfr[4];
#pragma unroll
    for (int t = 0; t < 4; ++t)
        bfr[t] = *(const short8v*)&Yl[(wid * 64 + t * 16 + col) * 40 + ko];
    __syncthreads();
    int mrow = wid * 16 + col;
    int sw2 = ((mrow >> 2) & 7) << 3;
    for (int tile = blockIdx.x; tile < ntiles; tile += gridDim.x) {
        int m0 = tile * 64;
        for (int i = tid; i < 512; i += 256) {
            int r = i >> 3, q = i & 7;
            const float4 v = *(const float4*)(NV + (size_t)(m0 + r) * 32 + q * 4);
            ushort4 u;
            u.x = to_bf16u(v.x); u.y = to_bf16u(v.y); u.z = to_bf16u(v.z); u.w = to_bf16u(v.w);
            *(ushort4*)&As[r][q * 4] = u;
        }
        __syncthreads();
        {
            short8v af[4];
#pragma unroll
            for (int t = 0; t < 4; ++t)
                af[t] = *(const short8v*)&As[t * 16 + col][ko];
            f32x4 yt[4][4];
#pragma unroll
            for (int j = 0; j < 4; ++j)
#pragma unroll
                for (int i = 0; i < 4; ++i) yt[j][i] = (f32x4){0.f, 0.f, 0.f, 0.f};
#pragma unroll
            for (int j = 0; j < 4; ++j)
#pragma unroll
                for (int i = 0; i < 4; ++i)
                    yt[j][i] = __builtin_amdgcn_mfma_f32_16x16x32_bf16(bfr[j], af[i], yt[j][i], 0, 0, 0);
#pragma unroll
            for (int i = 0; i < 4; ++i)
#pragma unroll
                for (int j = 0; j < 4; ++j) {
                    int m = i * 16 + col;
                    int n0 = wid * 64 + j * 16 + rbase;
                    ushort4 pk;
                    pk.x = to_bf16u(gelu_fast(yt[j][i][0]));
                    pk.y = to_bf16u(gelu_fast(yt[j][i][1]));
                    pk.z = to_bf16u(gelu_fast(yt[j][i][2]));
                    pk.w = to_bf16u(gelu_fast(yt[j][i][3]));
                    int idx = (m * 264 + n0) ^ (((m >> 2) & 7) << 3);
                    *(ushort4*)&Yl[idx] = pk;
                }
        }
        __syncthreads();
        {
            f32x4 acc2[2];
            acc2[0] = (f32x4){0.f, 0.f, 0.f, 0.f};
            acc2[1] = (f32x4){0.f, 0.f, 0.f, 0.f};
            for (int kc = 0; kc < 8; ++kc) {
                int ko2 = kc * 32 + ko;
                short8v a2 = *(const short8v*)&Yl[(mrow * 264 + ko2) ^ sw2];
                short8v b0 = *(const short8v*)&Bs2[col * 264 + ko2];
                short8v b1 = *(const short8v*)&Bs2[(16 + col) * 264 + ko2];
                acc2[0] = __builtin_amdgcn_mfma_f32_16x16x32_bf16(a2, b0, acc2[0], 0, 0, 0);
                acc2[1] = __builtin_amdgcn_mfma_f32_16x16x32_bf16(a2, b1, acc2[1], 0, 0, 0);
            }
#pragma unroll
            for (int j = 0; j < 2; ++j)
#pragma unroll
                for (int r = 0; r < 4; ++r)
                    Z[(size_t)(m0 + wid * 16 + rbase + r) * 32 + j * 16 + col] =
                        to_bf16u(acc2[j][r]);
        }
        __syncthreads();
    }
}

// C f32 [N,128] = A[N,128](bf16) @ WB[n][k](bf16) (+R f32, in-place safe C==R)
__global__ __launch_bounds__(256) void k_gmm_b(const unsigned short* __restrict__ A,
                                               const unsigned short* __restrict__ WB,
                                               const float* __restrict__ R,
                                               float* __restrict__ C) {
    __shared__ unsigned short As[128][40];
    __shared__ unsigned short Bs[128][40];
    int tid = threadIdx.x;
    int m0 = blockIdx.x * 128;
    int lane = tid & 63, wid = tid >> 6;
    int mw = wid >> 1, nw = wid & 1;
    f32x4 acc[4][4];
#pragma unroll
    for (int i = 0; i < 4; ++i)
#pragma unroll
        for (int j = 0; j < 4; ++j) acc[i][j] = (f32x4){0.f, 0.f, 0.f, 0.f};
    for (int kc = 0; kc < 4; ++kc) {
        __syncthreads();
        for (int i = tid; i < 512; i += 256) {
            int r = i >> 2, q = i & 3;
            *(uint4*)&As[r][q * 8] = *(const uint4*)(A + (size_t)(m0 + r) * TH + kc * 32 + q * 8);
            *(uint4*)&Bs[r][q * 8] = *(const uint4*)(WB + (size_t)r * TH + kc * 32 + q * 8);
        }
        __syncthreads();
        int ko = (lane >> 4) * 8;
        short8v af[4], bfr[4];
#pragma unroll
        for (int t = 0; t < 4; ++t) {
            af[t] = *(const short8v*)&As[mw * 64 + t * 16 + (lane & 15)][ko];
            bfr[t] = *(const short8v*)&Bs[nw * 64 + t * 16 + (lane & 15)][ko];
        }
#pragma unroll
        for (int i = 0; i < 4; ++i)
#pragma unroll
            for (int j = 0; j < 4; ++j)
                acc[i][j] = __builtin_amdgcn_mfma_f32_16x16x32_bf16(af[i], bfr[j], acc[i][j], 0, 0, 0);
    }
    int rbase = (lane >> 4) * 4, col = lane & 15;
#pragma unroll
    for (int i = 0; i < 4; ++i)
#pragma unroll
        for (int j = 0; j < 4; ++j) {
            int n = nw * 64 + j * 16 + col;
#pragma unroll
            for (int r = 0; r < 4; ++r) {
                size_t off = (size_t)(m0 + mw * 64 + i * 16 + rbase + r) * TH + n;
                float v = acc[i][j][r];
                if (R) v += R[off];
                C[off] = v;
            }
        }
}

// merged 3x GAT feature GEMMs: C bf16 = A @ WB (packed stores)
__global__ __launch_bounds__(256) void k_gmm3(
        const unsigned short* __restrict__ A0, const unsigned short* __restrict__ W0,
        unsigned short* __restrict__ C0, int nb0,
        const unsigned short* __restrict__ A1, const unsigned short* __restrict__ W1,
        unsigned short* __restrict__ C1, int nb1,
        const unsigned short* __restrict__ A2, const unsigned short* __restrict__ W2,
        unsigned short* __restrict__ C2) {
    __shared__ unsigned short As[128][40];
    __shared__ unsigned short Bs[128][40];
    int bx = blockIdx.x;
    const unsigned short *A, *WBp;
    unsigned short* C;
    if (bx < nb0) { A = A0; WBp = W0; C = C0; }
    else if (bx - nb0 < nb1) { bx -= nb0; A = A1; WBp = W1; C = C1; }
    else { bx -= nb0 + nb1; A = A2; WBp = W2; C = C2; }
    int tid = threadIdx.x;
    int m0 = bx * 128;
    int lane = tid & 63, wid = tid >> 6;
    int mw = wid >> 1, nw = wid & 1;
    f32x4 accT[4][4];   // [j][i]: D[n][m]
#pragma unroll
    for (int j = 0; j < 4; ++j)
#pragma unroll
        for (int i = 0; i < 4; ++i) accT[j][i] = (f32x4){0.f, 0.f, 0.f, 0.f};
    for (int kc = 0; kc < 4; ++kc) {
        __syncthreads();
        for (int i = tid; i < 512; i += 256) {
            int r = i >> 2, q = i & 3;
            *(uint4*)&As[r][q * 8] = *(const uint4*)(A + (size_t)(m0 + r) * TH + kc * 32 + q * 8);
            *(uint4*)&Bs[r][q * 8] = *(const uint4*)(WBp + (size_t)r * TH + kc * 32 + q * 8);
        }
        __syncthreads();
        int ko = (lane >> 4) * 8;
        short8v af[4], bfr[4];
#pragma unroll
        for (int t = 0; t < 4; ++t) {
            af[t] = *(const short8v*)&As[mw * 64 + t * 16 + (lane & 15)][ko];
            bfr[t] = *(const short8v*)&Bs[nw * 64 + t * 16 + (lane & 15)][ko];
        }
#pragma unroll
        for (int j = 0; j < 4; ++j)
#pragma unroll
            for (int i = 0; i < 4; ++i)
                accT[j][i] = __builtin_amdgcn_mfma_f32_16x16x32_bf16(bfr[j], af[i], accT[j][i], 0, 0, 0);
    }
    int rbase = (lane >> 4) * 4, col = lane & 15;
#pragma unroll
    for (int i = 0; i < 4; ++i)
#pragma unroll
        for (int j = 0; j < 4; ++j) {
            int m = m0 + mw * 64 + i * 16 + col;
            int n0 = nw * 64 + j * 16 + rbase;
            ushort4 pk;
            pk.x = to_bf16u(accT[j][i][0]);
            pk.y = to_bf16u(accT[j][i][1]);
            pk.z = to_bf16u(accT[j][i][2]);
            pk.w = to_bf16u(accT[j][i][3]);
            *(ushort4*)(C + (size_t)m * TH + n0) = pk;
        }
}

// alpha = softmax(V@wv over L); g = sum_l alpha*V
__global__ __launch_bounds__(256) void k_pool(const float* __restrict__ V, const float* __restrict__ wv,
                                              float* __restrict__ g) {
    __shared__ float sc[TL];
    __shared__ float red[4];
    __shared__ float part[TH];
    int b = blockIdx.x, tid = threadIdx.x;
    int lane = tid & 63, w = tid >> 6;
    for (int l = w; l < TL; l += 4) {
        const float2 v = ((const float2*)(V + (size_t)(b * TL + l) * TH))[lane];
        float a = v.x * wv[2 * lane] + v.y * wv[2 * lane + 1];
        for (int o = 32; o > 0; o >>= 1) a += __shfl_down(a, o, 64);
        if (lane == 0) sc[l] = a;
    }
    __syncthreads();
    float m = (tid < TL) ? sc[tid] : -INFINITY;
    for (int o = 32; o > 0; o >>= 1) m = fmaxf(m, __shfl_down(m, o, 64));
    if ((tid & 63) == 0) red[tid >> 6] = m;
    __syncthreads();
    m = fmaxf(fmaxf(red[0], red[1]), fmaxf(red[2], red[3]));
    __syncthreads();
    float e = (tid < TL) ? expf(sc[tid] - m) : 0.f;
    float s = block_reduce_sum(e, red);
    if (tid < TL) sc[tid] = e / s;
    __syncthreads();
    {
        int h = tid & 127, half = tid >> 7;
        float a = 0.f;
        for (int l = half * 100; l < half * 100 + 100; ++l)
            a += sc[l] * V[(size_t)(b * TL + l) * TH + h];
        if (half) part[h] = a;
        __syncthreads();
        if (!half) g[b * TH + h] = a + part[h];
    }
}

// merged 4x scores over bf16 features
__global__ __launch_bounds__(256) void k_scores4(
        const unsigned short* __restrict__ f0, const float* __restrict__ v0, float* __restrict__ o0, int n0,
        const unsigned short* __restrict__ f1, const float* __restrict__ v1, float* __restrict__ o1, int n1,
        const unsigned short* __restrict__ f2, const float* __restrict__ v2, float* __restrict__ o2, int n2,
        const unsigned short* __restrict__ f3, const float* __restrict__ v3, float* __restrict__ o3, int n3) {
    int t = blockIdx.x * 256 + threadIdx.x;
    const unsigned short* f; const float* vec; float* o;
    if (t < n0 * 4) { f = f0; vec = v0; o = o0; }
    else {
        t -= n0 * 4;
        if (t < n1 * 4) { f = f1; vec = v1; o = o1; }
        else {
            t -= n1 * 4;
            if (t < n2 * 4) { f = f2; vec = v2; o = o2; }
            else {
                t -= n2 * 4;
                if (t >= n3 * 4) return;
                f = f3; vec = v3; o = o3;
            }
        }
    }
    int node = t >> 2, k = t & 3;
    const unsigned short* fp = f + (size_t)node * TH + k * TD;
    const float* vp = vec + k * TD;
    float a = 0.f;
#pragma unroll
    for (int q = 0; q < 4; ++q) {
        uint4 u = *(const uint4*)(fp + q * 8);
        unsigned int ws[4] = {u.x, u.y, u.z, u.w};
#pragma unroll
        for (int p = 0; p < 4; ++p) {
            a += __uint_as_float(ws[p] << 16) * vp[q * 8 + p * 2];
            a += __uint_as_float(ws[p] & 0xffff0000u) * vp[q * 8 + p * 2 + 1];
        }
    }
    o[t] = a;
}

// fused per-dst-node GAT; cur bf16, fs bf16, nxt bf16 out, ACC f32
__global__ __launch_bounds__(128) void k_gat(const unsigned short* __restrict__ tax_cur,
                                             const unsigned short* __restrict__ fs_i, const float* __restrict__ el_i,
                                             const float* __restrict__ er_i, const int* __restrict__ src_i,
                                             const float* __restrict__ bi,
                                             const unsigned short* __restrict__ fs_t, const float* __restrict__ el_t,
                                             const float* __restrict__ er_t, const int* __restrict__ src_t,
                                             const float* __restrict__ bt,
                                             unsigned short* __restrict__ tax_nxt,
                                             float* __restrict__ acc, int hop) {
    int n = blockIdx.x, h = threadIdx.x, k = h >> 5;
    float cur = bfu_to_f(tax_cur[(size_t)n * TH + h]);
    float ti, tt2;
    {
        float er = er_i[n * 4 + k];
        int s[4]; float e[4]; float m = -INFINITY;
#pragma unroll
        for (int j = 0; j < 4; ++j) {
            s[j] = src_i[n * 4 + j];
            float xx = el_i[s[j] * 4 + k] + er;
            e[j] = xx > 0.f ? xx : 0.2f * xx;
            m = fmaxf(m, e[j]);
        }
        float ssum = 0.f, av = 0.f;
#pragma unroll
        for (int j = 0; j < 4; ++j) {
            float a = expf(e[j] - m);
            ssum += a;
            av += a * bfu_to_f(fs_i[(size_t)s[j] * TH + h]);
        }
        ti = fmaxf(av / ssum + cur + bi[h], 0.f);
    }
    {
        float er = er_t[n * 4 + k];
        int s[2]; float e[2]; float m = -INFINITY;
#pragma unroll
        for (int j = 0; j < 2; ++j) {
            s[j] = src_t[n * 2 + j];
            float xx = el_t[s[j] * 4 + k] + er;
            e[j] = xx > 0.f ? xx : 0.2f * xx;
            m = fmaxf(m, e[j]);
        }
        float ssum = 0.f, av = 0.f;
#pragma unroll
        for (int j = 0; j < 2; ++j) {
            float a = expf(e[j] - m);
            ssum += a;
            av += a * bfu_to_f(fs_t[(size_t)s[j] * TH + h]);
        }
        tt2 = fmaxf(av / ssum + cur + bt[h], 0.f);
    }
    float nx = ti + tt2;
    size_t ai = (size_t)n * TH + h;
    tax_nxt[ai] = to_bf16u(nx);
    acc[ai] = (hop == 0) ? nx : acc[ai] + nx;
}

// fused local-gather + mul + LN/softmax/LN + @uni_w -> PB bf16
__global__ __launch_bounds__(128) void k_locfuse(const int* __restrict__ root, const float* __restrict__ acc,
                                                 const float* __restrict__ g,
                                                 const float* __restrict__ liw_g, const float* __restrict__ liw_b,
                                                 const float* __restrict__ int_g, const float* __restrict__ int_b,
                                                 const float* __restrict__ uni_w,
                                                 unsigned short* __restrict__ PB) {
    __shared__ float loc[TFT][TH + 1];
    __shared__ float gsh[TH];
    __shared__ float lm[TFT], wv_[TFT], inten[TH];
    __shared__ float red[2];
    int b = blockIdx.x, tid = threadIdx.x;
    float gv = g[b * TH + tid];
    gsh[tid] = gv;
    for (int f = 0; f < TFT; ++f) {
        int r = root[b * TFT + f];
        float v = 0.f;
        if (r != -1) v = acc[(size_t)(b * TTP + (r < 0 ? 0 : r)) * TH + tid] * 0.5f;
        loc[f][tid] = v;
    }
    __syncthreads();
    {
        int f = tid >> 2, q = tid & 3;
        float a = 0.f;
        const float* lp = &loc[f][q * 32];
        const float* gp = &gsh[q * 32];
        for (int k = 0; k < 32; ++k) a += lp[k] * gp[k];
        a += __shfl_xor(a, 1);
        a += __shfl_xor(a, 2);
        if (q == 0) lm[f] = a;
    }
    __syncthreads();
    if (tid < TFT) {
        float mean = 0.f;
        for (int f = 0; f < TFT; ++f) mean += lm[f];
        mean *= (1.f / TFT);
        float var = 0.f;
        for (int f = 0; f < TFT; ++f) { float d = lm[f] - mean; var += d * d; }
        var *= (1.f / TFT);
        float ln = (lm[tid] - mean) * rsqrtf(var + 1e-8f) * liw_g[tid] + liw_b[tid];
        wv_[tid] = (lm[tid] != 0.f) ? ln : -INFINITY;
    }
    __syncthreads();
    if (tid < TFT) {
        float mx = -INFINITY;
        for (int f = 0; f < TFT; ++f) mx = fmaxf(mx, wv_[f]);
        float s = 0.f;
        for (int f = 0; f < TFT; ++f) s += expf(wv_[f] - mx);
        lm[tid] = expf(wv_[tid] - mx) / s;
    }
    __syncthreads();
    float ip = gv;
    for (int f = 0; f < TFT; ++f) ip += lm[f] * loc[f][tid];
    float mean = block_reduce_sum(ip, red) * (1.f / TH);
    float d = ip - mean;
    float var = block_reduce_sum(d * d, red) * (1.f / TH);
    inten[tid] = d * rsqrtf(var + 1e-8f) * int_g[tid] + int_b[tid];
    __syncthreads();
    float a = 0.f;
    for (int hp = 0; hp < TH; ++hp) a += inten[hp] * uni_w[hp * TH + tid];
    PB[(size_t)b * TH + tid] = to_bf16u(a);
}

// out[b,i] = PB[b,:] . E[i,:]; swapped MFMA -> packed float4 item-contiguous stores
__global__ __launch_bounds__(256) void k_final_m2(const unsigned short* __restrict__ PB,
                                                  const float* __restrict__ E,
                                                  float* __restrict__ out) {
    __shared__ unsigned short Bs[128][136];
    int tid = threadIdx.x;
    int i0 = blockIdx.x * 128;
    for (int i = tid; i < 2048; i += 256) {
        int r = i >> 4, q = i & 15;
        int it = i0 + r;
        float4 a = {0.f, 0.f, 0.f, 0.f}, b = {0.f, 0.f, 0.f, 0.f};
        if (it < TITEMS) {
            a = *(const float4*)(E + (size_t)it * TH + q * 8);
            b = *(const float4*)(E + (size_t)it * TH + q * 8 + 4);
        }
        ushort4 u0, u1;
        u0.x = to_bf16u(a.x); u0.y = to_bf16u(a.y); u0.z = to_bf16u(a.z); u0.w = to_bf16u(a.w);
        u1.x = to_bf16u(b.x); u1.y = to_bf16u(b.y); u1.z = to_bf16u(b.z); u1.w = to_bf16u(b.w);
        *(ushort4*)&Bs[r][q * 8] = u0;
        *(ushort4*)&Bs[r][q * 8 + 4] = u1;
    }
    __syncthreads();
    int lane = tid & 63, wid = tid >> 6;
    int mw = wid >> 1, nw = wid & 1;
    int rbase = (lane >> 4) * 4, col = lane & 15;
#pragma unroll 1
    for (int b0 = 0; b0 < TB; b0 += 128) {
        f32x4 accT[4][4];   // [j][i]: D[item][b]
#pragma unroll
        for (int j = 0; j < 4; ++j)
#pragma unroll
            for (int i = 0; i < 4; ++i) accT[j][i] = (f32x4){0.f, 0.f, 0.f, 0.f};
#pragma unroll
        for (int kc = 0; kc < 4; ++kc) {
            int ko = kc * 32 + (lane >> 4) * 8;
            short8v af[4], bfr[4];
#pragma unroll
            for (int t = 0; t < 4; ++t) {
                af[t] = *(const short8v*)(PB + (size_t)(b0 + mw * 64 + t * 16 + col) * TH + ko);
                bfr[t] = *(const short8v*)&Bs[nw * 64 + t * 16 + col][ko];
            }
#pragma unroll
            for (int j = 0; j < 4; ++j)
#pragma unroll
                for (int i = 0; i < 4; ++i)
                    accT[j][i] = __builtin_amdgcn_mfma_f32_16x16x32_bf16(bfr[j], af[i], accT[j][i], 0, 0, 0);
        }
#pragma unroll
        for (int i = 0; i < 4; ++i)
#pragma unroll
            for (int j = 0; j < 4; ++j) {
                int bb = b0 + mw * 64 + i * 16 + col;
                int ii = i0 + nw * 64 + j * 16 + rbase;   // reg walks items (contiguous)
                if (ii + 3 < TITEMS) {
                    float4 o;
                    o.x = accT[j][i][0]; o.y = accT[j][i][1];
                    o.z = accT[j][i][2]; o.w = accT[j][i][3];
                    *(float4*)(out + (size_t)bb * TITEMS + ii) = o;
                } else {
#pragma unroll
                    for (int r = 0; r < 4; ++r)
                        if (ii + r < TITEMS)
                            out[(size_t)bb * TITEMS + ii + r] = accT[j][i][r];
                }
            }
    }
}

extern "C" void kernel_launch(void* const* d_in, const int* in_sizes, int n_in,
                              void* d_out, int out_size, void* d_ws, size_t ws_size,
                              hipStream_t stream) {
    const int*   seq        = (const int*)d_in[0];
    const int*   root       = (const int*)d_in[1];
    const int*   i2t_src    = (const int*)d_in[3];
    const int*   t2t_src    = (const int*)d_in[5];
    const int*   item_ids   = (const int*)d_in[6];
    const int*   tax_ids    = (const int*)d_in[7];
    const float* item_embed = (const float*)d_in[8];
    const float* tax_embed  = (const float*)d_in[9];
    const float* scb_ln_g   = (const float*)d_in[10];
    const float* scb_ln_b   = (const float*)d_in[11];
    const float* scb_w1     = (const float*)d_in[12];
    const float* scb_w2     = (const float*)d_in[13];
    const float* fcb_ln_g   = (const float*)d_in[14];
    const float* fcb_ln_b   = (const float*)d_in[15];
    const float* fcb_w1     = (const float*)d_in[16];
    const float* fcb_w2     = (const float*)d_in[17];
    const float* fcb_w3     = (const float*)d_in[18];
    const float* wv         = (const float*)d_in[19];
    const float* gi_w       = (const float*)d_in[20];
    const float* gi_al      = (const float*)d_in[21];
    const float* gi_ar      = (const float*)d_in[22];
    const float* gi_b       = (const float*)d_in[23];
    const float* gt_w       = (const float*)d_in[24];
    const float* gt_al      = (const float*)d_in[25];
    const float* gt_ar      = (const float*)d_in[26];
    const float* gt_b       = (const float*)d_in[27];
    const float* liw_g      = (const float*)d_in[28];
    const float* liw_b      = (const float*)d_in[29];
    const float* int_g      = (const float*)d_in[30];
    const float* int_b      = (const float*)d_in[31];
    const float* uni_w      = (const float*)d_in[32];

    char* w = (char*)d_ws;
    // ---- mixer phase (V and NV merged into one in-place buffer) ----
    float* NV  = (float*)(w + 0);                            // 52.4MB (V == NV)
    unsigned short* NVT = (unsigned short*)(w + 52428800);   // 29.4MB (also ZB)
    unsigned short* ZB  = NVT;
    unsigned short* T   = (unsigned short*)(w + 81788928);   // 67.1MB (full 512 b)
    unsigned short* W1T2 = (unsigned short*)(w + 148897792); // 2x229KB
    unsigned short* W2T2 = (unsigned short*)(w + 149356544); // 2x213KB
    // ---- GAT phase (mixer buffers dead after k_pool) ----
    unsigned short* ITEMHB = (unsigned short*)(w + 0);           // 26.2MB
    unsigned short* FSIB   = (unsigned short*)(w + 26214400);    // 26.2MB
    unsigned short* TAXB0  = (unsigned short*)(w + 52428800);    // 8.4MB
    unsigned short* TAXB1  = (unsigned short*)(w + 60817408);    // 8.4MB
    float* ACC   = (float*)(w + 69206016);                       // 16.8MB
    unsigned short* FDIB = (unsigned short*)(w + 85983232);      // 8.4MB
    unsigned short* FSTB = (unsigned short*)(w + 94371840);      // 8.4MB
    float* ELI   = (float*)(w + 102760448);
    float* ERI   = (float*)(w + 104398848);
    float* ELT   = (float*)(w + 104923136);
    float* ERT   = (float*)(w + 105447424);
    // ---- stable tail ----
    unsigned short* WB = (unsigned short*)(w + 191954944);   // 262KB converted weights
    float* G     = (float*)(w + 200343552);
    unsigned short* PB = (unsigned short*)(w + 200671232);   // 128KB
    if (ws_size < 200933376ull) return;

    // one-time weight prep (all conversions + transposes in one dispatch)
    k_wprep<<<1952, 256, 0, stream>>>(fcb_w1, fcb_w2, fcb_w3, gi_w, gt_w, WB,
                                      scb_w1, scb_w2, W1T2, W2T2);

    // ---- global intention (mixer) ----
    for (int nb = 0; nb < 2; ++nb) {
        // nb=0: gather fused (reads item_embed[seq]); nb=1: in-place LN on NV
        k_lnt<<<dim3(4, TB), 128, 0, stream>>>(NV, nb == 0 ? seq : nullptr, item_embed,
                                               scb_ln_g + nb * TH, scb_ln_b + nb * TH, NV, NVT);
        k_mm1<<<dim3(4, TB), 256, 0, stream>>>(NVT, W1T2 + nb * 114688, T);
        k_mm2l<<<dim3(4, TB), 256, 0, stream>>>(T, W2T2 + nb * 106496, NV,
                                                fcb_ln_g + nb * TH, fcb_ln_b + nb * TH);
        k_ffuse<<<1024, 256, 0, stream>>>(NV, WB + nb * 8192, WB + 16384 + nb * 8192, ZB,
                                          TB * TL * 4 / 64);
        k_gmm_b<<<TB * TL / 128, 256, 0, stream>>>(ZB, WB + 32768 + nb * 16384, NV, NV);
    }
    k_pool<<<TB, 256, 0, stream>>>(NV, wv, G);

    // ---- local intention (GAT, bf16 features) ----
    k_gather2<<<(TNI * 16 + TNT * 16 + 255) / 256, 256, 0, stream>>>(
        item_embed, item_ids, ITEMHB, TNI, tax_embed, tax_ids, TAXB0, TNT);

    unsigned short* curb = TAXB0;
    unsigned short* nxtb = TAXB1;
    for (int hop = 0; hop < 2; ++hop) {
        const unsigned short* WiB = WB + 65536 + hop * 16384;
        const unsigned short* WtB = WB + 98304 + hop * 16384;
        k_gmm3<<<TNI / 128 + 2 * (TNT / 128), 256, 0, stream>>>(
            ITEMHB, WiB, FSIB, TNI / 128,
            curb, WiB, FDIB, TNT / 128,
            curb, WtB, FSTB);
        int total = (TNI + 3 * TNT) * TNH;
        k_scores4<<<(total + 255) / 256, 256, 0, stream>>>(
            FSIB, gi_al + hop * TH, ELI, TNI,
            FDIB, gi_ar + hop * TH, ERI, TNT,
            FSTB, gt_al + hop * TH, ELT, TNT,
            FSTB, gt_ar + hop * TH, ERT, TNT);
        k_gat<<<TNT, 128, 0, stream>>>(curb, FSIB, ELI, ERI, i2t_src, gi_b + hop * TH,
                                       FSTB, ELT, ERT, t2t_src, gt_b + hop * TH, nxtb, ACC, hop);
        unsigned short* tmp = curb; curb = nxtb; nxtb = tmp;
    }

    // ---- fuse + final ----
    k_locfuse<<<TB, 128, 0, stream>>>(root, ACC, G, liw_g, liw_b, int_g, int_b, uni_w, PB);
    k_final_m2<<<TIPAD / 128, 256, 0, stream>>>(PB, item_embed, (float*)d_out);
}

// Round 16
// 925.257 us; speedup vs baseline: 1.1692x; 1.0253x over previous
//
#include <hip/hip_runtime.h>
#include <hip/hip_bf16.h>

// ---- model dims ----
constexpr int TB = 512, TL = 200, TH = 128, TNH = 4, TD = 32;
constexpr int TFT = 32, TTP = 64, TIP = 200;
constexpr int TSH = 512, TFH = 256;
constexpr int TITEMS = 100001;
constexpr int TNT = TB * TTP;   // 32768
constexpr int TNI = TB * TIP;   // 102400
constexpr int TLP = 224;        // L padded (K of scb GEMM1)
constexpr int TIPAD = 100096;   // items padded to 128

typedef __attribute__((ext_vector_type(8))) short short8v;
typedef __attribute__((ext_vector_type(4))) float f32x4;

// tanh-form gelu, |err| <= ~3e-4 (below bf16 quantization of the result)
__device__ inline float gelu_fast(float x) {
    float u = x + 0.044715f * x * x * x;
    float e = exp2f(-2.302208f * u);
    return x / (1.0f + e);
}
__device__ inline unsigned short to_bf16u(float x) {
    __hip_bfloat16 h = __float2bfloat16(x);
    return *reinterpret_cast<unsigned short*>(&h);
}
__device__ inline float bfu_to_f(unsigned short u) {
    unsigned int x = ((unsigned int)u) << 16;
    return __uint_as_float(x);
}

__device__ inline float block_reduce_sum(float v, float* red) {
    for (int o = 32; o > 0; o >>= 1) v += __shfl_down(v, o, 64);
    int nw = blockDim.x >> 6;
    if ((threadIdx.x & 63) == 0) red[threadIdx.x >> 6] = v;
    __syncthreads();
    float r = 0.f;
    for (int w = 0; w < nw; ++w) r += red[w];
    __syncthreads();
    return r;
}

// merged double gather: out[r,:] = bf16(table[idx[r],:]) for two tables
__global__ __launch_bounds__(256) void k_gather2(const float* __restrict__ tab0,
                                                 const int* __restrict__ idx0,
                                                 unsigned short* __restrict__ out0, int n0,
                                                 const float* __restrict__ tab1,
                                                 const int* __restrict__ idx1,
                                                 unsigned short* __restrict__ out1, int n1) {
    int e = blockIdx.x * 256 + threadIdx.x;
    const float* tab; const int* idx; unsigned short* out;
    if (e < n0 * 16) { tab = tab0; idx = idx0; out = out0; }
    else {
        e -= n0 * 16;
        if (e >= n1 * 16) return;
        tab = tab1; idx = idx1; out = out1;
    }
    int r = e >> 4, c = e & 15;
    const float4 a = ((const float4*)tab)[(size_t)idx[r] * 32 + c * 2];
    const float4 b = ((const float4*)tab)[(size_t)idx[r] * 32 + c * 2 + 1];
    uint4 u;
    u.x = (unsigned int)to_bf16u(a.x) | ((unsigned int)to_bf16u(a.y) << 16);
    u.y = (unsigned int)to_bf16u(a.z) | ((unsigned int)to_bf16u(a.w) << 16);
    u.z = (unsigned int)to_bf16u(b.x) | ((unsigned int)to_bf16u(b.y) << 16);
    u.w = (unsigned int)to_bf16u(b.z) | ((unsigned int)to_bf16u(b.w) << 16);
    *(uint4*)(out + (size_t)e * 8) = u;
}

// merged one-time weight prep: blocks [0,512) = small-weight cvt; [512,1952) = scb transposes
__global__ __launch_bounds__(256) void k_wprep(const float* __restrict__ fw1, const float* __restrict__ fw2,
                                               const float* __restrict__ fw3, const float* __restrict__ giw,
                                               const float* __restrict__ gtw, unsigned short* __restrict__ WB,
                                               const float* __restrict__ sw1, const float* __restrict__ sw2,
                                               unsigned short* __restrict__ W1T,
                                               unsigned short* __restrict__ W2T) {
    int bxg = blockIdx.x;
    if (bxg < 512) {
        int idx = bxg * 256 + threadIdx.x;  // 0..131071
        float v;
        if (idx < 16384) {
            int nb = idx >> 13, r = idx & 8191, n = r >> 5, k = r & 31;
            v = fw1[(size_t)nb * 8192 + k * 256 + n];
        } else if (idx < 32768) {
            int t = idx - 16384;
            int nb = t >> 13, r = t & 8191, n = r >> 8, k = r & 255;
            v = fw2[(size_t)nb * 8192 + k * 32 + n];
        } else if (idx < 65536) {
            int t = idx - 32768;
            int nb = t >> 14, r = t & 16383, n = r >> 7, k = r & 127;
            v = fw3[(size_t)nb * 16384 + k * 128 + n];
        } else if (idx < 98304) {
            int t = idx - 65536;
            int hop = t >> 14, r = t & 16383, n = r >> 7, k = r & 127;
            v = giw[(size_t)hop * 16384 + k * 128 + n];
        } else {
            int t = idx - 98304;
            int hop = t >> 14, r = t & 16383, n = r >> 7, k = r & 127;
            v = gtw[(size_t)hop * 16384 + k * 128 + n];
        }
        WB[idx] = to_bf16u(v);
        return;
    }
    int bx = bxg - 512;
    if (bx < 1024) {
        int nb = bx >> 9, s = bx & 511, l = threadIdx.x;
        if (l < TLP)
            W1T[(size_t)nb * 114688 + (size_t)s * TLP + l] =
                to_bf16u(l < TL ? sw1[(size_t)nb * 102400 + l * TSH + s] : 0.f);
    } else {
        int t = bx - 1024;           // 0..415
        int nb = t / 208, l = t % 208;
        for (int it = 0; it < 2; ++it) {
            int s = it * 256 + threadIdx.x;
            W2T[(size_t)nb * 106496 + (size_t)l * TSH + s] =
                to_bf16u(l < TL ? sw2[(size_t)nb * 102400 + s * TL + l] : 0.f);
        }
    }
}

// fused [gather +] LN + bf16 transpose
__global__ __launch_bounds__(128) void k_lnt(const float* __restrict__ V,
                                             const int* __restrict__ seqp, const float* __restrict__ tab,
                                             const float* __restrict__ g, const float* __restrict__ b,
                                             float* __restrict__ NV, unsigned short* __restrict__ NVT) {
    __shared__ float tl[64][129];
    __shared__ float mrow[64], irow[64];
    int bb = blockIdx.y, l0 = blockIdx.x * 64, tid = threadIdx.x;
    for (int i = tid; i < 2048; i += 128) {
        int r = i >> 5, c = i & 31;
        int l = l0 + r;
        float4 v = {0.f, 0.f, 0.f, 0.f};
        if (l < TL) {
            const float* src = seqp ? (tab + (size_t)seqp[bb * TL + l] * TH)
                                    : (V + ((size_t)bb * TL + l) * TH);
            v = *(const float4*)(src + c * 4);
        }
        tl[r][c * 4 + 0] = v.x; tl[r][c * 4 + 1] = v.y;
        tl[r][c * 4 + 2] = v.z; tl[r][c * 4 + 3] = v.w;
    }
    __syncthreads();
    {
        int row = tid >> 1, half = tid & 1;
        float s = 0.f, sq = 0.f;
        for (int k = 0; k < 64; ++k) {
            float v = tl[row][half * 64 + k];
            s += v; sq += v * v;
        }
        s += __shfl_xor(s, 1);
        sq += __shfl_xor(sq, 1);
        if (half == 0) {
            float mean = s * (1.f / 128.f);
            mrow[row] = mean;
            irow[row] = rsqrtf(sq * (1.f / 128.f) - mean * mean + 1e-8f);
        }
    }
    __syncthreads();
    for (int i = tid; i < 2048; i += 128) {
        int r = i >> 5, c = i & 31;
        int l = l0 + r;
        float4 o = {0.f, 0.f, 0.f, 0.f};
        if (l < TL) {
            float4 v = *(float4*)&tl[r][c * 4];
            float m = mrow[r], inv = irow[r];
            const float4 gg = ((const float4*)g)[c];
            const float4 bv = ((const float4*)b)[c];
            o.x = (v.x - m) * inv * gg.x + bv.x;
            o.y = (v.y - m) * inv * gg.y + bv.y;
            o.z = (v.z - m) * inv * gg.z + bv.z;
            o.w = (v.w - m) * inv * gg.w + bv.w;
            *(float4*)(NV + ((size_t)bb * TL + l) * TH + c * 4) = o;
        }
        *(float4*)&tl[r][c * 4] = o;
    }
    __syncthreads();
    int h = tid;
    int ng = (l0 + 64 > TLP) ? (TLP - l0) / 8 : 8;
    for (int lg = 0; lg < ng; ++lg) {
        uint4 u;
        unsigned int p[4];
#pragma unroll
        for (int q = 0; q < 4; ++q) {
            unsigned short ua = to_bf16u(tl[lg * 8 + q * 2 + 0][h]);
            unsigned short ub = to_bf16u(tl[lg * 8 + q * 2 + 1][h]);
            p[q] = (unsigned int)ua | ((unsigned int)ub << 16);
        }
        u.x = p[0]; u.y = p[1]; u.z = p[2]; u.w = p[3];
        *(uint4*)(NVT + ((size_t)bb * TH + h) * TLP + l0 + lg * 8) = u;
    }
}

// scb GEMM1 (full batch grid)
__global__ __launch_bounds__(256) void k_mm1(const unsigned short* __restrict__ NVT,
                                             const unsigned short* __restrict__ W1T,
                                             unsigned short* __restrict__ T) {
    __shared__ unsigned short As[128][40];
    __shared__ unsigned short Bs[128][40];
    int tid = threadIdx.x;
    int b = blockIdx.y;
    int s0 = blockIdx.x * 128;
    int lane = tid & 63, wid = tid >> 6;
    int mw = wid >> 1, nw = wid & 1;
    f32x4 accT[4][4];
#pragma unroll
    for (int j = 0; j < 4; ++j)
#pragma unroll
        for (int i = 0; i < 4; ++i) accT[j][i] = (f32x4){0.f, 0.f, 0.f, 0.f};
    const unsigned short* Abase = NVT + (size_t)b * TH * TLP;
    const unsigned short* Bbase = W1T + (size_t)s0 * TLP;
    for (int kc = 0; kc < 7; ++kc) {
        __syncthreads();
        for (int i = tid; i < 512; i += 256) {
            int r = i >> 2, q = i & 3;
            *(uint4*)&As[r][q * 8] = *(const uint4*)(Abase + (size_t)r * TLP + kc * 32 + q * 8);
            *(uint4*)&Bs[r][q * 8] = *(const uint4*)(Bbase + (size_t)r * TLP + kc * 32 + q * 8);
        }
        __syncthreads();
        int ko = (lane >> 4) * 8;
        short8v af[4], bfr[4];
#pragma unroll
        for (int t = 0; t < 4; ++t) {
            af[t] = *(const short8v*)&As[mw * 64 + t * 16 + (lane & 15)][ko];
            bfr[t] = *(const short8v*)&Bs[nw * 64 + t * 16 + (lane & 15)][ko];
        }
#pragma unroll
        for (int j = 0; j < 4; ++j)
#pragma unroll
            for (int i = 0; i < 4; ++i)
                accT[j][i] = __builtin_amdgcn_mfma_f32_16x16x32_bf16(bfr[j], af[i], accT[j][i], 0, 0, 0);
    }
    int rbase = (lane >> 4) * 4, col = lane & 15;
#pragma unroll
    for (int i = 0; i < 4; ++i)
#pragma unroll
        for (int j = 0; j < 4; ++j) {
            int h = mw * 64 + i * 16 + col;
            int sb = s0 + nw * 64 + j * 16 + rbase;
            ushort4 pk;
            pk.x = to_bf16u(gelu_fast(accT[j][i][0]));
            pk.y = to_bf16u(gelu_fast(accT[j][i][1]));
            pk.z = to_bf16u(gelu_fast(accT[j][i][2]));
            pk.w = to_bf16u(gelu_fast(accT[j][i][3]));
            *(ushort4*)(T + ((size_t)b * TH + h) * TSH + sb) = pk;
        }
}

// scb GEMM2 + fcb LN fused (full batch grid)
__global__ __launch_bounds__(256) void k_mm2l(const unsigned short* __restrict__ T,
                                              const unsigned short* __restrict__ W2T,
                                              float* __restrict__ NV,
                                              const float* __restrict__ lg, const float* __restrict__ lb) {
    __shared__ unsigned short As[128][40];
    __shared__ unsigned short Bs[64][40];
    __shared__ float vsl[64][132];
    __shared__ float mrow[64], irow[64];
    int tid = threadIdx.x;
    int b = blockIdx.y;
    int l0 = blockIdx.x * 64;
    int lane = tid & 63, wid = tid >> 6;
    f32x4 acc[2][4];
#pragma unroll
    for (int i = 0; i < 2; ++i)
#pragma unroll
        for (int j = 0; j < 4; ++j) acc[i][j] = (f32x4){0.f, 0.f, 0.f, 0.f};
    const unsigned short* Abase = T + (size_t)b * TH * TSH;
    for (int kc = 0; kc < 16; ++kc) {
        __syncthreads();
        for (int i = tid; i < 512; i += 256) {
            int r = i >> 2, q = i & 3;
            *(uint4*)&As[r][q * 8] = *(const uint4*)(Abase + (size_t)r * TSH + kc * 32 + q * 8);
        }
        {
            int r = tid >> 2, q = tid & 3;
            int l = l0 + r;
            uint4 v = {0u, 0u, 0u, 0u};
            if (l < 208) v = *(const uint4*)(W2T + (size_t)l * TSH + kc * 32 + q * 8);
            *(uint4*)&Bs[r][q * 8] = v;
        }
        __syncthreads();
        int ko = (lane >> 4) * 8;
        short8v af[2], bfr[4];
#pragma unroll
        for (int t = 0; t < 2; ++t)
            af[t] = *(const short8v*)&As[wid * 32 + t * 16 + (lane & 15)][ko];
#pragma unroll
        for (int j = 0; j < 4; ++j)
            bfr[j] = *(const short8v*)&Bs[j * 16 + (lane & 15)][ko];
#pragma unroll
        for (int i = 0; i < 2; ++i)
#pragma unroll
            for (int j = 0; j < 4; ++j)
                acc[i][j] = __builtin_amdgcn_mfma_f32_16x16x32_bf16(af[i], bfr[j], acc[i][j], 0, 0, 0);
    }
    int rbase = (lane >> 4) * 4, col = lane & 15;
#pragma unroll
    for (int i = 0; i < 2; ++i)
#pragma unroll
        for (int j = 0; j < 4; ++j) {
            int l = l0 + j * 16 + col;
            int h0 = wid * 32 + i * 16 + rbase;
            float4 res = {0.f, 0.f, 0.f, 0.f};
            if (l < TL) res = *(const float4*)(NV + ((size_t)b * TL + l) * TH + h0);
            float4 o;
            o.x = acc[i][j][0] + res.x;
            o.y = acc[i][j][1] + res.y;
            o.z = acc[i][j][2] + res.z;
            o.w = acc[i][j][3] + res.w;
            *(float4*)&vsl[j * 16 + col][h0] = o;
        }
    __syncthreads();
    int row = tid >> 2, q = tid & 3;
    {
        float s = 0.f, sq = 0.f;
        for (int k = 0; k < 32; ++k) {
            float v = vsl[row][q * 32 + k];
            s += v; sq += v * v;
        }
        s += __shfl_xor(s, 1); s += __shfl_xor(s, 2);
        sq += __shfl_xor(sq, 1); sq += __shfl_xor(sq, 2);
        if (q == 0) {
            float mean = s * (1.f / 128.f);
            mrow[row] = mean;
            irow[row] = rsqrtf(sq * (1.f / 128.f) - mean * mean + 1e-8f);
        }
    }
    __syncthreads();
    {
        int l = l0 + row;
        if (l < TL) {
            float mean = mrow[row], inv = irow[row];
            float* dst = NV + ((size_t)b * TL + l) * TH + q * 32;
#pragma unroll
            for (int k4 = 0; k4 < 8; ++k4) {
                float4 v = *(float4*)&vsl[row][q * 32 + k4 * 4];
                const float4 gg = ((const float4*)lg)[q * 8 + k4];
                const float4 bv = ((const float4*)lb)[q * 8 + k4];
                float4 o;
                o.x = (v.x - mean) * inv * gg.x + bv.x;
                o.y = (v.y - mean) * inv * gg.y + bv.y;
                o.z = (v.z - mean) * inv * gg.z + bv.z;
                o.w = (v.w - mean) * inv * gg.w + bv.w;
                *(float4*)(dst + k4 * 4) = o;
            }
        }
    }
}

// fused fcb stage1+2; PERSISTENT grid-stride over 64-row tiles
__global__ __launch_bounds__(256) void k_ffuse(const float* __restrict__ NV,
                                               const unsigned short* __restrict__ FW1B,
                                               const unsigned short* __restrict__ FW2B,
                                               unsigned short* __restrict__ Z, int ntiles) {
    __shared__ unsigned short As[64][40];
    __shared__ unsigned short Bs2[32 * 264];
    __shared__ unsigned short Yl[64 * 264];
    int tid = threadIdx.x;
    int lane = tid & 63, wid = tid >> 6;
    int col = lane & 15, rbase = (lane >> 4) * 4, ko = (lane >> 4) * 8;
    for (int i = tid; i < 1024; i += 256) {
        int r = i >> 2, q = i & 3;
        *(uint4*)&Yl[r * 40 + q * 8] = *(const uint4*)(FW1B + r * 32 + q * 8);
    }
    for (int i = tid; i < 1024; i += 256) {
        int r = i >> 5, q = i & 31;
        *(uint4*)&Bs2[r * 264 + q * 8] = *(const uint4*)(FW2B + r * 256 + q * 8);
    }
    __syncthreads();
    short8v bfr[4];
#pragma unroll
    for (int t = 0; t < 4; ++t)
        bfr[t] = *(const short8v*)&Yl[(wid * 64 + t * 16 + col) * 40 + ko];
    __syncthreads();
    int mrow = wid * 16 + col;
    int sw2 = ((mrow >> 2) & 7) << 3;
    for (int tile = blockIdx.x; tile < ntiles; tile += gridDim.x) {
        int m0 = tile * 64;
        for (int i = tid; i < 512; i += 256) {
            int r = i >> 3, q = i & 7;
            const float4 v = *(const float4*)(NV + (size_t)(m0 + r) * 32 + q * 4);
            ushort4 u;
            u.x = to_bf16u(v.x); u.y = to_bf16u(v.y); u.z = to_bf16u(v.z); u.w = to_bf16u(v.w);
            *(ushort4*)&As[r][q * 4] = u;
        }
        __syncthreads();
        {
            short8v af[4];
#pragma unroll
            for (int t = 0; t < 4; ++t)
                af[t] = *(const short8v*)&As[t * 16 + col][ko];
            f32x4 yt[4][4];
#pragma unroll
            for (int j = 0; j < 4; ++j)
#pragma unroll
                for (int i = 0; i < 4; ++i) yt[j][i] = (f32x4){0.f, 0.f, 0.f, 0.f};
#pragma unroll
            for (int j = 0; j < 4; ++j)
#pragma unroll
                for (int i = 0; i < 4; ++i)
                    yt[j][i] = __builtin_amdgcn_mfma_f32_16x16x32_bf16(bfr[j], af[i], yt[j][i], 0, 0, 0);
#pragma unroll
            for (int i = 0; i < 4; ++i)
#pragma unroll
                for (int j = 0; j < 4; ++j) {
                    int m = i * 16 + col;
                    int n0 = wid * 64 + j * 16 + rbase;
                    ushort4 pk;
                    pk.x = to_bf16u(gelu_fast(yt[j][i][0]));
                    pk.y = to_bf16u(gelu_fast(yt[j][i][1]));
                    pk.z = to_bf16u(gelu_fast(yt[j][i][2]));
                    pk.w = to_bf16u(gelu_fast(yt[j][i][3]));
                    int idx = (m * 264 + n0) ^ (((m >> 2) & 7) << 3);
                    *(ushort4*)&Yl[idx] = pk;
                }
        }
        __syncthreads();
        {
            f32x4 acc2[2];
            acc2[0] = (f32x4){0.f, 0.f, 0.f, 0.f};
            acc2[1] = (f32x4){0.f, 0.f, 0.f, 0.f};
            for (int kc = 0; kc < 8; ++kc) {
                int ko2 = kc * 32 + ko;
                short8v a2 = *(const short8v*)&Yl[(mrow * 264 + ko2) ^ sw2];
                short8v b0 = *(const short8v*)&Bs2[col * 264 + ko2];
                short8v b1 = *(const short8v*)&Bs2[(16 + col) * 264 + ko2];
                acc2[0] = __builtin_amdgcn_mfma_f32_16x16x32_bf16(a2, b0, acc2[0], 0, 0, 0);
                acc2[1] = __builtin_amdgcn_mfma_f32_16x16x32_bf16(a2, b1, acc2[1], 0, 0, 0);
            }
#pragma unroll
            for (int j = 0; j < 2; ++j)
#pragma unroll
                for (int r = 0; r < 4; ++r)
                    Z[(size_t)(m0 + wid * 16 + rbase + r) * 32 + j * 16 + col] =
                        to_bf16u(acc2[j][r]);
        }
        __syncthreads();
    }
}

// C f32 [N,128] = A[N,128](bf16) @ WB[n][k](bf16) (+R f32, in-place safe C==R)
__global__ __launch_bounds__(256) void k_gmm_b(const unsigned short* __restrict__ A,
                                               const unsigned short* __restrict__ WB,
                                               const float* __restrict__ R,
                                               float* __restrict__ C) {
    __shared__ unsigned short As[128][40];
    __shared__ unsigned short Bs[128][40];
    int tid = threadIdx.x;
    int m0 = blockIdx.x * 128;
    int lane = tid & 63, wid = tid >> 6;
    int mw = wid >> 1, nw = wid & 1;
    f32x4 acc[4][4];
#pragma unroll
    for (int i = 0; i < 4; ++i)
#pragma unroll
        for (int j = 0; j < 4; ++j) acc[i][j] = (f32x4){0.f, 0.f, 0.f, 0.f};
    for (int kc = 0; kc < 4; ++kc) {
        __syncthreads();
        for (int i = tid; i < 512; i += 256) {
            int r = i >> 2, q = i & 3;
            *(uint4*)&As[r][q * 8] = *(const uint4*)(A + (size_t)(m0 + r) * TH + kc * 32 + q * 8);
            *(uint4*)&Bs[r][q * 8] = *(const uint4*)(WB + (size_t)r * TH + kc * 32 + q * 8);
        }
        __syncthreads();
        int ko = (lane >> 4) * 8;
        short8v af[4], bfr[4];
#pragma unroll
        for (int t = 0; t < 4; ++t) {
            af[t] = *(const short8v*)&As[mw * 64 + t * 16 + (lane & 15)][ko];
            bfr[t] = *(const short8v*)&Bs[nw * 64 + t * 16 + (lane & 15)][ko];
        }
#pragma unroll
        for (int i = 0; i < 4; ++i)
#pragma unroll
            for (int j = 0; j < 4; ++j)
                acc[i][j] = __builtin_amdgcn_mfma_f32_16x16x32_bf16(af[i], bfr[j], acc[i][j], 0, 0, 0);
    }
    int rbase = (lane >> 4) * 4, col = lane & 15;
#pragma unroll
    for (int i = 0; i < 4; ++i)
#pragma unroll
        for (int j = 0; j < 4; ++j) {
            int n = nw * 64 + j * 16 + col;
#pragma unroll
            for (int r = 0; r < 4; ++r) {
                size_t off = (size_t)(m0 + mw * 64 + i * 16 + rbase + r) * TH + n;
                float v = acc[i][j][r];
                if (R) v += R[off];
                C[off] = v;
            }
        }
}

// merged 3x GAT feature GEMMs WITH fused attention scores in epilogue.
// C bf16 = A @ WB; el/er scores computed from f32 accumulators.
__global__ __launch_bounds__(256) void k_gmm3s(
        const unsigned short* __restrict__ A0, const unsigned short* __restrict__ W0,
        unsigned short* __restrict__ C0, int nb0,
        const float* __restrict__ sv0, float* __restrict__ so0,
        const unsigned short* __restrict__ A1, const unsigned short* __restrict__ W1,
        unsigned short* __restrict__ C1, int nb1,
        const float* __restrict__ sv1, float* __restrict__ so1,
        const unsigned short* __restrict__ A2, const unsigned short* __restrict__ W2,
        unsigned short* __restrict__ C2,
        const float* __restrict__ sv2a, float* __restrict__ so2a,
        const float* __restrict__ sv2b, float* __restrict__ so2b) {
    __shared__ unsigned short As[128][40];
    __shared__ unsigned short Bs[128][40];
    __shared__ float svA[128];
    __shared__ float svB[128];
    int bx = blockIdx.x;
    const unsigned short *A, *WBp;
    unsigned short* C;
    const float *sva, *svb;
    float *soa, *sob;
    if (bx < nb0) { A = A0; WBp = W0; C = C0; sva = sv0; soa = so0; svb = nullptr; sob = nullptr; }
    else if (bx - nb0 < nb1) { bx -= nb0; A = A1; WBp = W1; C = C1; sva = sv1; soa = so1; svb = nullptr; sob = nullptr; }
    else { bx -= nb0 + nb1; A = A2; WBp = W2; C = C2; sva = sv2a; soa = so2a; svb = sv2b; sob = so2b; }
    int tid = threadIdx.x;
    if (tid < 128) svA[tid] = sva[tid];
    else if (svb) svB[tid - 128] = svb[tid - 128];
    int m0 = bx * 128;
    int lane = tid & 63, wid = tid >> 6;
    int mw = wid >> 1, nw = wid & 1;
    f32x4 accT[4][4];   // [j][i]: D[n][m]
#pragma unroll
    for (int j = 0; j < 4; ++j)
#pragma unroll
        for (int i = 0; i < 4; ++i) accT[j][i] = (f32x4){0.f, 0.f, 0.f, 0.f};
    for (int kc = 0; kc < 4; ++kc) {
        __syncthreads();
        for (int i = tid; i < 512; i += 256) {
            int r = i >> 2, q = i & 3;
            *(uint4*)&As[r][q * 8] = *(const uint4*)(A + (size_t)(m0 + r) * TH + kc * 32 + q * 8);
            *(uint4*)&Bs[r][q * 8] = *(const uint4*)(WBp + (size_t)r * TH + kc * 32 + q * 8);
        }
        __syncthreads();
        int ko = (lane >> 4) * 8;
        short8v af[4], bfr[4];
#pragma unroll
        for (int t = 0; t < 4; ++t) {
            af[t] = *(const short8v*)&As[mw * 64 + t * 16 + (lane & 15)][ko];
            bfr[t] = *(const short8v*)&Bs[nw * 64 + t * 16 + (lane & 15)][ko];
        }
#pragma unroll
        for (int j = 0; j < 4; ++j)
#pragma unroll
            for (int i = 0; i < 4; ++i)
                accT[j][i] = __builtin_amdgcn_mfma_f32_16x16x32_bf16(bfr[j], af[i], accT[j][i], 0, 0, 0);
    }
    int rbase = (lane >> 4) * 4, col = lane & 15;
#pragma unroll
    for (int i = 0; i < 4; ++i) {
        // feature stores (packed)
#pragma unroll
        for (int j = 0; j < 4; ++j) {
            int m = m0 + mw * 64 + i * 16 + col;
            int n0 = nw * 64 + j * 16 + rbase;
            ushort4 pk;
            pk.x = to_bf16u(accT[j][i][0]);
            pk.y = to_bf16u(accT[j][i][1]);
            pk.z = to_bf16u(accT[j][i][2]);
            pk.w = to_bf16u(accT[j][i][3]);
            *(ushort4*)(C + (size_t)m * TH + n0) = pk;
        }
        // fused scores: head k = nw*2 + hh covers n in [nw*64+hh*32, +32) = regs j=2hh,2hh+1
        float p1[2] = {0.f, 0.f}, p2[2] = {0.f, 0.f};
#pragma unroll
        for (int hh = 0; hh < 2; ++hh)
#pragma unroll
            for (int jj = 0; jj < 2; ++jj) {
                int j = hh * 2 + jj;
#pragma unroll
                for (int r = 0; r < 4; ++r) {
                    int n = nw * 64 + j * 16 + rbase + r;
                    float val = accT[j][i][r];
                    p1[hh] += val * svA[n];
                    if (sob) p2[hh] += val * svB[n];
                }
            }
#pragma unroll
        for (int hh = 0; hh < 2; ++hh) {
            p1[hh] += __shfl_xor(p1[hh], 16, 64);
            p1[hh] += __shfl_xor(p1[hh], 32, 64);
            if (sob) {
                p2[hh] += __shfl_xor(p2[hh], 16, 64);
                p2[hh] += __shfl_xor(p2[hh], 32, 64);
            }
        }
        if ((lane >> 4) == 0) {
            int m = m0 + mw * 64 + i * 16 + col;
#pragma unroll
            for (int hh = 0; hh < 2; ++hh) {
                int k = nw * 2 + hh;
                soa[(size_t)m * 4 + k] = p1[hh];
                if (sob) sob[(size_t)m * 4 + k] = p2[hh];
            }
        }
    }
}

// alpha = softmax(V@wv over L); g = sum_l alpha*V
__global__ __launch_bounds__(256) void k_pool(const float* __restrict__ V, const float* __restrict__ wv,
                                              float* __restrict__ g) {
    __shared__ float sc[TL];
    __shared__ float red[4];
    __shared__ float part[TH];
    int b = blockIdx.x, tid = threadIdx.x;
    int lane = tid & 63, w = tid >> 6;
    for (int l = w; l < TL; l += 4) {
        const float2 v = ((const float2*)(V + (size_t)(b * TL + l) * TH))[lane];
        float a = v.x * wv[2 * lane] + v.y * wv[2 * lane + 1];
        for (int o = 32; o > 0; o >>= 1) a += __shfl_down(a, o, 64);
        if (lane == 0) sc[l] = a;
    }
    __syncthreads();
    float m = (tid < TL) ? sc[tid] : -INFINITY;
    for (int o = 32; o > 0; o >>= 1) m = fmaxf(m, __shfl_down(m, o, 64));
    if ((tid & 63) == 0) red[tid >> 6] = m;
    __syncthreads();
    m = fmaxf(fmaxf(red[0], red[1]), fmaxf(red[2], red[3]));
    __syncthreads();
    float e = (tid < TL) ? expf(sc[tid] - m) : 0.f;
    float s = block_reduce_sum(e, red);
    if (tid < TL) sc[tid] = e / s;
    __syncthreads();
    {
        int h = tid & 127, half = tid >> 7;
        float a = 0.f;
        for (int l = half * 100; l < half * 100 + 100; ++l)
            a += sc[l] * V[(size_t)(b * TL + l) * TH + h];
        if (half) part[h] = a;
        __syncthreads();
        if (!half) g[b * TH + h] = a + part[h];
    }
}

// fused per-dst-node GAT; cur bf16, fs bf16, nxt bf16 out, ACC f32
__global__ __launch_bounds__(128) void k_gat(const unsigned short* __restrict__ tax_cur,
                                             const unsigned short* __restrict__ fs_i, const float* __restrict__ el_i,
                                             const float* __restrict__ er_i, const int* __restrict__ src_i,
                                             const float* __restrict__ bi,
                                             const unsigned short* __restrict__ fs_t, const float* __restrict__ el_t,
                                             const float* __restrict__ er_t, const int* __restrict__ src_t,
                                             const float* __restrict__ bt,
                                             unsigned short* __restrict__ tax_nxt,
                                             float* __restrict__ acc, int hop) {
    int n = blockIdx.x, h = threadIdx.x, k = h >> 5;
    float cur = bfu_to_f(tax_cur[(size_t)n * TH + h]);
    float ti, tt2;
    {
        float er = er_i[n * 4 + k];
        int s[4]; float e[4]; float m = -INFINITY;
#pragma unroll
        for (int j = 0; j < 4; ++j) {
            s[j] = src_i[n * 4 + j];
            float xx = el_i[s[j] * 4 + k] + er;
            e[j] = xx > 0.f ? xx : 0.2f * xx;
            m = fmaxf(m, e[j]);
        }
        float ssum = 0.f, av = 0.f;
#pragma unroll
        for (int j = 0; j < 4; ++j) {
            float a = expf(e[j] - m);
            ssum += a;
            av += a * bfu_to_f(fs_i[(size_t)s[j] * TH + h]);
        }
        ti = fmaxf(av / ssum + cur + bi[h], 0.f);
    }
    {
        float er = er_t[n * 4 + k];
        int s[2]; float e[2]; float m = -INFINITY;
#pragma unroll
        for (int j = 0; j < 2; ++j) {
            s[j] = src_t[n * 2 + j];
            float xx = el_t[s[j] * 4 + k] + er;
            e[j] = xx > 0.f ? xx : 0.2f * xx;
            m = fmaxf(m, e[j]);
        }
        float ssum = 0.f, av = 0.f;
#pragma unroll
        for (int j = 0; j < 2; ++j) {
            float a = expf(e[j] - m);
            ssum += a;
            av += a * bfu_to_f(fs_t[(size_t)s[j] * TH + h]);
        }
        tt2 = fmaxf(av / ssum + cur + bt[h], 0.f);
    }
    float nx = ti + tt2;
    size_t ai = (size_t)n * TH + h;
    tax_nxt[ai] = to_bf16u(nx);
    acc[ai] = (hop == 0) ? nx : acc[ai] + nx;
}

// fused local-gather + mul + LN/softmax/LN + @uni_w -> PB bf16
__global__ __launch_bounds__(128) void k_locfuse(const int* __restrict__ root, const float* __restrict__ acc,
                                                 const float* __restrict__ g,
                                                 const float* __restrict__ liw_g, const float* __restrict__ liw_b,
                                                 const float* __restrict__ int_g, const float* __restrict__ int_b,
                                                 const float* __restrict__ uni_w,
                                                 unsigned short* __restrict__ PB) {
    __shared__ float loc[TFT][TH + 1];
    __shared__ float gsh[TH];
    __shared__ float lm[TFT], wv_[TFT], inten[TH];
    __shared__ float red[2];
    int b = blockIdx.x, tid = threadIdx.x;
    float gv = g[b * TH + tid];
    gsh[tid] = gv;
    for (int f = 0; f < TFT; ++f) {
        int r = root[b * TFT + f];
        float v = 0.f;
        if (r != -1) v = acc[(size_t)(b * TTP + (r < 0 ? 0 : r)) * TH + tid] * 0.5f;
        loc[f][tid] = v;
    }
    __syncthreads();
    {
        int f = tid >> 2, q = tid & 3;
        float a = 0.f;
        const float* lp = &loc[f][q * 32];
        const float* gp = &gsh[q * 32];
        for (int k = 0; k < 32; ++k) a += lp[k] * gp[k];
        a += __shfl_xor(a, 1);
        a += __shfl_xor(a, 2);
        if (q == 0) lm[f] = a;
    }
    __syncthreads();
    if (tid < TFT) {
        float mean = 0.f;
        for (int f = 0; f < TFT; ++f) mean += lm[f];
        mean *= (1.f / TFT);
        float var = 0.f;
        for (int f = 0; f < TFT; ++f) { float d = lm[f] - mean; var += d * d; }
        var *= (1.f / TFT);
        float ln = (lm[tid] - mean) * rsqrtf(var + 1e-8f) * liw_g[tid] + liw_b[tid];
        wv_[tid] = (lm[tid] != 0.f) ? ln : -INFINITY;
    }
    __syncthreads();
    if (tid < TFT) {
        float mx = -INFINITY;
        for (int f = 0; f < TFT; ++f) mx = fmaxf(mx, wv_[f]);
        float s = 0.f;
        for (int f = 0; f < TFT; ++f) s += expf(wv_[f] - mx);
        lm[tid] = expf(wv_[tid] - mx) / s;
    }
    __syncthreads();
    float ip = gv;
    for (int f = 0; f < TFT; ++f) ip += lm[f] * loc[f][tid];
    float mean = block_reduce_sum(ip, red) * (1.f / TH);
    float d = ip - mean;
    float var = block_reduce_sum(d * d, red) * (1.f / TH);
    inten[tid] = d * rsqrtf(var + 1e-8f) * int_g[tid] + int_b[tid];
    __syncthreads();
    float a = 0.f;
    for (int hp = 0; hp < TH; ++hp) a += inten[hp] * uni_w[hp * TH + tid];
    PB[(size_t)b * TH + tid] = to_bf16u(a);
}

// out[b,i] = PB[b,:] . E[i,:]; swapped MFMA -> packed float4 item-contiguous stores
__global__ __launch_bounds__(256) void k_final_m2(const unsigned short* __restrict__ PB,
                                                  const float* __restrict__ E,
                                                  float* __restrict__ out) {
    __shared__ unsigned short Bs[128][136];
    int tid = threadIdx.x;
    int i0 = blockIdx.x * 128;
    for (int i = tid; i < 2048; i += 256) {
        int r = i >> 4, q = i & 15;
        int it = i0 + r;
        float4 a = {0.f, 0.f, 0.f, 0.f}, b = {0.f, 0.f, 0.f, 0.f};
        if (it < TITEMS) {
            a = *(const float4*)(E + (size_t)it * TH + q * 8);
            b = *(const float4*)(E + (size_t)it * TH + q * 8 + 4);
        }
        ushort4 u0, u1;
        u0.x = to_bf16u(a.x); u0.y = to_bf16u(a.y); u0.z = to_bf16u(a.z); u0.w = to_bf16u(a.w);
        u1.x = to_bf16u(b.x); u1.y = to_bf16u(b.y); u1.z = to_bf16u(b.z); u1.w = to_bf16u(b.w);
        *(ushort4*)&Bs[r][q * 8] = u0;
        *(ushort4*)&Bs[r][q * 8 + 4] = u1;
    }
    __syncthreads();
    int lane = tid & 63, wid = tid >> 6;
    int mw = wid >> 1, nw = wid & 1;
    int rbase = (lane >> 4) * 4, col = lane & 15;
#pragma unroll 1
    for (int b0 = 0; b0 < TB; b0 += 128) {
        f32x4 accT[4][4];   // [j][i]: D[item][b]
#pragma unroll
        for (int j = 0; j < 4; ++j)
#pragma unroll
            for (int i = 0; i < 4; ++i) accT[j][i] = (f32x4){0.f, 0.f, 0.f, 0.f};
#pragma unroll
        for (int kc = 0; kc < 4; ++kc) {
            int ko = kc * 32 + (lane >> 4) * 8;
            short8v af[4], bfr[4];
#pragma unroll
            for (int t = 0; t < 4; ++t) {
                af[t] = *(const short8v*)(PB + (size_t)(b0 + mw * 64 + t * 16 + col) * TH + ko);
                bfr[t] = *(const short8v*)&Bs[nw * 64 + t * 16 + col][ko];
            }
#pragma unroll
            for (int j = 0; j < 4; ++j)
#pragma unroll
                for (int i = 0; i < 4; ++i)
                    accT[j][i] = __builtin_amdgcn_mfma_f32_16x16x32_bf16(bfr[j], af[i], accT[j][i], 0, 0, 0);
        }
#pragma unroll
        for (int i = 0; i < 4; ++i)
#pragma unroll
            for (int j = 0; j < 4; ++j) {
                int bb = b0 + mw * 64 + i * 16 + col;
                int ii = i0 + nw * 64 + j * 16 + rbase;
                if (ii + 3 < TITEMS) {
                    float4 o;
                    o.x = accT[j][i][0]; o.y = accT[j][i][1];
                    o.z = accT[j][i][2]; o.w = accT[j][i][3];
                    *(float4*)(out + (size_t)bb * TITEMS + ii) = o;
                } else {
#pragma unroll
                    for (int r = 0; r < 4; ++r)
                        if (ii + r < TITEMS)
                            out[(size_t)bb * TITEMS + ii + r] = accT[j][i][r];
                }
            }
    }
}

extern "C" void kernel_launch(void* const* d_in, const int* in_sizes, int n_in,
                              void* d_out, int out_size, void* d_ws, size_t ws_size,
                              hipStream_t stream) {
    const int*   seq        = (const int*)d_in[0];
    const int*   root       = (const int*)d_in[1];
    const int*   i2t_src    = (const int*)d_in[3];
    const int*   t2t_src    = (const int*)d_in[5];
    const int*   item_ids   = (const int*)d_in[6];
    const int*   tax_ids    = (const int*)d_in[7];
    const float* item_embed = (const float*)d_in[8];
    const float* tax_embed  = (const float*)d_in[9];
    const float* scb_ln_g   = (const float*)d_in[10];
    const float* scb_ln_b   = (const float*)d_in[11];
    const float* scb_w1     = (const float*)d_in[12];
    const float* scb_w2     = (const float*)d_in[13];
    const float* fcb_ln_g   = (const float*)d_in[14];
    const float* fcb_ln_b   = (const float*)d_in[15];
    const float* fcb_w1     = (const float*)d_in[16];
    const float* fcb_w2     = (const float*)d_in[17];
    const float* fcb_w3     = (const float*)d_in[18];
    const float* wv         = (const float*)d_in[19];
    const float* gi_w       = (const float*)d_in[20];
    const float* gi_al      = (const float*)d_in[21];
    const float* gi_ar      = (const float*)d_in[22];
    const float* gi_b       = (const float*)d_in[23];
    const float* gt_w       = (const float*)d_in[24];
    const float* gt_al      = (const float*)d_in[25];
    const float* gt_ar      = (const float*)d_in[26];
    const float* gt_b       = (const float*)d_in[27];
    const float* liw_g      = (const float*)d_in[28];
    const float* liw_b      = (const float*)d_in[29];
    const float* int_g      = (const float*)d_in[30];
    const float* int_b      = (const float*)d_in[31];
    const float* uni_w      = (const float*)d_in[32];

    char* w = (char*)d_ws;
    // ---- mixer phase (V and NV merged into one in-place buffer) ----
    float* NV  = (float*)(w + 0);                            // 52.4MB (V == NV)
    unsigned short* NVT = (unsigned short*)(w + 52428800);   // 29.4MB (also ZB)
    unsigned short* ZB  = NVT;
    unsigned short* T   = (unsigned short*)(w + 81788928);   // 67.1MB (full 512 b)
    unsigned short* W1T2 = (unsigned short*)(w + 148897792); // 2x229KB
    unsigned short* W2T2 = (unsigned short*)(w + 149356544); // 2x213KB
    // ---- GAT phase (mixer buffers dead after k_pool) ----
    unsigned short* ITEMHB = (unsigned short*)(w + 0);           // 26.2MB
    unsigned short* FSIB   = (unsigned short*)(w + 26214400);    // 26.2MB
    unsigned short* TAXB0  = (unsigned short*)(w + 52428800);    // 8.4MB
    unsigned short* TAXB1  = (unsigned short*)(w + 60817408);    // 8.4MB
    float* ACC   = (float*)(w + 69206016);                       // 16.8MB
    unsigned short* FDIB = (unsigned short*)(w + 85983232);      // 8.4MB
    unsigned short* FSTB = (unsigned short*)(w + 94371840);      // 8.4MB
    float* ELI   = (float*)(w + 102760448);
    float* ERI   = (float*)(w + 104398848);
    float* ELT   = (float*)(w + 104923136);
    float* ERT   = (float*)(w + 105447424);
    // ---- stable tail ----
    unsigned short* WB = (unsigned short*)(w + 191954944);   // 262KB converted weights
    float* G     = (float*)(w + 200343552);
    unsigned short* PB = (unsigned short*)(w + 200671232);   // 128KB
    if (ws_size < 200933376ull) return;

    // one-time weight prep
    k_wprep<<<1952, 256, 0, stream>>>(fcb_w1, fcb_w2, fcb_w3, gi_w, gt_w, WB,
                                      scb_w1, scb_w2, W1T2, W2T2);

    // ---- global intention (mixer) ----
    for (int nb = 0; nb < 2; ++nb) {
        k_lnt<<<dim3(4, TB), 128, 0, stream>>>(NV, nb == 0 ? seq : nullptr, item_embed,
                                               scb_ln_g + nb * TH, scb_ln_b + nb * TH, NV, NVT);
        k_mm1<<<dim3(4, TB), 256, 0, stream>>>(NVT, W1T2 + nb * 114688, T);
        k_mm2l<<<dim3(4, TB), 256, 0, stream>>>(T, W2T2 + nb * 106496, NV,
                                                fcb_ln_g + nb * TH, fcb_ln_b + nb * TH);
        k_ffuse<<<1024, 256, 0, stream>>>(NV, WB + nb * 8192, WB + 16384 + nb * 8192, ZB,
                                          TB * TL * 4 / 64);
        k_gmm_b<<<TB * TL / 128, 256, 0, stream>>>(ZB, WB + 32768 + nb * 16384, NV, NV);
    }
    k_pool<<<TB, 256, 0, stream>>>(NV, wv, G);

    // ---- local intention (GAT, bf16 features; scores fused into GEMM epilogue) ----
    k_gather2<<<(TNI * 16 + TNT * 16 + 255) / 256, 256, 0, stream>>>(
        item_embed, item_ids, ITEMHB, TNI, tax_embed, tax_ids, TAXB0, TNT);

    unsigned short* curb = TAXB0;
    unsigned short* nxtb = TAXB1;
    for (int hop = 0; hop < 2; ++hop) {
        const unsigned short* WiB = WB + 65536 + hop * 16384;
        const unsigned short* WtB = WB + 98304 + hop * 16384;
        k_gmm3s<<<TNI / 128 + 2 * (TNT / 128), 256, 0, stream>>>(
            ITEMHB, WiB, FSIB, TNI / 128, gi_al + hop * TH, ELI,
            curb, WiB, FDIB, TNT / 128, gi_ar + hop * TH, ERI,
            curb, WtB, FSTB, gt_al + hop * TH, ELT, gt_ar + hop * TH, ERT);
        k_gat<<<TNT, 128, 0, stream>>>(curb, FSIB, ELI, ERI, i2t_src, gi_b + hop * TH,
                                       FSTB, ELT, ERT, t2t_src, gt_b + hop * TH, nxtb, ACC, hop);
        unsigned short* tmp = curb; curb = nxtb; nxtb = tmp;
    }

    // ---- fuse + final ----
    k_locfuse<<<TB, 128, 0, stream>>>(root, ACC, G, liw_g, liw_b, int_g, int_b, uni_w, PB);
    k_final_m2<<<TIPAD / 128, 256, 0, stream>>>(PB, item_embed, (float*)d_out);
}